// Round 1
// baseline (2940.806 us; speedup 1.0000x reference)
//
#include <hip/hip_runtime.h>
#include <math.h>

namespace {
constexpr int B_   = 64;
constexpr int NPG  = 2048;
constexpr int N0   = B_ * NPG;      // 131072
constexpr int E0   = N0 * 4;        // 524288
constexpr int H_   = 128;
constexpr int K1   = 1639, K2 = 1312, K3 = 1050;
constexpr int N1   = B_ * K1;       // 104896
constexpr int N2   = B_ * K2;       // 83968
constexpr int N3   = B_ * K3;       // 67200
constexpr int ACT  = 124;
}

// ---------- h = X[M,4] @ W[4,128] ----------
__global__ void mm4_k(const float* __restrict__ X, const float* __restrict__ W,
                      float* __restrict__ out, int M)
{
    __shared__ float sW[512];
    for (int i = threadIdx.x; i < 512; i += blockDim.x) sW[i] = W[i];
    __syncthreads();
    int gid = blockIdx.x * blockDim.x + threadIdx.x;
    int n = gid >> 7, c = gid & 127;
    if (n >= M) return;
    float4 xv = *(const float4*)(X + (size_t)n * 4);
    out[gid] = xv.x * sW[c] + xv.y * sW[128 + c] + xv.z * sW[256 + c] + xv.w * sW[384 + c];
}

// ---------- C[M,128] = A[M,128] @ W[128,128], fp32, LDS tiled ----------
__global__ __launch_bounds__(256) void mmh_k(const float* __restrict__ A,
                                             const float* __restrict__ W,
                                             float* __restrict__ C, int M)
{
    __shared__ float sW[128 * 128];
    __shared__ float sA[32 * 128];
    int tid = threadIdx.x;
    for (int i = tid * 4; i < 128 * 128; i += 1024)
        *(float4*)(sW + i) = *(const float4*)(W + i);
    int row0 = blockIdx.x * 32;
    for (int i = tid * 4; i < 32 * 128; i += 1024) {
        int r = row0 + (i >> 7);
        float4 v = make_float4(0.f, 0.f, 0.f, 0.f);
        if (r < M) v = *(const float4*)(A + (size_t)r * H_ + (i & 127));
        *(float4*)(sA + i) = v;
    }
    __syncthreads();
    int c4 = (tid & 31) * 4;
    int rg = tid >> 5;   // 0..7, 4 rows each
    float4 a0 = make_float4(0,0,0,0), a1 = a0, a2 = a0, a3 = a0;
    for (int kk = 0; kk < 128; ++kk) {
        float4 wv = *(const float4*)(sW + kk * 128 + c4);
        float x0 = sA[(rg * 4 + 0) * 128 + kk];
        float x1 = sA[(rg * 4 + 1) * 128 + kk];
        float x2 = sA[(rg * 4 + 2) * 128 + kk];
        float x3 = sA[(rg * 4 + 3) * 128 + kk];
        a0.x += x0 * wv.x; a0.y += x0 * wv.y; a0.z += x0 * wv.z; a0.w += x0 * wv.w;
        a1.x += x1 * wv.x; a1.y += x1 * wv.y; a1.z += x1 * wv.z; a1.w += x1 * wv.w;
        a2.x += x2 * wv.x; a2.y += x2 * wv.y; a2.z += x2 * wv.z; a2.w += x2 * wv.w;
        a3.x += x3 * wv.x; a3.y += x3 * wv.y; a3.z += x3 * wv.z; a3.w += x3 * wv.w;
    }
    int r = row0 + rg * 4;
    if (r + 0 < M) *(float4*)(C + (size_t)(r + 0) * H_ + c4) = a0;
    if (r + 1 < M) *(float4*)(C + (size_t)(r + 1) * H_ + c4) = a1;
    if (r + 2 < M) *(float4*)(C + (size_t)(r + 2) * H_ + c4) = a2;
    if (r + 3 < M) *(float4*)(C + (size_t)(r + 3) * H_ + c4) = a3;
}

// ---------- degree count (level 0: all edges valid) ----------
__global__ void count_deg_k(const int* __restrict__ dst, int E, int* __restrict__ deg)
{
    int e = blockIdx.x * blockDim.x + threadIdx.x;
    if (e < E) atomicAdd(deg + dst[e], 1);
}

__global__ void dis_k(const int* __restrict__ deg, float* __restrict__ dis, int n)
{
    int i = blockIdx.x * blockDim.x + threadIdx.x;
    if (i < n) dis[i] = 1.0f / sqrtf((float)deg[i] + 1.0f);
}

// ---------- edge scatter-aggregate: out[dst] += h[src]*dis[src]*dis[dst] ----------
__global__ void scatter_k(const float* __restrict__ Hf, const int* __restrict__ src,
                          const int* __restrict__ dst, const int* __restrict__ ecntIn,
                          int fixedE, const float* __restrict__ dis, float* __restrict__ out)
{
    int gid = blockIdx.x * blockDim.x + threadIdx.x;
    int e = gid >> 5;
    int E = ecntIn ? *ecntIn : fixedE;
    if (e >= E) return;
    int lane = gid & 31;
    int s = src[e], d = dst[e];
    float coef = dis[s] * dis[d];
    float4 hv = *(const float4*)(Hf + (size_t)s * H_ + lane * 4);
    float* o = out + (size_t)d * H_ + lane * 4;
    atomicAdd(o + 0, hv.x * coef);
    atomicAdd(o + 1, hv.y * coef);
    atomicAdd(o + 2, hv.z * coef);
    atomicAdd(o + 3, hv.w * coef);
}

// ---------- out = relu(agg + h*dis^2 + b) ----------
__global__ void final_k(float* __restrict__ out, const float* __restrict__ Hf,
                        const float* __restrict__ dis, const float* __restrict__ bias, int M)
{
    int gid = blockIdx.x * blockDim.x + threadIdx.x;
    if (gid >= M * H_) return;
    int n = gid >> 7, f = gid & 127;
    float dv = dis[n];
    float v = out[gid] + Hf[gid] * dv * dv + bias[f];
    out[gid] = v > 0.f ? v : 0.f;
}

// ---------- score[n] = tanh(dot(x[n],p)/||p||), one wave per node ----------
__global__ void score_k(const float* __restrict__ X, const float* __restrict__ p,
                        float* __restrict__ score, int nNodes)
{
    int gid = blockIdx.x * blockDim.x + threadIdx.x;
    int node = gid >> 6;
    int lane = threadIdx.x & 63;
    if (node >= nNodes) return;
    const float* xr = X + (size_t)node * H_;
    float a0 = xr[lane], a1 = xr[lane + 64];
    float p0 = p[lane],  p1 = p[lane + 64];
    float dt = a0 * p0 + a1 * p1;
    float nr = p0 * p0 + p1 * p1;
    for (int m = 32; m > 0; m >>= 1) {
        dt += __shfl_xor(dt, m);
        nr += __shfl_xor(nr, m);
    }
    if (lane == 0) score[node] = tanhf(dt / sqrtf(nr));
}

// ---------- exact per-graph top-k via bitonic sort (desc, tie: low index) ----------
__global__ __launch_bounds__(1024) void topk_k(const float* __restrict__ score, int n, int k,
                                               int* __restrict__ selOld, int* __restrict__ newpos)
{
    __shared__ unsigned long long key[2048];
    int b = blockIdx.x;
    const float* s = score + (size_t)b * n;
    for (int i = threadIdx.x; i < 2048; i += 1024) {
        unsigned long long pk = 0ull;
        if (i < n) {
            unsigned u = __float_as_uint(s[i]);
            u = (u & 0x80000000u) ? ~u : (u | 0x80000000u);
            pk = ((unsigned long long)u << 32) | (unsigned)(65535 - i);
        }
        key[i] = pk;
    }
    __syncthreads();
    for (int sz = 2; sz <= 2048; sz <<= 1) {
        for (int st = sz >> 1; st > 0; st >>= 1) {
            for (int t = threadIdx.x; t < 2048; t += 1024) {
                int j = t ^ st;
                if (j > t) {
                    unsigned long long a = key[t], c = key[j];
                    bool desc = ((t & sz) == 0);
                    if ((a < c) == desc) { key[t] = c; key[j] = a; }
                }
            }
            __syncthreads();
        }
    }
    for (int j = threadIdx.x; j < k; j += 1024) {
        int o = 65535 - (int)(key[j] & 0xFFFFFFFFull);
        int oldg = b * n + o;
        selOld[b * k + j] = oldg;
        newpos[oldg] = b * k + j;
    }
}

// ---------- x_new[j] = x[sel[j]] * score[sel[j]] ----------
__global__ void gather_k(const float* __restrict__ X, const float* __restrict__ score,
                         const int* __restrict__ selOld, float* __restrict__ out, int Mnew)
{
    int gid = blockIdx.x * blockDim.x + threadIdx.x;
    if (gid >= Mnew * H_) return;
    int j = gid >> 7, f = gid & 127;
    int o = selOld[j];
    out[gid] = X[(size_t)o * H_ + f] * score[o];
}

// ---------- zsum[b] += [max || mean] over k rows ----------
__global__ void readout_k(const float* __restrict__ X, int kRows, float* __restrict__ zsum)
{
    __shared__ float smax[4][128];
    __shared__ float ssum[4][128];
    int b = blockIdx.x;
    int f = threadIdx.x & 127;
    int q = threadIdx.x >> 7;
    int chunk = (kRows + 3) >> 2;
    int j0 = q * chunk;
    int j1 = min(kRows, j0 + chunk);
    const float* base = X + (size_t)b * kRows * H_;
    float mx = -3.4e38f, sm = 0.f;
    for (int j = j0; j < j1; ++j) {
        float v = base[(size_t)j * H_ + f];
        mx = fmaxf(mx, v); sm += v;
    }
    smax[q][f] = mx; ssum[q][f] = sm;
    __syncthreads();
    if (q == 0) {
        mx = fmaxf(fmaxf(smax[0][f], smax[1][f]), fmaxf(smax[2][f], smax[3][f]));
        sm = ssum[0][f] + ssum[1][f] + ssum[2][f] + ssum[3][f];
        zsum[b * 256 + f]       += mx;
        zsum[b * 256 + 128 + f] += sm * (1.0f / (float)kRows);
    }
}

// ---------- edge remap + compaction + next-level degree ----------
__global__ void remap_k(const int* __restrict__ osrc, const int* __restrict__ odst,
                        const int* __restrict__ ecntIn, int fixedE,
                        const int* __restrict__ newpos,
                        int* __restrict__ nsrc, int* __restrict__ ndst,
                        int* __restrict__ ecntOut, int* __restrict__ deg)
{
    int E = ecntIn ? *ecntIn : fixedE;
    int e = blockIdx.x * blockDim.x + threadIdx.x;
    if (e >= E) return;
    int ns = newpos[osrc[e]];
    int nd = newpos[odst[e]];
    if (ns >= 0 && nd >= 0) {
        int pos = atomicAdd(ecntOut, 1);
        nsrc[pos] = ns; ndst[pos] = nd;
        atomicAdd(deg + nd, 1);
    }
}

// ---------- small MLP layer: out[b,c] = act(in[b,:]@W + bias) ----------
__global__ void mlp_k(const float* __restrict__ in, const float* __restrict__ Wm,
                      const float* __restrict__ bias, float* __restrict__ out,
                      int inF, int outF, int mode)
{
    int b = blockIdx.x;
    int c = threadIdx.x;
    if (c >= outF) return;
    const float* xr = in + b * inF;
    float s = bias[c];
    for (int i = 0; i < inF; ++i) s += xr[i] * Wm[i * outF + c];
    if (mode == 0) s = fmaxf(s, 0.f);
    else s = 1.f / (1.f + expf(-s));
    out[b * outF + c] = s;
}

extern "C" void kernel_launch(void* const* d_in, const int* in_sizes, int n_in,
                              void* d_out, int out_size, void* d_ws, size_t ws_size,
                              hipStream_t stream)
{
    const float* x   = (const float*)d_in[0];
    const int*   src = (const int*)d_in[1];
    const int*   dst = (const int*)d_in[2];
    const float* W1  = (const float*)d_in[3];
    const float* b1  = (const float*)d_in[4];
    const float* W2  = (const float*)d_in[5];
    const float* b2  = (const float*)d_in[6];
    const float* W3  = (const float*)d_in[7];
    const float* b3  = (const float*)d_in[8];
    const float* p1  = (const float*)d_in[9];
    const float* p2  = (const float*)d_in[10];
    const float* p3  = (const float*)d_in[11];
    const float* lw1 = (const float*)d_in[12];
    const float* lb1 = (const float*)d_in[13];
    const float* lw2 = (const float*)d_in[14];
    const float* lb2 = (const float*)d_in[15];
    const float* lw3 = (const float*)d_in[16];
    const float* lb3 = (const float*)d_in[17];

    char* w = (char*)d_ws;
    size_t off = 0;
    auto alloc = [&](size_t bytes) -> void* {
        void* p = w + off;
        off = (off + bytes + 255) & ~(size_t)255;
        return p;
    };
    float* fA     = (float*)alloc((size_t)N0 * H_ * 4);   // h = X@W
    float* fB     = (float*)alloc((size_t)N0 * H_ * 4);   // aggregate / activations
    float* fC     = (float*)alloc((size_t)N1 * H_ * 4);   // pooled features
    float* score  = (float*)alloc((size_t)N0 * 4);
    int*   newpos = (int*)  alloc((size_t)N0 * 4);
    int*   deg    = (int*)  alloc((size_t)N0 * 4);
    float* dis    = (float*)alloc((size_t)N0 * 4);
    int*   selOld = (int*)  alloc((size_t)N1 * 4);
    int*   es1    = (int*)  alloc((size_t)E0 * 4);
    int*   ed1    = (int*)  alloc((size_t)E0 * 4);
    int*   es2    = (int*)  alloc((size_t)E0 * 4);
    int*   ed2    = (int*)  alloc((size_t)E0 * 4);
    float* zsum   = (float*)alloc((size_t)B_ * 256 * 4);
    float* z1     = (float*)alloc((size_t)B_ * 128 * 4);
    float* z2     = (float*)alloc((size_t)B_ * 64 * 4);
    int*   ecnt   = (int*)  alloc(256);                   // [0]=E1, [1]=E2

    hipMemsetAsync(zsum, 0, (size_t)B_ * 256 * 4, stream);
    hipMemsetAsync(ecnt, 0, 256, stream);

    // ================= GCN1 (level-0 graph: N0 nodes, E0 edges) =================
    hipMemsetAsync(deg, 0, (size_t)N0 * 4, stream);
    mm4_k<<<(N0 * H_) / 256, 256, 0, stream>>>(x, W1, fA, N0);
    count_deg_k<<<E0 / 256, 256, 0, stream>>>(dst, E0, deg);
    dis_k<<<(N0 + 255) / 256, 256, 0, stream>>>(deg, dis, N0);
    hipMemsetAsync(fB, 0, (size_t)N0 * H_ * 4, stream);
    scatter_k<<<(E0 * 32) / 256, 256, 0, stream>>>(fA, src, dst, nullptr, E0, dis, fB);
    final_k<<<(N0 * H_) / 256, 256, 0, stream>>>(fB, fA, dis, b1, N0);

    // ---- pool 1: 2048 -> K1 per graph ----
    score_k<<<(N0 * 64) / 256, 256, 0, stream>>>(fB, p1, score, N0);
    hipMemsetAsync(newpos, 0xFF, (size_t)N0 * 4, stream);
    topk_k<<<B_, 1024, 0, stream>>>(score, NPG, K1, selOld, newpos);
    gather_k<<<(N1 * H_ + 255) / 256, 256, 0, stream>>>(fB, score, selOld, fC, N1);
    readout_k<<<B_, 512, 0, stream>>>(fC, K1, zsum);
    hipMemsetAsync(deg, 0, (size_t)N1 * 4, stream);
    remap_k<<<E0 / 256, 256, 0, stream>>>(src, dst, nullptr, E0, newpos, es1, ed1, ecnt + 0, deg);
    dis_k<<<(N1 + 255) / 256, 256, 0, stream>>>(deg, dis, N1);

    // ================= GCN2 (N1 nodes) =================
    mmh_k<<<(N1 + 31) / 32, 256, 0, stream>>>(fC, W2, fA, N1);
    hipMemsetAsync(fB, 0, (size_t)N1 * H_ * 4, stream);
    scatter_k<<<(E0 * 32) / 256, 256, 0, stream>>>(fA, es1, ed1, ecnt + 0, 0, dis, fB);
    final_k<<<(N1 * H_ + 255) / 256, 256, 0, stream>>>(fB, fA, dis, b2, N1);

    // ---- pool 2: K1 -> K2 per graph ----
    score_k<<<(N1 * 64 + 255) / 256, 256, 0, stream>>>(fB, p2, score, N1);
    hipMemsetAsync(newpos, 0xFF, (size_t)N1 * 4, stream);
    topk_k<<<B_, 1024, 0, stream>>>(score, K1, K2, selOld, newpos);
    gather_k<<<(N2 * H_ + 255) / 256, 256, 0, stream>>>(fB, score, selOld, fC, N2);
    readout_k<<<B_, 512, 0, stream>>>(fC, K2, zsum);
    hipMemsetAsync(deg, 0, (size_t)N2 * 4, stream);
    remap_k<<<E0 / 256, 256, 0, stream>>>(es1, ed1, ecnt + 0, 0, newpos, es2, ed2, ecnt + 1, deg);
    dis_k<<<(N2 + 255) / 256, 256, 0, stream>>>(deg, dis, N2);

    // ================= GCN3 (N2 nodes) =================
    mmh_k<<<(N2 + 31) / 32, 256, 0, stream>>>(fC, W3, fA, N2);
    hipMemsetAsync(fB, 0, (size_t)N2 * H_ * 4, stream);
    scatter_k<<<(E0 * 32) / 256, 256, 0, stream>>>(fA, es2, ed2, ecnt + 1, 0, dis, fB);
    final_k<<<(N2 * H_ + 255) / 256, 256, 0, stream>>>(fB, fA, dis, b3, N2);

    // ---- pool 3: K2 -> K3 per graph ----
    score_k<<<(N2 * 64 + 255) / 256, 256, 0, stream>>>(fB, p3, score, N2);
    hipMemsetAsync(newpos, 0xFF, (size_t)N2 * 4, stream);
    topk_k<<<B_, 1024, 0, stream>>>(score, K2, K3, selOld, newpos);
    gather_k<<<(N3 * H_ + 255) / 256, 256, 0, stream>>>(fB, score, selOld, fC, N3);
    readout_k<<<B_, 512, 0, stream>>>(fC, K3, zsum);

    // ================= MLP head =================
    mlp_k<<<B_, 128, 0, stream>>>(zsum, lw1, lb1, z1, 256, 128, 0);
    mlp_k<<<B_, 64, 0, stream>>>(z1, lw2, lb2, z2, 128, 64, 0);
    mlp_k<<<B_, 128, 0, stream>>>(z2, lw3, lb3, (float*)d_out, 64, ACT, 1);
}

// Round 2
// 1242.089 us; speedup vs baseline: 2.3676x; 2.3676x over previous
//
#include <hip/hip_runtime.h>
#include <math.h>

namespace {
constexpr int B_   = 64;
constexpr int NPG  = 2048;
constexpr int N0   = B_ * NPG;      // 131072
constexpr int E0   = N0 * 4;        // 524288
constexpr int H_   = 128;
constexpr int K1   = 1639, K2 = 1312, K3 = 1050;
constexpr int N1   = B_ * K1;       // 104896
constexpr int N2   = B_ * K2;       // 83968
constexpr int N3   = B_ * K3;       // 67200
constexpr int ACT  = 124;
}

// ---------- h = X[M,4] @ W[4,128] ----------
__global__ void mm4_k(const float* __restrict__ X, const float* __restrict__ W,
                      float* __restrict__ out, int M)
{
    __shared__ float sW[512];
    for (int i = threadIdx.x; i < 512; i += blockDim.x) sW[i] = W[i];
    __syncthreads();
    int gid = blockIdx.x * blockDim.x + threadIdx.x;
    int n = gid >> 7, c = gid & 127;
    if (n >= M) return;
    float4 xv = *(const float4*)(X + (size_t)n * 4);
    out[gid] = xv.x * sW[c] + xv.y * sW[128 + c] + xv.z * sW[256 + c] + xv.w * sW[384 + c];
}

// ---------- C[M,128] = A[M,128] @ W[128,128], fp32, LDS tiled ----------
__global__ __launch_bounds__(256) void mmh_k(const float* __restrict__ A,
                                             const float* __restrict__ W,
                                             float* __restrict__ C, int M)
{
    __shared__ float sW[128 * 128];
    __shared__ float sA[32 * 128];
    int tid = threadIdx.x;
    for (int i = tid * 4; i < 128 * 128; i += 1024)
        *(float4*)(sW + i) = *(const float4*)(W + i);
    int row0 = blockIdx.x * 32;
    for (int i = tid * 4; i < 32 * 128; i += 1024) {
        int r = row0 + (i >> 7);
        float4 v = make_float4(0.f, 0.f, 0.f, 0.f);
        if (r < M) v = *(const float4*)(A + (size_t)r * H_ + (i & 127));
        *(float4*)(sA + i) = v;
    }
    __syncthreads();
    int c4 = (tid & 31) * 4;
    int rg = tid >> 5;   // 0..7, 4 rows each
    float4 a0 = make_float4(0,0,0,0), a1 = a0, a2 = a0, a3 = a0;
    for (int kk = 0; kk < 128; ++kk) {
        float4 wv = *(const float4*)(sW + kk * 128 + c4);
        float x0 = sA[(rg * 4 + 0) * 128 + kk];
        float x1 = sA[(rg * 4 + 1) * 128 + kk];
        float x2 = sA[(rg * 4 + 2) * 128 + kk];
        float x3 = sA[(rg * 4 + 3) * 128 + kk];
        a0.x += x0 * wv.x; a0.y += x0 * wv.y; a0.z += x0 * wv.z; a0.w += x0 * wv.w;
        a1.x += x1 * wv.x; a1.y += x1 * wv.y; a1.z += x1 * wv.z; a1.w += x1 * wv.w;
        a2.x += x2 * wv.x; a2.y += x2 * wv.y; a2.z += x2 * wv.z; a2.w += x2 * wv.w;
        a3.x += x3 * wv.x; a3.y += x3 * wv.y; a3.z += x3 * wv.z; a3.w += x3 * wv.w;
    }
    int r = row0 + rg * 4;
    if (r + 0 < M) *(float4*)(C + (size_t)(r + 0) * H_ + c4) = a0;
    if (r + 1 < M) *(float4*)(C + (size_t)(r + 1) * H_ + c4) = a1;
    if (r + 2 < M) *(float4*)(C + (size_t)(r + 2) * H_ + c4) = a2;
    if (r + 3 < M) *(float4*)(C + (size_t)(r + 3) * H_ + c4) = a3;
}

// ---------- degree count (level 0: all edges valid) ----------
__global__ void count_deg_k(const int* __restrict__ dst, int E, int* __restrict__ deg)
{
    int e = blockIdx.x * blockDim.x + threadIdx.x;
    if (e < E) atomicAdd(deg + dst[e], 1);
}

__global__ void dis_k(const int* __restrict__ deg, float* __restrict__ dis, int n)
{
    int i = blockIdx.x * blockDim.x + threadIdx.x;
    if (i < n) dis[i] = 1.0f / sqrtf((float)deg[i] + 1.0f);
}

// ---------- exclusive scan (3-kernel) over deg -> rowoff ----------
__global__ __launch_bounds__(1024) void scan1_k(const int* __restrict__ in, int* __restrict__ out,
                                                int* __restrict__ bsum, int n)
{
    __shared__ int s[1024];
    int t = threadIdx.x;
    int i = blockIdx.x * 1024 + t;
    int v = (i < n) ? in[i] : 0;
    s[t] = v;
    __syncthreads();
    for (int d = 1; d < 1024; d <<= 1) {
        int add = (t >= d) ? s[t - d] : 0;
        __syncthreads();
        s[t] += add;
        __syncthreads();
    }
    if (i < n) out[i] = s[t] - v;          // exclusive
    if (t == 1023) bsum[blockIdx.x] = s[1023];
}

__global__ void scan2_k(int* __restrict__ bsum, int nb)
{
    if (threadIdx.x == 0) {
        int acc = 0;
        for (int i = 0; i < nb; ++i) { int v = bsum[i]; bsum[i] = acc; acc += v; }
    }
}

__global__ void scan3_k(int* __restrict__ out, const int* __restrict__ bsum, int n)
{
    int i = blockIdx.x * blockDim.x + threadIdx.x;
    if (i < n) out[i] += bsum[i >> 10];
}

// ---------- counting-sort fill: bucket src ids by dst ----------
__global__ void fill_k(const int* __restrict__ src, const int* __restrict__ dst,
                       const int* __restrict__ ecntIn, int fixedE,
                       const int* __restrict__ rowoff, int* __restrict__ cur,
                       int* __restrict__ esrc)
{
    int E = ecntIn ? *ecntIn : fixedE;
    int e = blockIdx.x * blockDim.x + threadIdx.x;
    if (e >= E) return;
    int d = dst[e];
    int pos = rowoff[d] + atomicAdd(cur + d, 1);
    esrc[pos] = src[e];
}

// ---------- fused gather-aggregate + self-loop + bias + relu ----------
// one wave (64 lanes) per dst node, float2 per lane
__global__ __launch_bounds__(256) void agg_k(const float* __restrict__ Hf,
                                             const int* __restrict__ rowoff,
                                             const int* __restrict__ esrc,
                                             const int* __restrict__ ecntIn, int fixedE,
                                             const float* __restrict__ dis,
                                             const float* __restrict__ bias,
                                             float* __restrict__ out, int M)
{
    int gid = blockIdx.x * blockDim.x + threadIdx.x;
    int n = gid >> 6;
    if (n >= M) return;
    int lane = gid & 63;
    float dn = dis[n];
    int beg = rowoff[n];
    int end = (n + 1 < M) ? rowoff[n + 1] : (ecntIn ? *ecntIn : fixedE);
    float2 hv = ((const float2*)(Hf + (size_t)n * H_))[lane];
    float acc0 = hv.x * dn * dn + bias[lane * 2 + 0];
    float acc1 = hv.y * dn * dn + bias[lane * 2 + 1];
    for (int e = beg; e < end; ++e) {
        int s = esrc[e];
        float c = dis[s] * dn;
        float2 sv = ((const float2*)(Hf + (size_t)s * H_))[lane];
        acc0 += sv.x * c;
        acc1 += sv.y * c;
    }
    float2 o;
    o.x = fmaxf(acc0, 0.f);
    o.y = fmaxf(acc1, 0.f);
    ((float2*)(out + (size_t)n * H_))[lane] = o;
}

// ---------- score[n] = tanh(dot(x[n],p)/||p||), one wave per node ----------
__global__ void score_k(const float* __restrict__ X, const float* __restrict__ p,
                        float* __restrict__ score, int nNodes)
{
    int gid = blockIdx.x * blockDim.x + threadIdx.x;
    int node = gid >> 6;
    int lane = threadIdx.x & 63;
    if (node >= nNodes) return;
    const float* xr = X + (size_t)node * H_;
    float a0 = xr[lane], a1 = xr[lane + 64];
    float p0 = p[lane],  p1 = p[lane + 64];
    float dt = a0 * p0 + a1 * p1;
    float nr = p0 * p0 + p1 * p1;
    for (int m = 32; m > 0; m >>= 1) {
        dt += __shfl_xor(dt, m);
        nr += __shfl_xor(nr, m);
    }
    if (lane == 0) score[node] = tanhf(dt / sqrtf(nr));
}

// ---------- exact per-graph top-k via bitonic sort (desc, tie: low index) ----------
__global__ __launch_bounds__(1024) void topk_k(const float* __restrict__ score, int n, int k,
                                               int* __restrict__ selOld, int* __restrict__ newpos)
{
    __shared__ unsigned long long key[2048];
    int b = blockIdx.x;
    const float* s = score + (size_t)b * n;
    for (int i = threadIdx.x; i < 2048; i += 1024) {
        unsigned long long pk = 0ull;
        if (i < n) {
            unsigned u = __float_as_uint(s[i]);
            u = (u & 0x80000000u) ? ~u : (u | 0x80000000u);
            pk = ((unsigned long long)u << 32) | (unsigned)(65535 - i);
        }
        key[i] = pk;
    }
    __syncthreads();
    for (int sz = 2; sz <= 2048; sz <<= 1) {
        for (int st = sz >> 1; st > 0; st >>= 1) {
            for (int t = threadIdx.x; t < 2048; t += 1024) {
                int j = t ^ st;
                if (j > t) {
                    unsigned long long a = key[t], c = key[j];
                    bool desc = ((t & sz) == 0);
                    if ((a < c) == desc) { key[t] = c; key[j] = a; }
                }
            }
            __syncthreads();
        }
    }
    for (int j = threadIdx.x; j < k; j += 1024) {
        int o = 65535 - (int)(key[j] & 0xFFFFFFFFull);
        int oldg = b * n + o;
        selOld[b * k + j] = oldg;
        newpos[oldg] = b * k + j;
    }
}

// ---------- x_new[j] = x[sel[j]] * score[sel[j]] ----------
__global__ void gather_k(const float* __restrict__ X, const float* __restrict__ score,
                         const int* __restrict__ selOld, float* __restrict__ out, int Mnew)
{
    int gid = blockIdx.x * blockDim.x + threadIdx.x;
    if (gid >= Mnew * H_) return;
    int j = gid >> 7, f = gid & 127;
    int o = selOld[j];
    out[gid] = X[(size_t)o * H_ + f] * score[o];
}

// ---------- zsum[b] += [max || mean] over k rows ----------
__global__ void readout_k(const float* __restrict__ X, int kRows, float* __restrict__ zsum)
{
    __shared__ float smax[4][128];
    __shared__ float ssum[4][128];
    int b = blockIdx.x;
    int f = threadIdx.x & 127;
    int q = threadIdx.x >> 7;
    int chunk = (kRows + 3) >> 2;
    int j0 = q * chunk;
    int j1 = min(kRows, j0 + chunk);
    const float* base = X + (size_t)b * kRows * H_;
    float mx = -3.4e38f, sm = 0.f;
    for (int j = j0; j < j1; ++j) {
        float v = base[(size_t)j * H_ + f];
        mx = fmaxf(mx, v); sm += v;
    }
    smax[q][f] = mx; ssum[q][f] = sm;
    __syncthreads();
    if (q == 0) {
        mx = fmaxf(fmaxf(smax[0][f], smax[1][f]), fmaxf(smax[2][f], smax[3][f]));
        sm = ssum[0][f] + ssum[1][f] + ssum[2][f] + ssum[3][f];
        zsum[b * 256 + f]       += mx;
        zsum[b * 256 + 128 + f] += sm * (1.0f / (float)kRows);
    }
}

// ---------- edge remap + compaction + next-level degree ----------
__global__ void remap_k(const int* __restrict__ osrc, const int* __restrict__ odst,
                        const int* __restrict__ ecntIn, int fixedE,
                        const int* __restrict__ newpos,
                        int* __restrict__ nsrc, int* __restrict__ ndst,
                        int* __restrict__ ecntOut, int* __restrict__ deg)
{
    int E = ecntIn ? *ecntIn : fixedE;
    int e = blockIdx.x * blockDim.x + threadIdx.x;
    if (e >= E) return;
    int ns = newpos[osrc[e]];
    int nd = newpos[odst[e]];
    if (ns >= 0 && nd >= 0) {
        int pos = atomicAdd(ecntOut, 1);
        nsrc[pos] = ns; ndst[pos] = nd;
        atomicAdd(deg + nd, 1);
    }
}

// ---------- small MLP layer: out[b,c] = act(in[b,:]@W + bias) ----------
__global__ void mlp_k(const float* __restrict__ in, const float* __restrict__ Wm,
                      const float* __restrict__ bias, float* __restrict__ out,
                      int inF, int outF, int mode)
{
    int b = blockIdx.x;
    int c = threadIdx.x;
    if (c >= outF) return;
    const float* xr = in + b * inF;
    float s = bias[c];
    for (int i = 0; i < inF; ++i) s += xr[i] * Wm[i * outF + c];
    if (mode == 0) s = fmaxf(s, 0.f);
    else s = 1.f / (1.f + expf(-s));
    out[b * outF + c] = s;
}

extern "C" void kernel_launch(void* const* d_in, const int* in_sizes, int n_in,
                              void* d_out, int out_size, void* d_ws, size_t ws_size,
                              hipStream_t stream)
{
    const float* x   = (const float*)d_in[0];
    const int*   src = (const int*)d_in[1];
    const int*   dst = (const int*)d_in[2];
    const float* W1  = (const float*)d_in[3];
    const float* b1  = (const float*)d_in[4];
    const float* W2  = (const float*)d_in[5];
    const float* b2  = (const float*)d_in[6];
    const float* W3  = (const float*)d_in[7];
    const float* b3  = (const float*)d_in[8];
    const float* p1  = (const float*)d_in[9];
    const float* p2  = (const float*)d_in[10];
    const float* p3  = (const float*)d_in[11];
    const float* lw1 = (const float*)d_in[12];
    const float* lb1 = (const float*)d_in[13];
    const float* lw2 = (const float*)d_in[14];
    const float* lb2 = (const float*)d_in[15];
    const float* lw3 = (const float*)d_in[16];
    const float* lb3 = (const float*)d_in[17];

    char* w = (char*)d_ws;
    size_t off = 0;
    auto alloc = [&](size_t bytes) -> void* {
        void* p = w + off;
        off = (off + bytes + 255) & ~(size_t)255;
        return p;
    };
    float* fA     = (float*)alloc((size_t)N0 * H_ * 4);   // h = X@W
    float* fB     = (float*)alloc((size_t)N0 * H_ * 4);   // gcn output activations
    float* fC     = (float*)alloc((size_t)N1 * H_ * 4);   // pooled features
    float* score  = (float*)alloc((size_t)N0 * 4);
    int*   newpos = (int*)  alloc((size_t)N0 * 4);
    int*   deg    = (int*)  alloc((size_t)N0 * 4);
    float* dis    = (float*)alloc((size_t)N0 * 4);
    int*   selOld = (int*)  alloc((size_t)N1 * 4);
    int*   rowoff = (int*)  alloc((size_t)N0 * 4);
    int*   cur    = (int*)  alloc((size_t)N0 * 4);
    int*   esrc   = (int*)  alloc((size_t)E0 * 4);
    int*   bsum   = (int*)  alloc((size_t)1024 * 4);
    int*   es1    = (int*)  alloc((size_t)E0 * 4);
    int*   ed1    = (int*)  alloc((size_t)E0 * 4);
    int*   es2    = (int*)  alloc((size_t)E0 * 4);
    int*   ed2    = (int*)  alloc((size_t)E0 * 4);
    float* zsum   = (float*)alloc((size_t)B_ * 256 * 4);
    float* z1     = (float*)alloc((size_t)B_ * 128 * 4);
    float* z2     = (float*)alloc((size_t)B_ * 64 * 4);
    int*   ecnt   = (int*)  alloc(256);                   // [0]=E1, [1]=E2

    hipMemsetAsync(zsum, 0, (size_t)B_ * 256 * 4, stream);
    hipMemsetAsync(ecnt, 0, 256, stream);

    auto build_csr = [&](const int* s_, const int* d_, const int* ecntIn, int fixedE, int nNodes) {
        int nb = (nNodes + 1023) / 1024;
        scan1_k<<<nb, 1024, 0, stream>>>(deg, rowoff, bsum, nNodes);
        scan2_k<<<1, 64, 0, stream>>>(bsum, nb);
        scan3_k<<<(nNodes + 255) / 256, 256, 0, stream>>>(rowoff, bsum, nNodes);
        hipMemsetAsync(cur, 0, (size_t)nNodes * 4, stream);
        fill_k<<<E0 / 256, 256, 0, stream>>>(s_, d_, ecntIn, fixedE, rowoff, cur, esrc);
    };

    // ================= GCN1 (level-0 graph: N0 nodes, E0 edges) =================
    hipMemsetAsync(deg, 0, (size_t)N0 * 4, stream);
    mm4_k<<<(N0 * H_) / 256, 256, 0, stream>>>(x, W1, fA, N0);
    count_deg_k<<<E0 / 256, 256, 0, stream>>>(dst, E0, deg);
    dis_k<<<(N0 + 255) / 256, 256, 0, stream>>>(deg, dis, N0);
    build_csr(src, dst, nullptr, E0, N0);
    agg_k<<<(N0 * 64) / 256, 256, 0, stream>>>(fA, rowoff, esrc, nullptr, E0, dis, b1, fB, N0);

    // ---- pool 1: 2048 -> K1 per graph ----
    score_k<<<(N0 * 64) / 256, 256, 0, stream>>>(fB, p1, score, N0);
    hipMemsetAsync(newpos, 0xFF, (size_t)N0 * 4, stream);
    topk_k<<<B_, 1024, 0, stream>>>(score, NPG, K1, selOld, newpos);
    gather_k<<<(N1 * H_ + 255) / 256, 256, 0, stream>>>(fB, score, selOld, fC, N1);
    readout_k<<<B_, 512, 0, stream>>>(fC, K1, zsum);
    hipMemsetAsync(deg, 0, (size_t)N1 * 4, stream);
    remap_k<<<E0 / 256, 256, 0, stream>>>(src, dst, nullptr, E0, newpos, es1, ed1, ecnt + 0, deg);
    dis_k<<<(N1 + 255) / 256, 256, 0, stream>>>(deg, dis, N1);

    // ================= GCN2 (N1 nodes) =================
    mmh_k<<<(N1 + 31) / 32, 256, 0, stream>>>(fC, W2, fA, N1);
    build_csr(es1, ed1, ecnt + 0, 0, N1);
    agg_k<<<(N1 * 64 + 255) / 256, 256, 0, stream>>>(fA, rowoff, esrc, ecnt + 0, 0, dis, b2, fB, N1);

    // ---- pool 2: K1 -> K2 per graph ----
    score_k<<<(N1 * 64 + 255) / 256, 256, 0, stream>>>(fB, p2, score, N1);
    hipMemsetAsync(newpos, 0xFF, (size_t)N1 * 4, stream);
    topk_k<<<B_, 1024, 0, stream>>>(score, K1, K2, selOld, newpos);
    gather_k<<<(N2 * H_ + 255) / 256, 256, 0, stream>>>(fB, score, selOld, fC, N2);
    readout_k<<<B_, 512, 0, stream>>>(fC, K2, zsum);
    hipMemsetAsync(deg, 0, (size_t)N2 * 4, stream);
    remap_k<<<E0 / 256, 256, 0, stream>>>(es1, ed1, ecnt + 0, 0, newpos, es2, ed2, ecnt + 1, deg);
    dis_k<<<(N2 + 255) / 256, 256, 0, stream>>>(deg, dis, N2);

    // ================= GCN3 (N2 nodes) =================
    mmh_k<<<(N2 + 31) / 32, 256, 0, stream>>>(fC, W3, fA, N2);
    build_csr(es2, ed2, ecnt + 1, 0, N2);
    agg_k<<<(N2 * 64 + 255) / 256, 256, 0, stream>>>(fA, rowoff, esrc, ecnt + 1, 0, dis, b3, fB, N2);

    // ---- pool 3: K2 -> K3 per graph ----
    score_k<<<(N2 * 64 + 255) / 256, 256, 0, stream>>>(fB, p3, score, N2);
    hipMemsetAsync(newpos, 0xFF, (size_t)N2 * 4, stream);
    topk_k<<<B_, 1024, 0, stream>>>(score, K2, K3, selOld, newpos);
    gather_k<<<(N3 * H_ + 255) / 256, 256, 0, stream>>>(fB, score, selOld, fC, N3);
    readout_k<<<B_, 512, 0, stream>>>(fC, K3, zsum);

    // ================= MLP head =================
    mlp_k<<<B_, 128, 0, stream>>>(zsum, lw1, lb1, z1, 256, 128, 0);
    mlp_k<<<B_, 64, 0, stream>>>(z1, lw2, lb2, z2, 128, 64, 0);
    mlp_k<<<B_, 128, 0, stream>>>(z2, lw3, lb3, (float*)d_out, 64, ACT, 1);
}

// Round 3
// 945.658 us; speedup vs baseline: 3.1098x; 1.3135x over previous
//
#include <hip/hip_runtime.h>
#include <math.h>

namespace {
constexpr int B_   = 64;
constexpr int NPG  = 2048;
constexpr int N0   = B_ * NPG;      // 131072
constexpr int E0   = N0 * 4;        // 524288
constexpr int H_   = 128;
constexpr int K1   = 1639, K2 = 1312, K3 = 1050;
constexpr int N1   = B_ * K1;       // 104896
constexpr int N2   = B_ * K2;       // 83968
constexpr int N3   = B_ * K3;       // 67200
constexpr int ACT  = 124;
constexpr int RS   = 32;            // readout segments per graph
}

// ---------- h = X[M,4] @ W[4,128] ----------
__global__ void mm4_k(const float* __restrict__ X, const float* __restrict__ W,
                      float* __restrict__ out, int M)
{
    __shared__ float sW[512];
    for (int i = threadIdx.x; i < 512; i += blockDim.x) sW[i] = W[i];
    __syncthreads();
    int gid = blockIdx.x * blockDim.x + threadIdx.x;
    int n = gid >> 7, c = gid & 127;
    if (n >= M) return;
    float4 xv = *(const float4*)(X + (size_t)n * 4);
    out[gid] = xv.x * sW[c] + xv.y * sW[128 + c] + xv.z * sW[256 + c] + xv.w * sW[384 + c];
}

// ---------- C[M,128] = A[M,128] @ W[128,128], fp32, LDS tiled ----------
__global__ __launch_bounds__(256) void mmh_k(const float* __restrict__ A,
                                             const float* __restrict__ W,
                                             float* __restrict__ C, int M)
{
    __shared__ float sW[128 * 128];
    __shared__ float sA[32 * 128];
    int tid = threadIdx.x;
    for (int i = tid * 4; i < 128 * 128; i += 1024)
        *(float4*)(sW + i) = *(const float4*)(W + i);
    int row0 = blockIdx.x * 32;
    for (int i = tid * 4; i < 32 * 128; i += 1024) {
        int r = row0 + (i >> 7);
        float4 v = make_float4(0.f, 0.f, 0.f, 0.f);
        if (r < M) v = *(const float4*)(A + (size_t)r * H_ + (i & 127));
        *(float4*)(sA + i) = v;
    }
    __syncthreads();
    int c4 = (tid & 31) * 4;
    int rg = tid >> 5;   // 0..7, 4 rows each
    float4 a0 = make_float4(0,0,0,0), a1 = a0, a2 = a0, a3 = a0;
    for (int kk = 0; kk < 128; ++kk) {
        float4 wv = *(const float4*)(sW + kk * 128 + c4);
        float x0 = sA[(rg * 4 + 0) * 128 + kk];
        float x1 = sA[(rg * 4 + 1) * 128 + kk];
        float x2 = sA[(rg * 4 + 2) * 128 + kk];
        float x3 = sA[(rg * 4 + 3) * 128 + kk];
        a0.x += x0 * wv.x; a0.y += x0 * wv.y; a0.z += x0 * wv.z; a0.w += x0 * wv.w;
        a1.x += x1 * wv.x; a1.y += x1 * wv.y; a1.z += x1 * wv.z; a1.w += x1 * wv.w;
        a2.x += x2 * wv.x; a2.y += x2 * wv.y; a2.z += x2 * wv.z; a2.w += x2 * wv.w;
        a3.x += x3 * wv.x; a3.y += x3 * wv.y; a3.z += x3 * wv.z; a3.w += x3 * wv.w;
    }
    int r = row0 + rg * 4;
    if (r + 0 < M) *(float4*)(C + (size_t)(r + 0) * H_ + c4) = a0;
    if (r + 1 < M) *(float4*)(C + (size_t)(r + 1) * H_ + c4) = a1;
    if (r + 2 < M) *(float4*)(C + (size_t)(r + 2) * H_ + c4) = a2;
    if (r + 3 < M) *(float4*)(C + (size_t)(r + 3) * H_ + c4) = a3;
}

// ---------- degree count ----------
__global__ void count_deg_k(const int* __restrict__ dst, int E, int* __restrict__ deg)
{
    int e = blockIdx.x * blockDim.x + threadIdx.x;
    if (e < E) atomicAdd(deg + dst[e], 1);
}

__global__ void dis_k(const int* __restrict__ deg, float* __restrict__ dis, int n)
{
    int i = blockIdx.x * blockDim.x + threadIdx.x;
    if (i < n) dis[i] = 1.0f / sqrtf((float)deg[i] + 1.0f);
}

// ---------- exclusive scan (3-kernel) over deg -> rowoff ----------
__global__ __launch_bounds__(1024) void scan1_k(const int* __restrict__ in, int* __restrict__ out,
                                                int* __restrict__ bsum, int n)
{
    __shared__ int s[1024];
    int t = threadIdx.x;
    int i = blockIdx.x * 1024 + t;
    int v = (i < n) ? in[i] : 0;
    s[t] = v;
    __syncthreads();
    for (int d = 1; d < 1024; d <<= 1) {
        int add = (t >= d) ? s[t - d] : 0;
        __syncthreads();
        s[t] += add;
        __syncthreads();
    }
    if (i < n) out[i] = s[t] - v;          // exclusive
    if (t == 1023) bsum[blockIdx.x] = s[1023];
}

__global__ void scan2_k(int* __restrict__ bsum, int nb)
{
    if (threadIdx.x == 0) {
        int acc = 0;
        for (int i = 0; i < nb; ++i) { int v = bsum[i]; bsum[i] = acc; acc += v; }
    }
}

__global__ void scan3_k(int* __restrict__ out, const int* __restrict__ bsum, int n)
{
    int i = blockIdx.x * blockDim.x + threadIdx.x;
    if (i < n) out[i] += bsum[i >> 10];
}

// ---------- counting-sort fill: bucket src ids by dst ----------
__global__ void fill_k(const int* __restrict__ src, const int* __restrict__ dst,
                       const int* __restrict__ ecntIn, int fixedE,
                       const int* __restrict__ rowoff, int* __restrict__ cur,
                       int* __restrict__ esrc)
{
    int E = ecntIn ? *ecntIn : fixedE;
    int e = blockIdx.x * blockDim.x + threadIdx.x;
    if (e >= E) return;
    int d = dst[e];
    int pos = rowoff[d] + atomicAdd(cur + d, 1);
    esrc[pos] = src[e];
}

// ---------- fused gather-aggregate + self-loop + bias + relu + pooling score ----------
// one wave (64 lanes) per dst node, float2 per lane
__global__ __launch_bounds__(256) void agg_k(const float* __restrict__ Hf,
                                             const int* __restrict__ rowoff,
                                             const int* __restrict__ esrc,
                                             const int* __restrict__ ecntIn, int fixedE,
                                             const float* __restrict__ dis,
                                             const float* __restrict__ bias,
                                             const float* __restrict__ p,
                                             float* __restrict__ out,
                                             float* __restrict__ score, int M)
{
    int gid = blockIdx.x * blockDim.x + threadIdx.x;
    int n = gid >> 6;
    if (n >= M) return;
    int lane = gid & 63;
    float dn = dis[n];
    int beg = rowoff[n];
    int end = (n + 1 < M) ? rowoff[n + 1] : (ecntIn ? *ecntIn : fixedE);
    float2 hv = ((const float2*)(Hf + (size_t)n * H_))[lane];
    float acc0 = hv.x * dn * dn + bias[lane * 2 + 0];
    float acc1 = hv.y * dn * dn + bias[lane * 2 + 1];
    for (int e = beg; e < end; ++e) {
        int s = esrc[e];
        float c = dis[s] * dn;
        float2 sv = ((const float2*)(Hf + (size_t)s * H_))[lane];
        acc0 += sv.x * c;
        acc1 += sv.y * c;
    }
    float o0 = fmaxf(acc0, 0.f);
    float o1 = fmaxf(acc1, 0.f);
    ((float2*)(out + (size_t)n * H_))[lane] = make_float2(o0, o1);
    // fused pooling score: tanh(dot(o, p) / ||p||)
    float p0 = p[lane * 2], p1 = p[lane * 2 + 1];
    float dt = o0 * p0 + o1 * p1;
    float nr = p0 * p0 + p1 * p1;
    for (int m = 32; m > 0; m >>= 1) {
        dt += __shfl_xor(dt, m);
        nr += __shfl_xor(nr, m);
    }
    if (lane == 0) score[n] = tanhf(dt / sqrtf(nr));
}

// ---------- exact per-graph top-k via bitonic sort (desc, tie: low index) ----------
__global__ __launch_bounds__(1024) void topk_k(const float* __restrict__ score, int n, int k,
                                               int* __restrict__ selOld, int* __restrict__ newpos)
{
    __shared__ unsigned long long key[2048];
    int b = blockIdx.x;
    const float* s = score + (size_t)b * n;
    for (int i = threadIdx.x; i < 2048; i += 1024) {
        unsigned long long pk = 0ull;
        if (i < n) {
            unsigned u = __float_as_uint(s[i]);
            u = (u & 0x80000000u) ? ~u : (u | 0x80000000u);
            pk = ((unsigned long long)u << 32) | (unsigned)(65535 - i);
        }
        key[i] = pk;
    }
    __syncthreads();
    for (int sz = 2; sz <= 2048; sz <<= 1) {
        for (int st = sz >> 1; st > 0; st >>= 1) {
            for (int t = threadIdx.x; t < 2048; t += 1024) {
                int j = t ^ st;
                if (j > t) {
                    unsigned long long a = key[t], c = key[j];
                    bool desc = ((t & sz) == 0);
                    if ((a < c) == desc) { key[t] = c; key[j] = a; }
                }
            }
            __syncthreads();
        }
    }
    for (int j = threadIdx.x; j < k; j += 1024) {
        int o = 65535 - (int)(key[j] & 0xFFFFFFFFull);
        int oldg = b * n + o;
        selOld[b * k + j] = oldg;
        newpos[oldg] = b * k + j;
    }
}

// ---------- x_new[j] = x[sel[j]] * score[sel[j]] ----------
__global__ void gather_k(const float* __restrict__ X, const float* __restrict__ score,
                         const int* __restrict__ selOld, float* __restrict__ out, int Mnew)
{
    int gid = blockIdx.x * blockDim.x + threadIdx.x;
    if (gid >= Mnew * H_) return;
    int j = gid >> 7, f = gid & 127;
    int o = selOld[j];
    out[gid] = X[(size_t)o * H_ + f] * score[o];
}

// ---------- readout stage 1: per-(graph,segment) partial max/sum ----------
__global__ __launch_bounds__(512) void readout_part_k(const float* __restrict__ X, int kRows,
                                                      float* __restrict__ part)
{
    __shared__ float smax[4][128];
    __shared__ float ssum[4][128];
    int b = blockIdx.x / RS;
    int s = blockIdx.x % RS;
    int chunk = (kRows + RS - 1) / RS;
    int j0 = s * chunk;
    int j1 = min(kRows, j0 + chunk);
    int f = threadIdx.x & 127;
    int q = threadIdx.x >> 7;          // 4 row groups
    const float* base = X + (size_t)b * kRows * H_;
    float mx = -3.4e38f, sm = 0.f;
    for (int j = j0 + q; j < j1; j += 4) {
        float v = base[(size_t)j * H_ + f];
        mx = fmaxf(mx, v); sm += v;
    }
    smax[q][f] = mx; ssum[q][f] = sm;
    __syncthreads();
    if (q == 0) {
        mx = fmaxf(fmaxf(smax[0][f], smax[1][f]), fmaxf(smax[2][f], smax[3][f]));
        sm = ssum[0][f] + ssum[1][f] + ssum[2][f] + ssum[3][f];
        float* pr = part + ((size_t)b * RS + s) * 256;
        pr[f] = mx;
        pr[128 + f] = sm;
    }
}

// ---------- readout stage 2: fold RS partials into zsum ----------
__global__ __launch_bounds__(256) void readout_red_k(const float* __restrict__ part, int kRows,
                                                     float* __restrict__ zsum)
{
    int b = blockIdx.x;
    int f = threadIdx.x & 127;
    int half = threadIdx.x >> 7;       // 0: max, 1: sum
    const float* pr = part + (size_t)b * RS * 256;
    if (half == 0) {
        float mx = -3.4e38f;
        for (int s = 0; s < RS; ++s) mx = fmaxf(mx, pr[s * 256 + f]);
        zsum[b * 256 + f] += mx;
    } else {
        float sm = 0.f;
        for (int s = 0; s < RS; ++s) sm += pr[s * 256 + 128 + f];
        zsum[b * 256 + 128 + f] += sm * (1.0f / (float)kRows);
    }
}

// ---------- edge remap + compaction + next-level degree ----------
__global__ void remap_k(const int* __restrict__ osrc, const int* __restrict__ odst,
                        const int* __restrict__ ecntIn, int fixedE,
                        const int* __restrict__ newpos,
                        int* __restrict__ nsrc, int* __restrict__ ndst,
                        int* __restrict__ ecntOut, int* __restrict__ deg)
{
    int E = ecntIn ? *ecntIn : fixedE;
    int e = blockIdx.x * blockDim.x + threadIdx.x;
    if (e >= E) return;
    int ns = newpos[osrc[e]];
    int nd = newpos[odst[e]];
    if (ns >= 0 && nd >= 0) {
        int pos = atomicAdd(ecntOut, 1);
        nsrc[pos] = ns; ndst[pos] = nd;
        atomicAdd(deg + nd, 1);
    }
}

// ---------- small MLP layer: out[b,c] = act(in[b,:]@W + bias) ----------
__global__ void mlp_k(const float* __restrict__ in, const float* __restrict__ Wm,
                      const float* __restrict__ bias, float* __restrict__ out,
                      int inF, int outF, int mode)
{
    int b = blockIdx.x;
    int c = threadIdx.x;
    if (c >= outF) return;
    const float* xr = in + b * inF;
    float s = bias[c];
    for (int i = 0; i < inF; ++i) s += xr[i] * Wm[i * outF + c];
    if (mode == 0) s = fmaxf(s, 0.f);
    else s = 1.f / (1.f + expf(-s));
    out[b * outF + c] = s;
}

extern "C" void kernel_launch(void* const* d_in, const int* in_sizes, int n_in,
                              void* d_out, int out_size, void* d_ws, size_t ws_size,
                              hipStream_t stream)
{
    const float* x   = (const float*)d_in[0];
    const int*   src = (const int*)d_in[1];
    const int*   dst = (const int*)d_in[2];
    const float* W1  = (const float*)d_in[3];
    const float* b1  = (const float*)d_in[4];
    const float* W2  = (const float*)d_in[5];
    const float* b2  = (const float*)d_in[6];
    const float* W3  = (const float*)d_in[7];
    const float* b3  = (const float*)d_in[8];
    const float* p1  = (const float*)d_in[9];
    const float* p2  = (const float*)d_in[10];
    const float* p3  = (const float*)d_in[11];
    const float* lw1 = (const float*)d_in[12];
    const float* lb1 = (const float*)d_in[13];
    const float* lw2 = (const float*)d_in[14];
    const float* lb2 = (const float*)d_in[15];
    const float* lw3 = (const float*)d_in[16];
    const float* lb3 = (const float*)d_in[17];

    char* w = (char*)d_ws;
    size_t off = 0;
    auto alloc = [&](size_t bytes) -> void* {
        void* p = w + off;
        off = (off + bytes + 255) & ~(size_t)255;
        return p;
    };
    float* fA     = (float*)alloc((size_t)N0 * H_ * 4);   // h = X@W
    float* fB     = (float*)alloc((size_t)N0 * H_ * 4);   // gcn output activations
    float* fC     = (float*)alloc((size_t)N1 * H_ * 4);   // pooled features
    float* score  = (float*)alloc((size_t)N0 * 4);
    int*   newpos = (int*)  alloc((size_t)N0 * 4);
    int*   deg    = (int*)  alloc((size_t)N0 * 4);
    float* dis    = (float*)alloc((size_t)N0 * 4);
    int*   selOld = (int*)  alloc((size_t)N1 * 4);
    int*   rowoff = (int*)  alloc((size_t)N0 * 4);
    int*   cur    = (int*)  alloc((size_t)N0 * 4);
    int*   esrc   = (int*)  alloc((size_t)E0 * 4);
    int*   bsum   = (int*)  alloc((size_t)1024 * 4);
    int*   es1    = (int*)  alloc((size_t)E0 * 4);
    int*   ed1    = (int*)  alloc((size_t)E0 * 4);
    int*   es2    = (int*)  alloc((size_t)E0 * 4);
    int*   ed2    = (int*)  alloc((size_t)E0 * 4);
    float* part   = (float*)alloc((size_t)B_ * RS * 256 * 4);
    float* zsum   = (float*)alloc((size_t)B_ * 256 * 4);
    float* z1     = (float*)alloc((size_t)B_ * 128 * 4);
    float* z2     = (float*)alloc((size_t)B_ * 64 * 4);
    int*   ecnt   = (int*)  alloc(256);                   // [0]=E1, [1]=E2

    hipMemsetAsync(zsum, 0, (size_t)B_ * 256 * 4, stream);
    hipMemsetAsync(ecnt, 0, 256, stream);

    auto build_csr = [&](const int* s_, const int* d_, const int* ecntIn, int fixedE, int nNodes) {
        int nb = (nNodes + 1023) / 1024;
        scan1_k<<<nb, 1024, 0, stream>>>(deg, rowoff, bsum, nNodes);
        scan2_k<<<1, 64, 0, stream>>>(bsum, nb);
        scan3_k<<<(nNodes + 255) / 256, 256, 0, stream>>>(rowoff, bsum, nNodes);
        hipMemsetAsync(cur, 0, (size_t)nNodes * 4, stream);
        fill_k<<<E0 / 256, 256, 0, stream>>>(s_, d_, ecntIn, fixedE, rowoff, cur, esrc);
    };

    // ================= GCN1 (level-0 graph: N0 nodes, E0 edges) =================
    hipMemsetAsync(deg, 0, (size_t)N0 * 4, stream);
    mm4_k<<<(N0 * H_) / 256, 256, 0, stream>>>(x, W1, fA, N0);
    count_deg_k<<<E0 / 256, 256, 0, stream>>>(dst, E0, deg);
    dis_k<<<(N0 + 255) / 256, 256, 0, stream>>>(deg, dis, N0);
    build_csr(src, dst, nullptr, E0, N0);
    agg_k<<<(N0 * 64) / 256, 256, 0, stream>>>(fA, rowoff, esrc, nullptr, E0, dis, b1, p1, fB, score, N0);

    // ---- pool 1: 2048 -> K1 per graph ----
    hipMemsetAsync(newpos, 0xFF, (size_t)N0 * 4, stream);
    topk_k<<<B_, 1024, 0, stream>>>(score, NPG, K1, selOld, newpos);
    gather_k<<<(N1 * H_ + 255) / 256, 256, 0, stream>>>(fB, score, selOld, fC, N1);
    readout_part_k<<<B_ * RS, 512, 0, stream>>>(fC, K1, part);
    readout_red_k<<<B_, 256, 0, stream>>>(part, K1, zsum);
    hipMemsetAsync(deg, 0, (size_t)N1 * 4, stream);
    remap_k<<<E0 / 256, 256, 0, stream>>>(src, dst, nullptr, E0, newpos, es1, ed1, ecnt + 0, deg);
    dis_k<<<(N1 + 255) / 256, 256, 0, stream>>>(deg, dis, N1);

    // ================= GCN2 (N1 nodes) =================
    mmh_k<<<(N1 + 31) / 32, 256, 0, stream>>>(fC, W2, fA, N1);
    build_csr(es1, ed1, ecnt + 0, 0, N1);
    agg_k<<<(N1 * 64 + 255) / 256, 256, 0, stream>>>(fA, rowoff, esrc, ecnt + 0, 0, dis, b2, p2, fB, score, N1);

    // ---- pool 2: K1 -> K2 per graph ----
    hipMemsetAsync(newpos, 0xFF, (size_t)N1 * 4, stream);
    topk_k<<<B_, 1024, 0, stream>>>(score, K1, K2, selOld, newpos);
    gather_k<<<(N2 * H_ + 255) / 256, 256, 0, stream>>>(fB, score, selOld, fC, N2);
    readout_part_k<<<B_ * RS, 512, 0, stream>>>(fC, K2, part);
    readout_red_k<<<B_, 256, 0, stream>>>(part, K2, zsum);
    hipMemsetAsync(deg, 0, (size_t)N2 * 4, stream);
    remap_k<<<E0 / 256, 256, 0, stream>>>(es1, ed1, ecnt + 0, 0, newpos, es2, ed2, ecnt + 1, deg);
    dis_k<<<(N2 + 255) / 256, 256, 0, stream>>>(deg, dis, N2);

    // ================= GCN3 (N2 nodes) =================
    mmh_k<<<(N2 + 31) / 32, 256, 0, stream>>>(fC, W3, fA, N2);
    build_csr(es2, ed2, ecnt + 1, 0, N2);
    agg_k<<<(N2 * 64 + 255) / 256, 256, 0, stream>>>(fA, rowoff, esrc, ecnt + 1, 0, dis, b3, p3, fB, score, N2);

    // ---- pool 3: K2 -> K3 per graph ----
    hipMemsetAsync(newpos, 0xFF, (size_t)N2 * 4, stream);
    topk_k<<<B_, 1024, 0, stream>>>(score, K2, K3, selOld, newpos);
    gather_k<<<(N3 * H_ + 255) / 256, 256, 0, stream>>>(fB, score, selOld, fC, N3);
    readout_part_k<<<B_ * RS, 512, 0, stream>>>(fC, K3, part);
    readout_red_k<<<B_, 256, 0, stream>>>(part, K3, zsum);

    // ================= MLP head =================
    mlp_k<<<B_, 128, 0, stream>>>(zsum, lw1, lb1, z1, 256, 128, 0);
    mlp_k<<<B_, 64, 0, stream>>>(z1, lw2, lb2, z2, 128, 64, 0);
    mlp_k<<<B_, 128, 0, stream>>>(z2, lw3, lb3, (float*)d_out, 64, ACT, 1);
}

// Round 4
// 810.733 us; speedup vs baseline: 3.6273x; 1.1664x over previous
//
#include <hip/hip_runtime.h>
#include <math.h>

namespace {
constexpr int B_   = 64;
constexpr int NPG  = 2048;
constexpr int N0   = B_ * NPG;      // 131072
constexpr int E0   = N0 * 4;        // 524288
constexpr int H_   = 128;
constexpr int K1   = 1639, K2 = 1312, K3 = 1050;
constexpr int N1   = B_ * K1;       // 104896
constexpr int N2   = B_ * K2;       // 83968
constexpr int N3   = B_ * K3;       // 67200
constexpr int ACT  = 124;
constexpr int RS   = 32;            // readout segments per graph
}

// ---------- h = X[M,4] @ W[4,128] ----------
__global__ void mm4_k(const float* __restrict__ X, const float* __restrict__ W,
                      float* __restrict__ out, int M)
{
    __shared__ float sW[512];
    for (int i = threadIdx.x; i < 512; i += blockDim.x) sW[i] = W[i];
    __syncthreads();
    int gid = blockIdx.x * blockDim.x + threadIdx.x;
    int n = gid >> 7, c = gid & 127;
    if (n >= M) return;
    float4 xv = *(const float4*)(X + (size_t)n * 4);
    out[gid] = xv.x * sW[c] + xv.y * sW[128 + c] + xv.z * sW[256 + c] + xv.w * sW[384 + c];
}

// ---------- C[M,128] = A[M,128] @ W[128,128], fp32, LDS tiled ----------
__global__ __launch_bounds__(256) void mmh_k(const float* __restrict__ A,
                                             const float* __restrict__ W,
                                             float* __restrict__ C, int M)
{
    __shared__ float sW[128 * 128];
    __shared__ float sA[32 * 128];
    int tid = threadIdx.x;
    for (int i = tid * 4; i < 128 * 128; i += 1024)
        *(float4*)(sW + i) = *(const float4*)(W + i);
    int row0 = blockIdx.x * 32;
    for (int i = tid * 4; i < 32 * 128; i += 1024) {
        int r = row0 + (i >> 7);
        float4 v = make_float4(0.f, 0.f, 0.f, 0.f);
        if (r < M) v = *(const float4*)(A + (size_t)r * H_ + (i & 127));
        *(float4*)(sA + i) = v;
    }
    __syncthreads();
    int c4 = (tid & 31) * 4;
    int rg = tid >> 5;   // 0..7, 4 rows each
    float4 a0 = make_float4(0,0,0,0), a1 = a0, a2 = a0, a3 = a0;
    for (int kk = 0; kk < 128; ++kk) {
        float4 wv = *(const float4*)(sW + kk * 128 + c4);
        float x0 = sA[(rg * 4 + 0) * 128 + kk];
        float x1 = sA[(rg * 4 + 1) * 128 + kk];
        float x2 = sA[(rg * 4 + 2) * 128 + kk];
        float x3 = sA[(rg * 4 + 3) * 128 + kk];
        a0.x += x0 * wv.x; a0.y += x0 * wv.y; a0.z += x0 * wv.z; a0.w += x0 * wv.w;
        a1.x += x1 * wv.x; a1.y += x1 * wv.y; a1.z += x1 * wv.z; a1.w += x1 * wv.w;
        a2.x += x2 * wv.x; a2.y += x2 * wv.y; a2.z += x2 * wv.z; a2.w += x2 * wv.w;
        a3.x += x3 * wv.x; a3.y += x3 * wv.y; a3.z += x3 * wv.z; a3.w += x3 * wv.w;
    }
    int r = row0 + rg * 4;
    if (r + 0 < M) *(float4*)(C + (size_t)(r + 0) * H_ + c4) = a0;
    if (r + 1 < M) *(float4*)(C + (size_t)(r + 1) * H_ + c4) = a1;
    if (r + 2 < M) *(float4*)(C + (size_t)(r + 2) * H_ + c4) = a2;
    if (r + 3 < M) *(float4*)(C + (size_t)(r + 3) * H_ + c4) = a3;
}

// ---------- degree count (level 0) ----------
__global__ void count_deg_k(const int* __restrict__ dst, int E, int* __restrict__ deg)
{
    int e = blockIdx.x * blockDim.x + threadIdx.x;
    if (e < E) atomicAdd(deg + dst[e], 1);
}

__global__ void dis_k(const int* __restrict__ deg, float* __restrict__ dis, int n)
{
    int i = blockIdx.x * blockDim.x + threadIdx.x;
    if (i < n) dis[i] = 1.0f / sqrtf((float)deg[i] + 1.0f);
}

// ---------- exclusive scan (3-kernel) over deg[0..n-1] -> rowoff ----------
__global__ __launch_bounds__(1024) void scan1_k(const int* __restrict__ in, int* __restrict__ out,
                                                int* __restrict__ bsum, int n)
{
    __shared__ int s[1024];
    int t = threadIdx.x;
    int i = blockIdx.x * 1024 + t;
    int v = (i < n) ? in[i] : 0;
    s[t] = v;
    __syncthreads();
    for (int d = 1; d < 1024; d <<= 1) {
        int add = (t >= d) ? s[t - d] : 0;
        __syncthreads();
        s[t] += add;
        __syncthreads();
    }
    if (i < n) out[i] = s[t] - v;          // exclusive
    if (t == 1023) bsum[blockIdx.x] = s[1023];
}

__global__ void scan2_k(int* __restrict__ bsum, int nb)
{
    if (threadIdx.x == 0) {
        int acc = 0;
        for (int i = 0; i < nb; ++i) { int v = bsum[i]; bsum[i] = acc; acc += v; }
    }
}

__global__ void scan3_k(int* __restrict__ out, const int* __restrict__ bsum, int n)
{
    int i = blockIdx.x * blockDim.x + threadIdx.x;
    if (i < n) out[i] += bsum[i >> 10];
}

__global__ void copy1_k(int* __restrict__ dstp, const int* __restrict__ srcp)
{
    if (threadIdx.x == 0) *dstp = *srcp;
}

// ---------- level-0 counting-sort fill: bucket src ids by dst ----------
__global__ void fill_k(const int* __restrict__ src, const int* __restrict__ dst, int E,
                       const int* __restrict__ rowoff, int* __restrict__ cur,
                       int* __restrict__ esrc)
{
    int e = blockIdx.x * blockDim.x + threadIdx.x;
    if (e >= E) return;
    int d = dst[e];
    int pos = rowoff[d] + atomicAdd(cur + d, 1);
    esrc[pos] = src[e];
}

// ---------- remap pass A: count surviving-edge degrees (distributed atomics) ----------
__global__ void remap_count_k(const int* __restrict__ osrc, const int* __restrict__ odst,
                              const int* __restrict__ ecntIn, int fixedE,
                              const int* __restrict__ newpos, int* __restrict__ deg)
{
    int E = ecntIn ? *ecntIn : fixedE;
    int e = blockIdx.x * blockDim.x + threadIdx.x;
    if (e >= E) return;
    int ns = newpos[osrc[e]];
    int nd = newpos[odst[e]];
    if (ns >= 0 && nd >= 0) atomicAdd(deg + nd, 1);
}

// ---------- remap pass B: fill next-level CSR (+ compacted edge list) ----------
__global__ void remap_fill_k(const int* __restrict__ osrc, const int* __restrict__ odst,
                             const int* __restrict__ ecntIn, int fixedE,
                             const int* __restrict__ newpos, const int* __restrict__ rowoff,
                             int* __restrict__ cur,
                             int* __restrict__ esrc, int* __restrict__ edst)
{
    int E = ecntIn ? *ecntIn : fixedE;
    int e = blockIdx.x * blockDim.x + threadIdx.x;
    if (e >= E) return;
    int ns = newpos[osrc[e]];
    int nd = newpos[odst[e]];
    if (ns >= 0 && nd >= 0) {
        int pos = rowoff[nd] + atomicAdd(cur + nd, 1);
        esrc[pos] = ns;
        edst[pos] = nd;
    }
}

// ---------- fused gather-aggregate + self-loop + bias + relu + pooling score ----------
// one wave (64 lanes) per dst node, float2 per lane; rowoff has M+1 entries
__global__ __launch_bounds__(256) void agg_k(const float* __restrict__ Hf,
                                             const int* __restrict__ rowoff,
                                             const int* __restrict__ esrc,
                                             const float* __restrict__ dis,
                                             const float* __restrict__ bias,
                                             const float* __restrict__ p,
                                             float* __restrict__ out,
                                             float* __restrict__ score, int M)
{
    int gid = blockIdx.x * blockDim.x + threadIdx.x;
    int n = gid >> 6;
    if (n >= M) return;
    int lane = gid & 63;
    float dn = dis[n];
    int beg = rowoff[n];
    int end = rowoff[n + 1];
    float2 hv = ((const float2*)(Hf + (size_t)n * H_))[lane];
    float acc0 = hv.x * dn * dn + bias[lane * 2 + 0];
    float acc1 = hv.y * dn * dn + bias[lane * 2 + 1];
    for (int e = beg; e < end; ++e) {
        int s = esrc[e];
        float c = dis[s] * dn;
        float2 sv = ((const float2*)(Hf + (size_t)s * H_))[lane];
        acc0 += sv.x * c;
        acc1 += sv.y * c;
    }
    float o0 = fmaxf(acc0, 0.f);
    float o1 = fmaxf(acc1, 0.f);
    ((float2*)(out + (size_t)n * H_))[lane] = make_float2(o0, o1);
    // fused pooling score: tanh(dot(o, p) / ||p||)
    float p0 = p[lane * 2], p1 = p[lane * 2 + 1];
    float dt = o0 * p0 + o1 * p1;
    float nr = p0 * p0 + p1 * p1;
    for (int m = 32; m > 0; m >>= 1) {
        dt += __shfl_xor(dt, m);
        nr += __shfl_xor(nr, m);
    }
    if (lane == 0) score[n] = tanhf(dt / sqrtf(nr));
}

// ---------- exact per-graph top-k via bitonic sort (desc, tie: low index) ----------
__global__ __launch_bounds__(1024) void topk_k(const float* __restrict__ score, int n, int k,
                                               int* __restrict__ selOld, int* __restrict__ newpos)
{
    __shared__ unsigned long long key[2048];
    int b = blockIdx.x;
    const float* s = score + (size_t)b * n;
    for (int i = threadIdx.x; i < 2048; i += 1024) {
        unsigned long long pk = 0ull;
        if (i < n) {
            unsigned u = __float_as_uint(s[i]);
            u = (u & 0x80000000u) ? ~u : (u | 0x80000000u);
            pk = ((unsigned long long)u << 32) | (unsigned)(65535 - i);
        }
        key[i] = pk;
    }
    __syncthreads();
    for (int sz = 2; sz <= 2048; sz <<= 1) {
        for (int st = sz >> 1; st > 0; st >>= 1) {
            for (int t = threadIdx.x; t < 2048; t += 1024) {
                int j = t ^ st;
                if (j > t) {
                    unsigned long long a = key[t], c = key[j];
                    bool desc = ((t & sz) == 0);
                    if ((a < c) == desc) { key[t] = c; key[j] = a; }
                }
            }
            __syncthreads();
        }
    }
    for (int j = threadIdx.x; j < k; j += 1024) {
        int o = 65535 - (int)(key[j] & 0xFFFFFFFFull);
        int oldg = b * n + o;
        selOld[b * k + j] = oldg;
        newpos[oldg] = b * k + j;
    }
}

// ---------- x_new[j] = x[sel[j]] * score[sel[j]] ----------
__global__ void gather_k(const float* __restrict__ X, const float* __restrict__ score,
                         const int* __restrict__ selOld, float* __restrict__ out, int Mnew)
{
    int gid = blockIdx.x * blockDim.x + threadIdx.x;
    if (gid >= Mnew * H_) return;
    int j = gid >> 7, f = gid & 127;
    int o = selOld[j];
    out[gid] = X[(size_t)o * H_ + f] * score[o];
}

// ---------- readout stage 1: per-(graph,segment) partial max/sum ----------
__global__ __launch_bounds__(512) void readout_part_k(const float* __restrict__ X, int kRows,
                                                      float* __restrict__ part)
{
    __shared__ float smax[4][128];
    __shared__ float ssum[4][128];
    int b = blockIdx.x / RS;
    int s = blockIdx.x % RS;
    int chunk = (kRows + RS - 1) / RS;
    int j0 = s * chunk;
    int j1 = min(kRows, j0 + chunk);
    int f = threadIdx.x & 127;
    int q = threadIdx.x >> 7;          // 4 row groups
    const float* base = X + (size_t)b * kRows * H_;
    float mx = -3.4e38f, sm = 0.f;
    for (int j = j0 + q; j < j1; j += 4) {
        float v = base[(size_t)j * H_ + f];
        mx = fmaxf(mx, v); sm += v;
    }
    smax[q][f] = mx; ssum[q][f] = sm;
    __syncthreads();
    if (q == 0) {
        mx = fmaxf(fmaxf(smax[0][f], smax[1][f]), fmaxf(smax[2][f], smax[3][f]));
        sm = ssum[0][f] + ssum[1][f] + ssum[2][f] + ssum[3][f];
        float* pr = part + ((size_t)b * RS + s) * 256;
        pr[f] = mx;
        pr[128 + f] = sm;
    }
}

// ---------- readout stage 2: fold RS partials into zsum ----------
__global__ __launch_bounds__(256) void readout_red_k(const float* __restrict__ part, int kRows,
                                                     float* __restrict__ zsum)
{
    int b = blockIdx.x;
    int f = threadIdx.x & 127;
    int half = threadIdx.x >> 7;       // 0: max, 1: sum
    const float* pr = part + (size_t)b * RS * 256;
    if (half == 0) {
        float mx = -3.4e38f;
        for (int s = 0; s < RS; ++s) mx = fmaxf(mx, pr[s * 256 + f]);
        zsum[b * 256 + f] += mx;
    } else {
        float sm = 0.f;
        for (int s = 0; s < RS; ++s) sm += pr[s * 256 + 128 + f];
        zsum[b * 256 + 128 + f] += sm * (1.0f / (float)kRows);
    }
}

// ---------- small MLP layer: out[b,c] = act(in[b,:]@W + bias) ----------
__global__ void mlp_k(const float* __restrict__ in, const float* __restrict__ Wm,
                      const float* __restrict__ bias, float* __restrict__ out,
                      int inF, int outF, int mode)
{
    int b = blockIdx.x;
    int c = threadIdx.x;
    if (c >= outF) return;
    const float* xr = in + b * inF;
    float s = bias[c];
    for (int i = 0; i < inF; ++i) s += xr[i] * Wm[i * outF + c];
    if (mode == 0) s = fmaxf(s, 0.f);
    else s = 1.f / (1.f + expf(-s));
    out[b * outF + c] = s;
}

extern "C" void kernel_launch(void* const* d_in, const int* in_sizes, int n_in,
                              void* d_out, int out_size, void* d_ws, size_t ws_size,
                              hipStream_t stream)
{
    const float* x   = (const float*)d_in[0];
    const int*   src = (const int*)d_in[1];
    const int*   dst = (const int*)d_in[2];
    const float* W1  = (const float*)d_in[3];
    const float* b1  = (const float*)d_in[4];
    const float* W2  = (const float*)d_in[5];
    const float* b2  = (const float*)d_in[6];
    const float* W3  = (const float*)d_in[7];
    const float* b3  = (const float*)d_in[8];
    const float* p1  = (const float*)d_in[9];
    const float* p2  = (const float*)d_in[10];
    const float* p3  = (const float*)d_in[11];
    const float* lw1 = (const float*)d_in[12];
    const float* lb1 = (const float*)d_in[13];
    const float* lw2 = (const float*)d_in[14];
    const float* lb2 = (const float*)d_in[15];
    const float* lw3 = (const float*)d_in[16];
    const float* lb3 = (const float*)d_in[17];

    char* w = (char*)d_ws;
    size_t off = 0;
    auto alloc = [&](size_t bytes) -> void* {
        void* p = w + off;
        off = (off + bytes + 255) & ~(size_t)255;
        return p;
    };
    float* fA     = (float*)alloc((size_t)N0 * H_ * 4);   // h = X@W
    float* fB     = (float*)alloc((size_t)N0 * H_ * 4);   // gcn output activations
    float* fC     = (float*)alloc((size_t)N1 * H_ * 4);   // pooled features
    float* score  = (float*)alloc((size_t)N0 * 4);
    int*   newpos = (int*)  alloc((size_t)N0 * 4);
    int*   deg    = (int*)  alloc((size_t)(N0 + 1) * 4);
    float* dis    = (float*)alloc((size_t)N0 * 4);
    int*   selOld = (int*)  alloc((size_t)N1 * 4);
    int*   rowoff = (int*)  alloc((size_t)(N0 + 1) * 4);
    int*   cur    = (int*)  alloc((size_t)N0 * 4);
    int*   bsum   = (int*)  alloc((size_t)1024 * 4);
    int*   cs0    = (int*)  alloc((size_t)E0 * 4);        // level-0 CSR src
    int*   cs1    = (int*)  alloc((size_t)E0 * 4);        // level-1 CSR src (= edge src list)
    int*   cd1    = (int*)  alloc((size_t)E0 * 4);        // level-1 edge dst list
    int*   cs2    = (int*)  alloc((size_t)E0 * 4);        // level-2 CSR src
    int*   cd2    = (int*)  alloc((size_t)E0 * 4);        // level-2 edge dst list (unused downstream)
    float* part   = (float*)alloc((size_t)B_ * RS * 256 * 4);
    float* zsum   = (float*)alloc((size_t)B_ * 256 * 4);
    float* z1     = (float*)alloc((size_t)B_ * 128 * 4);
    float* z2     = (float*)alloc((size_t)B_ * 64 * 4);
    int*   ecnt   = (int*)  alloc(256);                   // [0] = E1 (level-1 edge count)

    hipMemsetAsync(zsum, 0, (size_t)B_ * 256 * 4, stream);

    auto scan_rowoff = [&](int nNodes) {   // exclusive scan over deg[0..nNodes] (nNodes+1 entries)
        int n = nNodes + 1;
        int nb = (n + 1023) / 1024;
        scan1_k<<<nb, 1024, 0, stream>>>(deg, rowoff, bsum, n);
        scan2_k<<<1, 64, 0, stream>>>(bsum, nb);
        scan3_k<<<(n + 255) / 256, 256, 0, stream>>>(rowoff, bsum, n);
    };

    // ================= GCN1 (level-0 graph: N0 nodes, E0 edges) =================
    hipMemsetAsync(deg, 0, (size_t)(N0 + 1) * 4, stream);
    mm4_k<<<(N0 * H_) / 256, 256, 0, stream>>>(x, W1, fA, N0);
    count_deg_k<<<E0 / 256, 256, 0, stream>>>(dst, E0, deg);
    dis_k<<<(N0 + 255) / 256, 256, 0, stream>>>(deg, dis, N0);
    scan_rowoff(N0);
    hipMemsetAsync(cur, 0, (size_t)N0 * 4, stream);
    fill_k<<<E0 / 256, 256, 0, stream>>>(src, dst, E0, rowoff, cur, cs0);
    agg_k<<<(N0 * 64) / 256, 256, 0, stream>>>(fA, rowoff, cs0, dis, b1, p1, fB, score, N0);

    // ---- pool 1: 2048 -> K1 per graph ----
    hipMemsetAsync(newpos, 0xFF, (size_t)N0 * 4, stream);
    topk_k<<<B_, 1024, 0, stream>>>(score, NPG, K1, selOld, newpos);
    gather_k<<<(N1 * H_ + 255) / 256, 256, 0, stream>>>(fB, score, selOld, fC, N1);
    readout_part_k<<<B_ * RS, 512, 0, stream>>>(fC, K1, part);
    readout_red_k<<<B_, 256, 0, stream>>>(part, K1, zsum);

    // ---- build level-1 CSR directly from (src,dst) + newpos ----
    hipMemsetAsync(deg, 0, (size_t)(N1 + 1) * 4, stream);
    remap_count_k<<<E0 / 256, 256, 0, stream>>>(src, dst, nullptr, E0, newpos, deg);
    dis_k<<<(N1 + 255) / 256, 256, 0, stream>>>(deg, dis, N1);
    scan_rowoff(N1);
    copy1_k<<<1, 64, 0, stream>>>(ecnt, rowoff + N1);     // E1 for level-2 remap bound
    hipMemsetAsync(cur, 0, (size_t)N1 * 4, stream);
    remap_fill_k<<<E0 / 256, 256, 0, stream>>>(src, dst, nullptr, E0, newpos, rowoff, cur, cs1, cd1);

    // ================= GCN2 (N1 nodes) =================
    mmh_k<<<(N1 + 31) / 32, 256, 0, stream>>>(fC, W2, fA, N1);
    agg_k<<<(N1 * 64 + 255) / 256, 256, 0, stream>>>(fA, rowoff, cs1, dis, b2, p2, fB, score, N1);

    // ---- pool 2: K1 -> K2 per graph ----
    hipMemsetAsync(newpos, 0xFF, (size_t)N1 * 4, stream);
    topk_k<<<B_, 1024, 0, stream>>>(score, K1, K2, selOld, newpos);
    gather_k<<<(N2 * H_ + 255) / 256, 256, 0, stream>>>(fB, score, selOld, fC, N2);
    readout_part_k<<<B_ * RS, 512, 0, stream>>>(fC, K2, part);
    readout_red_k<<<B_, 256, 0, stream>>>(part, K2, zsum);

    // ---- build level-2 CSR from (cs1,cd1) + newpos ----
    hipMemsetAsync(deg, 0, (size_t)(N2 + 1) * 4, stream);
    remap_count_k<<<E0 / 256, 256, 0, stream>>>(cs1, cd1, ecnt, 0, newpos, deg);
    dis_k<<<(N2 + 255) / 256, 256, 0, stream>>>(deg, dis, N2);
    scan_rowoff(N2);
    hipMemsetAsync(cur, 0, (size_t)N2 * 4, stream);
    remap_fill_k<<<E0 / 256, 256, 0, stream>>>(cs1, cd1, ecnt, 0, newpos, rowoff, cur, cs2, cd2);

    // ================= GCN3 (N2 nodes) =================
    mmh_k<<<(N2 + 31) / 32, 256, 0, stream>>>(fC, W3, fA, N2);
    agg_k<<<(N2 * 64 + 255) / 256, 256, 0, stream>>>(fA, rowoff, cs2, dis, b3, p3, fB, score, N2);

    // ---- pool 3: K2 -> K3 per graph ----
    topk_k<<<B_, 1024, 0, stream>>>(score, K2, K3, selOld, newpos);
    gather_k<<<(N3 * H_ + 255) / 256, 256, 0, stream>>>(fB, score, selOld, fC, N3);
    readout_part_k<<<B_ * RS, 512, 0, stream>>>(fC, K3, part);
    readout_red_k<<<B_, 256, 0, stream>>>(part, K3, zsum);

    // ================= MLP head =================
    mlp_k<<<B_, 128, 0, stream>>>(zsum, lw1, lb1, z1, 256, 128, 0);
    mlp_k<<<B_, 64, 0, stream>>>(z1, lw2, lb2, z2, 128, 64, 0);
    mlp_k<<<B_, 128, 0, stream>>>(z2, lw3, lb3, (float*)d_out, 64, ACT, 1);
}

// Round 5
// 680.842 us; speedup vs baseline: 4.3194x; 1.1908x over previous
//
#include <hip/hip_runtime.h>
#include <math.h>

namespace {
constexpr int B_   = 64;
constexpr int NPG  = 2048;
constexpr int N0   = B_ * NPG;      // 131072
constexpr int E0   = N0 * 4;        // 524288
constexpr int H_   = 128;
constexpr int K1   = 1639, K2 = 1312, K3 = 1050;
constexpr int N1   = B_ * K1;       // 104896
constexpr int N2   = B_ * K2;       // 83968
constexpr int N3   = B_ * K3;       // 67200
constexpr int ACT  = 124;
constexpr int RS   = 32;            // readout segments per graph
}

// ---------- h = X[M,4] @ W[4,128] ----------
__global__ void mm4_k(const float* __restrict__ X, const float* __restrict__ W,
                      float* __restrict__ out, int M)
{
    __shared__ float sW[512];
    for (int i = threadIdx.x; i < 512; i += blockDim.x) sW[i] = W[i];
    __syncthreads();
    int gid = blockIdx.x * blockDim.x + threadIdx.x;
    int n = gid >> 7, c = gid & 127;
    if (n >= M) return;
    float4 xv = *(const float4*)(X + (size_t)n * 4);
    out[gid] = xv.x * sW[c] + xv.y * sW[128 + c] + xv.z * sW[256 + c] + xv.w * sW[384 + c];
}

// ---------- C[M,128] = A[M,128] @ W[128,128], fp32, LDS tiled ----------
__global__ __launch_bounds__(256) void mmh_k(const float* __restrict__ A,
                                             const float* __restrict__ W,
                                             float* __restrict__ C, int M)
{
    __shared__ float sW[128 * 128];
    __shared__ float sA[32 * 128];
    int tid = threadIdx.x;
    for (int i = tid * 4; i < 128 * 128; i += 1024)
        *(float4*)(sW + i) = *(const float4*)(W + i);
    int row0 = blockIdx.x * 32;
    for (int i = tid * 4; i < 32 * 128; i += 1024) {
        int r = row0 + (i >> 7);
        float4 v = make_float4(0.f, 0.f, 0.f, 0.f);
        if (r < M) v = *(const float4*)(A + (size_t)r * H_ + (i & 127));
        *(float4*)(sA + i) = v;
    }
    __syncthreads();
    int c4 = (tid & 31) * 4;
    int rg = tid >> 5;   // 0..7, 4 rows each
    float4 a0 = make_float4(0,0,0,0), a1 = a0, a2 = a0, a3 = a0;
    for (int kk = 0; kk < 128; ++kk) {
        float4 wv = *(const float4*)(sW + kk * 128 + c4);
        float x0 = sA[(rg * 4 + 0) * 128 + kk];
        float x1 = sA[(rg * 4 + 1) * 128 + kk];
        float x2 = sA[(rg * 4 + 2) * 128 + kk];
        float x3 = sA[(rg * 4 + 3) * 128 + kk];
        a0.x += x0 * wv.x; a0.y += x0 * wv.y; a0.z += x0 * wv.z; a0.w += x0 * wv.w;
        a1.x += x1 * wv.x; a1.y += x1 * wv.y; a1.z += x1 * wv.z; a1.w += x1 * wv.w;
        a2.x += x2 * wv.x; a2.y += x2 * wv.y; a2.z += x2 * wv.z; a2.w += x2 * wv.w;
        a3.x += x3 * wv.x; a3.y += x3 * wv.y; a3.z += x3 * wv.z; a3.w += x3 * wv.w;
    }
    int r = row0 + rg * 4;
    if (r + 0 < M) *(float4*)(C + (size_t)(r + 0) * H_ + c4) = a0;
    if (r + 1 < M) *(float4*)(C + (size_t)(r + 1) * H_ + c4) = a1;
    if (r + 2 < M) *(float4*)(C + (size_t)(r + 2) * H_ + c4) = a2;
    if (r + 3 < M) *(float4*)(C + (size_t)(r + 3) * H_ + c4) = a3;
}

// ---------- degree count (level 0) ----------
__global__ void count_deg_k(const int* __restrict__ dst, int E, int* __restrict__ deg)
{
    int e = blockIdx.x * blockDim.x + threadIdx.x;
    if (e < E) atomicAdd(deg + dst[e], 1);
}

__global__ void dis_k(const int* __restrict__ deg, float* __restrict__ dis, int n)
{
    int i = blockIdx.x * blockDim.x + threadIdx.x;
    if (i < n) dis[i] = 1.0f / sqrtf((float)deg[i] + 1.0f);
}

// ---------- exclusive scan (3-kernel) over deg[0..n-1] -> rowoff ----------
__global__ __launch_bounds__(1024) void scan1_k(const int* __restrict__ in, int* __restrict__ out,
                                                int* __restrict__ bsum, int n)
{
    __shared__ int s[1024];
    int t = threadIdx.x;
    int i = blockIdx.x * 1024 + t;
    int v = (i < n) ? in[i] : 0;
    s[t] = v;
    __syncthreads();
    for (int d = 1; d < 1024; d <<= 1) {
        int add = (t >= d) ? s[t - d] : 0;
        __syncthreads();
        s[t] += add;
        __syncthreads();
    }
    if (i < n) out[i] = s[t] - v;          // exclusive
    if (t == 1023) bsum[blockIdx.x] = s[1023];
}

__global__ void scan2_k(int* __restrict__ bsum, int nb)
{
    if (threadIdx.x == 0) {
        int acc = 0;
        for (int i = 0; i < nb; ++i) { int v = bsum[i]; bsum[i] = acc; acc += v; }
    }
}

__global__ void scan3_k(int* __restrict__ out, const int* __restrict__ bsum, int n)
{
    int i = blockIdx.x * blockDim.x + threadIdx.x;
    if (i < n) out[i] += bsum[i >> 10];
}

__global__ void copy1_k(int* __restrict__ dstp, const int* __restrict__ srcp)
{
    if (threadIdx.x == 0) *dstp = *srcp;
}

// ---------- level-0 counting-sort fill: bucket src ids by dst ----------
__global__ void fill_k(const int* __restrict__ src, const int* __restrict__ dst, int E,
                       const int* __restrict__ rowoff, int* __restrict__ cur,
                       int* __restrict__ esrc)
{
    int e = blockIdx.x * blockDim.x + threadIdx.x;
    if (e >= E) return;
    int d = dst[e];
    int pos = rowoff[d] + atomicAdd(cur + d, 1);
    esrc[pos] = src[e];
}

// ---------- remap pass A: count surviving-edge degrees (distributed atomics) ----------
__global__ void remap_count_k(const int* __restrict__ osrc, const int* __restrict__ odst,
                              const int* __restrict__ ecntIn, int fixedE,
                              const int* __restrict__ newpos, int* __restrict__ deg)
{
    int E = ecntIn ? *ecntIn : fixedE;
    int e = blockIdx.x * blockDim.x + threadIdx.x;
    if (e >= E) return;
    int ns = newpos[osrc[e]];
    int nd = newpos[odst[e]];
    if (ns >= 0 && nd >= 0) atomicAdd(deg + nd, 1);
}

// ---------- remap pass B: fill next-level CSR (+ compacted edge list) ----------
__global__ void remap_fill_k(const int* __restrict__ osrc, const int* __restrict__ odst,
                             const int* __restrict__ ecntIn, int fixedE,
                             const int* __restrict__ newpos, const int* __restrict__ rowoff,
                             int* __restrict__ cur,
                             int* __restrict__ esrc, int* __restrict__ edst)
{
    int E = ecntIn ? *ecntIn : fixedE;
    int e = blockIdx.x * blockDim.x + threadIdx.x;
    if (e >= E) return;
    int ns = newpos[osrc[e]];
    int nd = newpos[odst[e]];
    if (ns >= 0 && nd >= 0) {
        int pos = rowoff[nd] + atomicAdd(cur + nd, 1);
        esrc[pos] = ns;
        edst[pos] = nd;
    }
}

// ---------- fused gather-aggregate + self-loop + bias + relu + pooling score ----------
// one wave (64 lanes) per dst node, float2 per lane; rowoff has M+1 entries.
// XCD-swizzled: graph g's blocks pinned to XCD g%8 so its ~1MB h working set
// stays in that XCD's 4MB L2 (blockIdx%8 ~ XCD on gfx950; perf heuristic only).
__global__ __launch_bounds__(256) void agg_k(const float* __restrict__ Hf,
                                             const int* __restrict__ rowoff,
                                             const int* __restrict__ esrc,
                                             const float* __restrict__ dis,
                                             const float* __restrict__ bias,
                                             const float* __restrict__ p,
                                             float* __restrict__ out,
                                             float* __restrict__ score,
                                             int npg, int Gb)
{
    int pb = blockIdx.x;
    int x  = pb & 7;                    // target XCD
    int m  = pb >> 3;
    int g  = x + 8 * (m / Gb);          // graph
    int lb = m % Gb;                    // local block within graph
    int j  = lb * 4 + (threadIdx.x >> 6);
    if (j >= npg) return;
    int n = g * npg + j;
    int lane = threadIdx.x & 63;
    float dn = dis[n];
    int beg = rowoff[n];
    int end = rowoff[n + 1];
    float2 hv = ((const float2*)(Hf + (size_t)n * H_))[lane];
    float acc0 = hv.x * dn * dn + bias[lane * 2 + 0];
    float acc1 = hv.y * dn * dn + bias[lane * 2 + 1];
    for (int e = beg; e < end; ++e) {
        int s = esrc[e];
        float c = dis[s] * dn;
        float2 sv = ((const float2*)(Hf + (size_t)s * H_))[lane];
        acc0 += sv.x * c;
        acc1 += sv.y * c;
    }
    float o0 = fmaxf(acc0, 0.f);
    float o1 = fmaxf(acc1, 0.f);
    ((float2*)(out + (size_t)n * H_))[lane] = make_float2(o0, o1);
    // fused pooling score: tanh(dot(o, p) / ||p||)
    float p0 = p[lane * 2], p1 = p[lane * 2 + 1];
    float dt = o0 * p0 + o1 * p1;
    float nr = p0 * p0 + p1 * p1;
    for (int mm = 32; mm > 0; mm >>= 1) {
        dt += __shfl_xor(dt, mm);
        nr += __shfl_xor(nr, mm);
    }
    if (lane == 0) score[n] = tanhf(dt / sqrtf(nr));
}

// ---------- exact per-graph top-k via bitonic sort (desc, tie: low index) ----------
__global__ __launch_bounds__(1024) void topk_k(const float* __restrict__ score, int n, int k,
                                               int* __restrict__ selOld, int* __restrict__ newpos)
{
    __shared__ unsigned long long key[2048];
    int b = blockIdx.x;
    const float* s = score + (size_t)b * n;
    for (int i = threadIdx.x; i < 2048; i += 1024) {
        unsigned long long pk = 0ull;
        if (i < n) {
            unsigned u = __float_as_uint(s[i]);
            u = (u & 0x80000000u) ? ~u : (u | 0x80000000u);
            pk = ((unsigned long long)u << 32) | (unsigned)(65535 - i);
        }
        key[i] = pk;
    }
    __syncthreads();
    for (int sz = 2; sz <= 2048; sz <<= 1) {
        for (int st = sz >> 1; st > 0; st >>= 1) {
            for (int t = threadIdx.x; t < 2048; t += 1024) {
                int j = t ^ st;
                if (j > t) {
                    unsigned long long a = key[t], c = key[j];
                    bool desc = ((t & sz) == 0);
                    if ((a < c) == desc) { key[t] = c; key[j] = a; }
                }
            }
            __syncthreads();
        }
    }
    for (int j = threadIdx.x; j < k; j += 1024) {
        int o = 65535 - (int)(key[j] & 0xFFFFFFFFull);
        int oldg = b * n + o;
        selOld[b * k + j] = oldg;
        newpos[oldg] = b * k + j;
    }
}

// ---------- x_new[j] = x[sel[j]] * score[sel[j]] ----------
__global__ void gather_k(const float* __restrict__ X, const float* __restrict__ score,
                         const int* __restrict__ selOld, float* __restrict__ out, int Mnew)
{
    int gid = blockIdx.x * blockDim.x + threadIdx.x;
    if (gid >= Mnew * H_) return;
    int j = gid >> 7, f = gid & 127;
    int o = selOld[j];
    out[gid] = X[(size_t)o * H_ + f] * score[o];
}

// ---------- readout stage 1: per-(graph,segment) partial max/sum ----------
__global__ __launch_bounds__(512) void readout_part_k(const float* __restrict__ X, int kRows,
                                                      float* __restrict__ part)
{
    __shared__ float smax[4][128];
    __shared__ float ssum[4][128];
    int b = blockIdx.x / RS;
    int s = blockIdx.x % RS;
    int chunk = (kRows + RS - 1) / RS;
    int j0 = s * chunk;
    int j1 = min(kRows, j0 + chunk);
    int f = threadIdx.x & 127;
    int q = threadIdx.x >> 7;          // 4 row groups
    const float* base = X + (size_t)b * kRows * H_;
    float mx = -3.4e38f, sm = 0.f;
    for (int j = j0 + q; j < j1; j += 4) {
        float v = base[(size_t)j * H_ + f];
        mx = fmaxf(mx, v); sm += v;
    }
    smax[q][f] = mx; ssum[q][f] = sm;
    __syncthreads();
    if (q == 0) {
        mx = fmaxf(fmaxf(smax[0][f], smax[1][f]), fmaxf(smax[2][f], smax[3][f]));
        sm = ssum[0][f] + ssum[1][f] + ssum[2][f] + ssum[3][f];
        float* pr = part + ((size_t)b * RS + s) * 256;
        pr[f] = mx;
        pr[128 + f] = sm;
    }
}

// ---------- readout stage 2: fold RS partials into zsum ----------
__global__ __launch_bounds__(256) void readout_red_k(const float* __restrict__ part, int kRows,
                                                     float* __restrict__ zsum)
{
    int b = blockIdx.x;
    int f = threadIdx.x & 127;
    int half = threadIdx.x >> 7;       // 0: max, 1: sum
    const float* pr = part + (size_t)b * RS * 256;
    if (half == 0) {
        float mx = -3.4e38f;
        for (int s = 0; s < RS; ++s) mx = fmaxf(mx, pr[s * 256 + f]);
        zsum[b * 256 + f] += mx;
    } else {
        float sm = 0.f;
        for (int s = 0; s < RS; ++s) sm += pr[s * 256 + 128 + f];
        zsum[b * 256 + 128 + f] += sm * (1.0f / (float)kRows);
    }
}

// ---------- fused 3-layer MLP head, one block per graph ----------
// relu(z@lw1+lb1) -> relu(@lw2+lb2) -> sigmoid(@lw3+lb3)
// All loop bounds compile-time so weight loads fully pipeline.
__global__ __launch_bounds__(256) void head_k(const float* __restrict__ zsum,
                                              const float* __restrict__ lw1, const float* __restrict__ lb1,
                                              const float* __restrict__ lw2, const float* __restrict__ lb2,
                                              const float* __restrict__ lw3, const float* __restrict__ lb3,
                                              float* __restrict__ out)
{
    __shared__ float sZ[256];
    __shared__ float sZ1[128];
    __shared__ float sZ2[64];
    __shared__ float red[256];
    int b = blockIdx.x;
    int t = threadIdx.x;
    sZ[t] = zsum[b * 256 + t];
    __syncthreads();
    // layer 1: 256 -> 128, two threads per output
    {
        int c = t & 127, h = t >> 7;
        float acc = 0.f;
        #pragma unroll
        for (int i = 0; i < 128; ++i) {
            int ii = h * 128 + i;
            acc += sZ[ii] * lw1[ii * 128 + c];
        }
        red[t] = acc;
        __syncthreads();
        if (t < 128) sZ1[t] = fmaxf(red[t] + red[128 + t] + lb1[t], 0.f);
        __syncthreads();
    }
    // layer 2: 128 -> 64, four threads per output
    {
        int c = t & 63, q = t >> 6;
        float acc = 0.f;
        #pragma unroll
        for (int i = 0; i < 32; ++i) {
            int ii = q * 32 + i;
            acc += sZ1[ii] * lw2[ii * 64 + c];
        }
        red[t] = acc;
        __syncthreads();
        if (t < 64) sZ2[t] = fmaxf(red[t] + red[64 + t] + red[128 + t] + red[192 + t] + lb2[t], 0.f);
        __syncthreads();
    }
    // layer 3: 64 -> 124, two threads per output, sigmoid
    {
        if (t < 2 * ACT) {
            int c = t >> 1, h = t & 1;
            float acc = 0.f;
            #pragma unroll
            for (int i = 0; i < 32; ++i) {
                int ii = h * 32 + i;
                acc += sZ2[ii] * lw3[ii * ACT + c];
            }
            red[t] = acc;
        }
        __syncthreads();
        if (t < ACT) {
            float s = red[2 * t] + red[2 * t + 1] + lb3[t];
            out[b * ACT + t] = 1.f / (1.f + expf(-s));
        }
    }
}

extern "C" void kernel_launch(void* const* d_in, const int* in_sizes, int n_in,
                              void* d_out, int out_size, void* d_ws, size_t ws_size,
                              hipStream_t stream)
{
    const float* x   = (const float*)d_in[0];
    const int*   src = (const int*)d_in[1];
    const int*   dst = (const int*)d_in[2];
    const float* W1  = (const float*)d_in[3];
    const float* b1  = (const float*)d_in[4];
    const float* W2  = (const float*)d_in[5];
    const float* b2  = (const float*)d_in[6];
    const float* W3  = (const float*)d_in[7];
    const float* b3  = (const float*)d_in[8];
    const float* p1  = (const float*)d_in[9];
    const float* p2  = (const float*)d_in[10];
    const float* p3  = (const float*)d_in[11];
    const float* lw1 = (const float*)d_in[12];
    const float* lb1 = (const float*)d_in[13];
    const float* lw2 = (const float*)d_in[14];
    const float* lb2 = (const float*)d_in[15];
    const float* lw3 = (const float*)d_in[16];
    const float* lb3 = (const float*)d_in[17];

    char* w = (char*)d_ws;
    size_t off = 0;
    auto alloc = [&](size_t bytes) -> void* {
        void* p = w + off;
        off = (off + bytes + 255) & ~(size_t)255;
        return p;
    };
    float* fA     = (float*)alloc((size_t)N0 * H_ * 4);   // h = X@W
    float* fB     = (float*)alloc((size_t)N0 * H_ * 4);   // gcn output activations
    float* fC     = (float*)alloc((size_t)N1 * H_ * 4);   // pooled features
    float* score  = (float*)alloc((size_t)N0 * 4);
    int*   newpos = (int*)  alloc((size_t)N0 * 4);
    int*   deg    = (int*)  alloc((size_t)(N0 + 1) * 4);
    float* dis    = (float*)alloc((size_t)N0 * 4);
    int*   selOld = (int*)  alloc((size_t)N1 * 4);
    int*   rowoff = (int*)  alloc((size_t)(N0 + 1) * 4);
    int*   cur    = (int*)  alloc((size_t)N0 * 4);
    int*   bsum   = (int*)  alloc((size_t)1024 * 4);
    int*   cs0    = (int*)  alloc((size_t)E0 * 4);        // level-0 CSR src
    int*   cs1    = (int*)  alloc((size_t)E0 * 4);        // level-1 CSR src
    int*   cd1    = (int*)  alloc((size_t)E0 * 4);        // level-1 edge dst list
    int*   cs2    = (int*)  alloc((size_t)E0 * 4);        // level-2 CSR src
    int*   cd2    = (int*)  alloc((size_t)E0 * 4);        // level-2 edge dst list
    float* part   = (float*)alloc((size_t)B_ * RS * 256 * 4);
    float* zsum   = (float*)alloc((size_t)B_ * 256 * 4);
    int*   ecnt   = (int*)  alloc(256);                   // [0] = E1 (level-1 edge count)

    hipMemsetAsync(zsum, 0, (size_t)B_ * 256 * 4, stream);

    auto scan_rowoff = [&](int nNodes) {   // exclusive scan over deg[0..nNodes] (nNodes+1 entries)
        int n = nNodes + 1;
        int nb = (n + 1023) / 1024;
        scan1_k<<<nb, 1024, 0, stream>>>(deg, rowoff, bsum, n);
        scan2_k<<<1, 64, 0, stream>>>(bsum, nb);
        scan3_k<<<(n + 255) / 256, 256, 0, stream>>>(rowoff, bsum, n);
    };

    // blocks per graph (4 nodes/block) for agg_k swizzled launch
    const int Gb0 = (NPG + 3) / 4;     // 512
    const int Gb1 = (K1 + 3) / 4;      // 410
    const int Gb2 = (K2 + 3) / 4;      // 328

    // ================= GCN1 (level-0 graph: N0 nodes, E0 edges) =================
    hipMemsetAsync(deg, 0, (size_t)(N0 + 1) * 4, stream);
    mm4_k<<<(N0 * H_) / 256, 256, 0, stream>>>(x, W1, fA, N0);
    count_deg_k<<<E0 / 256, 256, 0, stream>>>(dst, E0, deg);
    dis_k<<<(N0 + 255) / 256, 256, 0, stream>>>(deg, dis, N0);
    scan_rowoff(N0);
    hipMemsetAsync(cur, 0, (size_t)N0 * 4, stream);
    fill_k<<<E0 / 256, 256, 0, stream>>>(src, dst, E0, rowoff, cur, cs0);
    agg_k<<<B_ * Gb0, 256, 0, stream>>>(fA, rowoff, cs0, dis, b1, p1, fB, score, NPG, Gb0);

    // ---- pool 1: 2048 -> K1 per graph ----
    hipMemsetAsync(newpos, 0xFF, (size_t)N0 * 4, stream);
    topk_k<<<B_, 1024, 0, stream>>>(score, NPG, K1, selOld, newpos);
    gather_k<<<(N1 * H_ + 255) / 256, 256, 0, stream>>>(fB, score, selOld, fC, N1);
    readout_part_k<<<B_ * RS, 512, 0, stream>>>(fC, K1, part);
    readout_red_k<<<B_, 256, 0, stream>>>(part, K1, zsum);

    // ---- build level-1 CSR directly from (src,dst) + newpos ----
    hipMemsetAsync(deg, 0, (size_t)(N1 + 1) * 4, stream);
    remap_count_k<<<E0 / 256, 256, 0, stream>>>(src, dst, nullptr, E0, newpos, deg);
    dis_k<<<(N1 + 255) / 256, 256, 0, stream>>>(deg, dis, N1);
    scan_rowoff(N1);
    copy1_k<<<1, 64, 0, stream>>>(ecnt, rowoff + N1);     // E1 for level-2 remap bound
    hipMemsetAsync(cur, 0, (size_t)N1 * 4, stream);
    remap_fill_k<<<E0 / 256, 256, 0, stream>>>(src, dst, nullptr, E0, newpos, rowoff, cur, cs1, cd1);

    // ================= GCN2 (N1 nodes) =================
    mmh_k<<<(N1 + 31) / 32, 256, 0, stream>>>(fC, W2, fA, N1);
    agg_k<<<B_ * Gb1, 256, 0, stream>>>(fA, rowoff, cs1, dis, b2, p2, fB, score, K1, Gb1);

    // ---- pool 2: K1 -> K2 per graph ----
    hipMemsetAsync(newpos, 0xFF, (size_t)N1 * 4, stream);
    topk_k<<<B_, 1024, 0, stream>>>(score, K1, K2, selOld, newpos);
    gather_k<<<(N2 * H_ + 255) / 256, 256, 0, stream>>>(fB, score, selOld, fC, N2);
    readout_part_k<<<B_ * RS, 512, 0, stream>>>(fC, K2, part);
    readout_red_k<<<B_, 256, 0, stream>>>(part, K2, zsum);

    // ---- build level-2 CSR from (cs1,cd1) + newpos ----
    hipMemsetAsync(deg, 0, (size_t)(N2 + 1) * 4, stream);
    remap_count_k<<<E0 / 256, 256, 0, stream>>>(cs1, cd1, ecnt, 0, newpos, deg);
    dis_k<<<(N2 + 255) / 256, 256, 0, stream>>>(deg, dis, N2);
    scan_rowoff(N2);
    hipMemsetAsync(cur, 0, (size_t)N2 * 4, stream);
    remap_fill_k<<<E0 / 256, 256, 0, stream>>>(cs1, cd1, ecnt, 0, newpos, rowoff, cur, cs2, cd2);

    // ================= GCN3 (N2 nodes) =================
    mmh_k<<<(N2 + 31) / 32, 256, 0, stream>>>(fC, W3, fA, N2);
    agg_k<<<B_ * Gb2, 256, 0, stream>>>(fA, rowoff, cs2, dis, b3, p3, fB, score, K2, Gb2);

    // ---- pool 3: K2 -> K3 per graph ----
    topk_k<<<B_, 1024, 0, stream>>>(score, K2, K3, selOld, newpos);
    gather_k<<<(N3 * H_ + 255) / 256, 256, 0, stream>>>(fB, score, selOld, fC, N3);
    readout_part_k<<<B_ * RS, 512, 0, stream>>>(fC, K3, part);
    readout_red_k<<<B_, 256, 0, stream>>>(part, K3, zsum);

    // ================= fused MLP head =================
    head_k<<<B_, 256, 0, stream>>>(zsum, lw1, lb1, lw2, lb2, lw3, lb3, (float*)d_out);
}

// Round 6
// 613.922 us; speedup vs baseline: 4.7902x; 1.1090x over previous
//
#include <hip/hip_runtime.h>
#include <math.h>

namespace {
constexpr int B_   = 64;
constexpr int NPG  = 2048;
constexpr int N0   = B_ * NPG;      // 131072
constexpr int E0   = N0 * 4;        // 524288
constexpr int H_   = 128;
constexpr int K1   = 1639, K2 = 1312, K3 = 1050;
constexpr int N1   = B_ * K1;       // 104896
constexpr int N2   = B_ * K2;       // 83968
constexpr int N3   = B_ * K3;       // 67200
constexpr int ACT  = 124;
constexpr int RS   = 32;            // readout segments per graph
}

// ---------- h = X[M,4] @ W[4,128] ----------
__global__ void mm4_k(const float* __restrict__ X, const float* __restrict__ W,
                      float* __restrict__ out, int M)
{
    __shared__ float sW[512];
    for (int i = threadIdx.x; i < 512; i += blockDim.x) sW[i] = W[i];
    __syncthreads();
    int gid = blockIdx.x * blockDim.x + threadIdx.x;
    int n = gid >> 7, c = gid & 127;
    if (n >= M) return;
    float4 xv = *(const float4*)(X + (size_t)n * 4);
    out[gid] = xv.x * sW[c] + xv.y * sW[128 + c] + xv.z * sW[256 + c] + xv.w * sW[384 + c];
}

// ---------- C[r,:] = (Xin[selOld[r],:]*score[selOld[r]]) @ W[128,128] ----------
// register-tiled: 64 rows/block, A-tile in LDS (32KB), W streamed from L1/L2.
// M must be a multiple of 64 (N1, N2 are).
__global__ __launch_bounds__(256) void mmh_k(const float* __restrict__ Xin,
                                             const int* __restrict__ selOld,
                                             const float* __restrict__ score,
                                             const float* __restrict__ W,
                                             float* __restrict__ C, int M)
{
    __shared__ float sA[64 * 128];   // 32 KB
    int tid = threadIdx.x;
    int row0 = blockIdx.x * 64;
    #pragma unroll
    for (int ch = 0; ch < 8; ++ch) {
        int i = ch * 1024 + tid * 4;
        int r = i >> 7, c = i & 127;
        int g = selOld[row0 + r];
        float sc = score[g];
        float4 v = *(const float4*)(Xin + (size_t)g * H_ + c);
        v.x *= sc; v.y *= sc; v.z *= sc; v.w *= sc;
        *(float4*)(sA + i) = v;
    }
    __syncthreads();
    int c4 = (tid & 31) * 4;
    int rg = tid >> 5;               // 0..7 -> rows rg*8 .. rg*8+7
    float4 acc[8];
    #pragma unroll
    for (int q = 0; q < 8; ++q) acc[q] = make_float4(0.f, 0.f, 0.f, 0.f);
    #pragma unroll 2
    for (int kk = 0; kk < 128; ++kk) {
        float4 wv = *(const float4*)(W + kk * 128 + c4);
        #pragma unroll
        for (int q = 0; q < 8; ++q) {
            float a = sA[(rg * 8 + q) * 128 + kk];
            acc[q].x += a * wv.x; acc[q].y += a * wv.y;
            acc[q].z += a * wv.z; acc[q].w += a * wv.w;
        }
    }
    #pragma unroll
    for (int q = 0; q < 8; ++q) {
        int r = row0 + rg * 8 + q;
        *(float4*)(C + (size_t)r * H_ + c4) = acc[q];
    }
}

// ---------- degree count (level 0) ----------
__global__ void count_deg_k(const int* __restrict__ dst, int E, int* __restrict__ deg)
{
    int e = blockIdx.x * blockDim.x + threadIdx.x;
    if (e < E) atomicAdd(deg + dst[e], 1);
}

__global__ void dis_k(const int* __restrict__ deg, float* __restrict__ dis, int n)
{
    int i = blockIdx.x * blockDim.x + threadIdx.x;
    if (i < n) dis[i] = 1.0f / sqrtf((float)deg[i] + 1.0f);
}

// ---------- exclusive scan (3-kernel) over deg[0..n-1] -> rowoff ----------
__global__ __launch_bounds__(1024) void scan1_k(const int* __restrict__ in, int* __restrict__ out,
                                                int* __restrict__ bsum, int n)
{
    __shared__ int s[1024];
    int t = threadIdx.x;
    int i = blockIdx.x * 1024 + t;
    int v = (i < n) ? in[i] : 0;
    s[t] = v;
    __syncthreads();
    for (int d = 1; d < 1024; d <<= 1) {
        int add = (t >= d) ? s[t - d] : 0;
        __syncthreads();
        s[t] += add;
        __syncthreads();
    }
    if (i < n) out[i] = s[t] - v;          // exclusive
    if (t == 1023) bsum[blockIdx.x] = s[1023];
}

__global__ void scan2_k(int* __restrict__ bsum, int nb)
{
    if (threadIdx.x == 0) {
        int acc = 0;
        for (int i = 0; i < nb; ++i) { int v = bsum[i]; bsum[i] = acc; acc += v; }
    }
}

__global__ void scan3_k(int* __restrict__ out, const int* __restrict__ bsum, int n)
{
    int i = blockIdx.x * blockDim.x + threadIdx.x;
    if (i < n) out[i] += bsum[i >> 10];
}

__global__ void copy1_k(int* __restrict__ dstp, const int* __restrict__ srcp)
{
    if (threadIdx.x == 0) *dstp = *srcp;
}

// ---------- level-0 counting-sort fill: bucket src ids by dst ----------
__global__ void fill_k(const int* __restrict__ src, const int* __restrict__ dst, int E,
                       const int* __restrict__ rowoff, int* __restrict__ cur,
                       int* __restrict__ esrc)
{
    int e = blockIdx.x * blockDim.x + threadIdx.x;
    if (e >= E) return;
    int d = dst[e];
    int pos = rowoff[d] + atomicAdd(cur + d, 1);
    esrc[pos] = src[e];
}

// ---------- remap pass A: count surviving-edge degrees (distributed atomics) ----------
__global__ void remap_count_k(const int* __restrict__ osrc, const int* __restrict__ odst,
                              const int* __restrict__ ecntIn, int fixedE,
                              const int* __restrict__ newpos, int* __restrict__ deg)
{
    int E = ecntIn ? *ecntIn : fixedE;
    int e = blockIdx.x * blockDim.x + threadIdx.x;
    if (e >= E) return;
    int ns = newpos[osrc[e]];
    int nd = newpos[odst[e]];
    if (ns >= 0 && nd >= 0) atomicAdd(deg + nd, 1);
}

// ---------- remap pass B: fill next-level CSR (+ compacted edge list) ----------
__global__ void remap_fill_k(const int* __restrict__ osrc, const int* __restrict__ odst,
                             const int* __restrict__ ecntIn, int fixedE,
                             const int* __restrict__ newpos, const int* __restrict__ rowoff,
                             int* __restrict__ cur,
                             int* __restrict__ esrc, int* __restrict__ edst)
{
    int E = ecntIn ? *ecntIn : fixedE;
    int e = blockIdx.x * blockDim.x + threadIdx.x;
    if (e >= E) return;
    int ns = newpos[osrc[e]];
    int nd = newpos[odst[e]];
    if (ns >= 0 && nd >= 0) {
        int pos = rowoff[nd] + atomicAdd(cur + nd, 1);
        esrc[pos] = ns;
        edst[pos] = nd;
    }
}

// ---------- fused gather-aggregate + self-loop + bias + relu + pooling score ----------
// one wave per dst node; 4-wide unrolled edge loop for load-latency overlap.
// XCD-swizzled: graph g's blocks pinned to XCD g%8 so its ~1MB h working set
// stays in that XCD's 4MB L2.
__global__ __launch_bounds__(256) void agg_k(const float* __restrict__ Hf,
                                             const int* __restrict__ rowoff,
                                             const int* __restrict__ esrc,
                                             const float* __restrict__ dis,
                                             const float* __restrict__ bias,
                                             const float* __restrict__ p,
                                             float* __restrict__ out,
                                             float* __restrict__ score,
                                             int npg, int Gb)
{
    int pb = blockIdx.x;
    int x  = pb & 7;                    // target XCD
    int m  = pb >> 3;
    int g  = x + 8 * (m / Gb);          // graph
    int lb = m % Gb;                    // local block within graph
    int j  = lb * 4 + (threadIdx.x >> 6);
    if (j >= npg) return;
    int n = g * npg + j;
    int lane = threadIdx.x & 63;
    float dn = dis[n];
    int beg = rowoff[n];
    int end = rowoff[n + 1];
    float2 hv = ((const float2*)(Hf + (size_t)n * H_))[lane];
    float acc0 = hv.x * dn * dn + bias[lane * 2 + 0];
    float acc1 = hv.y * dn * dn + bias[lane * 2 + 1];
    int e = beg;
    while (e + 4 <= end) {
        int s0 = esrc[e], s1 = esrc[e + 1], s2 = esrc[e + 2], s3 = esrc[e + 3];
        float c0 = dis[s0] * dn, c1 = dis[s1] * dn, c2 = dis[s2] * dn, c3 = dis[s3] * dn;
        float2 v0 = ((const float2*)(Hf + (size_t)s0 * H_))[lane];
        float2 v1 = ((const float2*)(Hf + (size_t)s1 * H_))[lane];
        float2 v2 = ((const float2*)(Hf + (size_t)s2 * H_))[lane];
        float2 v3 = ((const float2*)(Hf + (size_t)s3 * H_))[lane];
        acc0 += v0.x * c0; acc1 += v0.y * c0;
        acc0 += v1.x * c1; acc1 += v1.y * c1;
        acc0 += v2.x * c2; acc1 += v2.y * c2;
        acc0 += v3.x * c3; acc1 += v3.y * c3;
        e += 4;
    }
    while (e < end) {
        int s = esrc[e];
        float c = dis[s] * dn;
        float2 sv = ((const float2*)(Hf + (size_t)s * H_))[lane];
        acc0 += sv.x * c;
        acc1 += sv.y * c;
        ++e;
    }
    float o0 = fmaxf(acc0, 0.f);
    float o1 = fmaxf(acc1, 0.f);
    ((float2*)(out + (size_t)n * H_))[lane] = make_float2(o0, o1);
    // fused pooling score: tanh(dot(o, p) / ||p||)
    float p0 = p[lane * 2], p1 = p[lane * 2 + 1];
    float dt = o0 * p0 + o1 * p1;
    float nr = p0 * p0 + p1 * p1;
    for (int mm = 32; mm > 0; mm >>= 1) {
        dt += __shfl_xor(dt, mm);
        nr += __shfl_xor(nr, mm);
    }
    if (lane == 0) score[n] = tanhf(dt / sqrtf(nr));
}

// ---------- exact per-graph top-k via bitonic sort (desc, tie: low index) ----------
__global__ __launch_bounds__(1024) void topk_k(const float* __restrict__ score, int n, int k,
                                               int* __restrict__ selOld, int* __restrict__ newpos)
{
    __shared__ unsigned long long key[2048];
    int b = blockIdx.x;
    const float* s = score + (size_t)b * n;
    for (int i = threadIdx.x; i < 2048; i += 1024) {
        unsigned long long pk = 0ull;
        if (i < n) {
            unsigned u = __float_as_uint(s[i]);
            u = (u & 0x80000000u) ? ~u : (u | 0x80000000u);
            pk = ((unsigned long long)u << 32) | (unsigned)(65535 - i);
        }
        key[i] = pk;
    }
    __syncthreads();
    for (int sz = 2; sz <= 2048; sz <<= 1) {
        for (int st = sz >> 1; st > 0; st >>= 1) {
            for (int t = threadIdx.x; t < 2048; t += 1024) {
                int j = t ^ st;
                if (j > t) {
                    unsigned long long a = key[t], c = key[j];
                    bool desc = ((t & sz) == 0);
                    if ((a < c) == desc) { key[t] = c; key[j] = a; }
                }
            }
            __syncthreads();
        }
    }
    for (int j = threadIdx.x; j < k; j += 1024) {
        int o = 65535 - (int)(key[j] & 0xFFFFFFFFull);
        int oldg = b * n + o;
        selOld[b * k + j] = oldg;
        newpos[oldg] = b * k + j;
    }
}

// ---------- readout stage 1: per-(graph,segment) partial max/sum over gathered rows ----------
__global__ __launch_bounds__(512) void readout_part_k(const float* __restrict__ X,
                                                      const int* __restrict__ selOld,
                                                      const float* __restrict__ score,
                                                      int kRows, float* __restrict__ part)
{
    __shared__ float smax[4][128];
    __shared__ float ssum[4][128];
    int b = blockIdx.x / RS;
    int s = blockIdx.x % RS;
    int chunk = (kRows + RS - 1) / RS;
    int j0 = s * chunk;
    int j1 = min(kRows, j0 + chunk);
    int f = threadIdx.x & 127;
    int q = threadIdx.x >> 7;          // 4 row groups
    float mx = -3.4e38f, sm = 0.f;
    for (int j = j0 + q; j < j1; j += 4) {
        int g = selOld[b * kRows + j];
        float v = X[(size_t)g * H_ + f] * score[g];
        mx = fmaxf(mx, v); sm += v;
    }
    smax[q][f] = mx; ssum[q][f] = sm;
    __syncthreads();
    if (q == 0) {
        mx = fmaxf(fmaxf(smax[0][f], smax[1][f]), fmaxf(smax[2][f], smax[3][f]));
        sm = ssum[0][f] + ssum[1][f] + ssum[2][f] + ssum[3][f];
        float* pr = part + ((size_t)b * RS + s) * 256;
        pr[f] = mx;
        pr[128 + f] = sm;
    }
}

// ---------- readout stage 2: fold RS partials into zsum ----------
__global__ __launch_bounds__(256) void readout_red_k(const float* __restrict__ part, int kRows,
                                                     float* __restrict__ zsum)
{
    int b = blockIdx.x;
    int f = threadIdx.x & 127;
    int half = threadIdx.x >> 7;       // 0: max, 1: sum
    const float* pr = part + (size_t)b * RS * 256;
    if (half == 0) {
        float mx = -3.4e38f;
        for (int s = 0; s < RS; ++s) mx = fmaxf(mx, pr[s * 256 + f]);
        zsum[b * 256 + f] += mx;
    } else {
        float sm = 0.f;
        for (int s = 0; s < RS; ++s) sm += pr[s * 256 + 128 + f];
        zsum[b * 256 + 128 + f] += sm * (1.0f / (float)kRows);
    }
}

// ---------- fused 3-layer MLP head, one block per graph ----------
__global__ __launch_bounds__(256) void head_k(const float* __restrict__ zsum,
                                              const float* __restrict__ lw1, const float* __restrict__ lb1,
                                              const float* __restrict__ lw2, const float* __restrict__ lb2,
                                              const float* __restrict__ lw3, const float* __restrict__ lb3,
                                              float* __restrict__ out)
{
    __shared__ float sZ[256];
    __shared__ float sZ1[128];
    __shared__ float sZ2[64];
    __shared__ float red[256];
    int b = blockIdx.x;
    int t = threadIdx.x;
    sZ[t] = zsum[b * 256 + t];
    __syncthreads();
    // layer 1: 256 -> 128, two threads per output
    {
        int c = t & 127, h = t >> 7;
        float acc = 0.f;
        #pragma unroll
        for (int i = 0; i < 128; ++i) {
            int ii = h * 128 + i;
            acc += sZ[ii] * lw1[ii * 128 + c];
        }
        red[t] = acc;
        __syncthreads();
        if (t < 128) sZ1[t] = fmaxf(red[t] + red[128 + t] + lb1[t], 0.f);
        __syncthreads();
    }
    // layer 2: 128 -> 64, four threads per output
    {
        int c = t & 63, q = t >> 6;
        float acc = 0.f;
        #pragma unroll
        for (int i = 0; i < 32; ++i) {
            int ii = q * 32 + i;
            acc += sZ1[ii] * lw2[ii * 64 + c];
        }
        red[t] = acc;
        __syncthreads();
        if (t < 64) sZ2[t] = fmaxf(red[t] + red[64 + t] + red[128 + t] + red[192 + t] + lb2[t], 0.f);
        __syncthreads();
    }
    // layer 3: 64 -> 124, two threads per output, sigmoid
    {
        if (t < 2 * ACT) {
            int c = t >> 1, h = t & 1;
            float acc = 0.f;
            #pragma unroll
            for (int i = 0; i < 32; ++i) {
                int ii = h * 32 + i;
                acc += sZ2[ii] * lw3[ii * ACT + c];
            }
            red[t] = acc;
        }
        __syncthreads();
        if (t < ACT) {
            float s = red[2 * t] + red[2 * t + 1] + lb3[t];
            out[b * ACT + t] = 1.f / (1.f + expf(-s));
        }
    }
}

extern "C" void kernel_launch(void* const* d_in, const int* in_sizes, int n_in,
                              void* d_out, int out_size, void* d_ws, size_t ws_size,
                              hipStream_t stream)
{
    const float* x   = (const float*)d_in[0];
    const int*   src = (const int*)d_in[1];
    const int*   dst = (const int*)d_in[2];
    const float* W1  = (const float*)d_in[3];
    const float* b1  = (const float*)d_in[4];
    const float* W2  = (const float*)d_in[5];
    const float* b2  = (const float*)d_in[6];
    const float* W3  = (const float*)d_in[7];
    const float* b3  = (const float*)d_in[8];
    const float* p1  = (const float*)d_in[9];
    const float* p2  = (const float*)d_in[10];
    const float* p3  = (const float*)d_in[11];
    const float* lw1 = (const float*)d_in[12];
    const float* lb1 = (const float*)d_in[13];
    const float* lw2 = (const float*)d_in[14];
    const float* lb2 = (const float*)d_in[15];
    const float* lw3 = (const float*)d_in[16];
    const float* lb3 = (const float*)d_in[17];

    char* w = (char*)d_ws;
    size_t off = 0;
    auto alloc = [&](size_t bytes) -> void* {
        void* p = w + off;
        off = (off + bytes + 255) & ~(size_t)255;
        return p;
    };
    float* fA     = (float*)alloc((size_t)N0 * H_ * 4);   // h = X@W (pre-aggregate)
    float* fB     = (float*)alloc((size_t)N0 * H_ * 4);   // gcn output activations
    float* score  = (float*)alloc((size_t)N0 * 4);
    int*   newpos = (int*)  alloc((size_t)N0 * 4);
    int*   deg    = (int*)  alloc((size_t)(N0 + 1) * 4);
    float* dis    = (float*)alloc((size_t)N0 * 4);
    int*   selOld = (int*)  alloc((size_t)N1 * 4);
    int*   rowoff = (int*)  alloc((size_t)(N0 + 1) * 4);
    int*   cur    = (int*)  alloc((size_t)N0 * 4);
    int*   bsum   = (int*)  alloc((size_t)1024 * 4);
    int*   cs0    = (int*)  alloc((size_t)E0 * 4);        // level-0 CSR src
    int*   cs1    = (int*)  alloc((size_t)E0 * 4);        // level-1 CSR src
    int*   cd1    = (int*)  alloc((size_t)E0 * 4);        // level-1 edge dst list
    int*   cs2    = (int*)  alloc((size_t)E0 * 4);        // level-2 CSR src
    int*   cd2    = (int*)  alloc((size_t)E0 * 4);        // level-2 edge dst list
    float* part   = (float*)alloc((size_t)B_ * RS * 256 * 4);
    float* zsum   = (float*)alloc((size_t)B_ * 256 * 4);
    int*   ecnt   = (int*)  alloc(256);                   // [0] = E1 (level-1 edge count)

    hipMemsetAsync(zsum, 0, (size_t)B_ * 256 * 4, stream);

    auto scan_rowoff = [&](int nNodes) {   // exclusive scan over deg[0..nNodes] (nNodes+1 entries)
        int n = nNodes + 1;
        int nb = (n + 1023) / 1024;
        scan1_k<<<nb, 1024, 0, stream>>>(deg, rowoff, bsum, n);
        scan2_k<<<1, 64, 0, stream>>>(bsum, nb);
        scan3_k<<<(n + 255) / 256, 256, 0, stream>>>(rowoff, bsum, n);
    };

    // blocks per graph (4 nodes/block) for agg_k swizzled launch
    const int Gb0 = (NPG + 3) / 4;     // 512
    const int Gb1 = (K1 + 3) / 4;      // 410
    const int Gb2 = (K2 + 3) / 4;      // 328

    // ================= GCN1 (level-0 graph: N0 nodes, E0 edges) =================
    hipMemsetAsync(deg, 0, (size_t)(N0 + 1) * 4, stream);
    mm4_k<<<(N0 * H_) / 256, 256, 0, stream>>>(x, W1, fA, N0);
    count_deg_k<<<E0 / 256, 256, 0, stream>>>(dst, E0, deg);
    dis_k<<<(N0 + 255) / 256, 256, 0, stream>>>(deg, dis, N0);
    scan_rowoff(N0);
    hipMemsetAsync(cur, 0, (size_t)N0 * 4, stream);
    fill_k<<<E0 / 256, 256, 0, stream>>>(src, dst, E0, rowoff, cur, cs0);
    agg_k<<<B_ * Gb0, 256, 0, stream>>>(fA, rowoff, cs0, dis, b1, p1, fB, score, NPG, Gb0);

    // ---- pool 1: 2048 -> K1 per graph ----
    hipMemsetAsync(newpos, 0xFF, (size_t)N0 * 4, stream);
    topk_k<<<B_, 1024, 0, stream>>>(score, NPG, K1, selOld, newpos);
    readout_part_k<<<B_ * RS, 512, 0, stream>>>(fB, selOld, score, K1, part);
    readout_red_k<<<B_, 256, 0, stream>>>(part, K1, zsum);

    // ---- build level-1 CSR directly from (src,dst) + newpos ----
    hipMemsetAsync(deg, 0, (size_t)(N1 + 1) * 4, stream);
    remap_count_k<<<E0 / 256, 256, 0, stream>>>(src, dst, nullptr, E0, newpos, deg);
    dis_k<<<(N1 + 255) / 256, 256, 0, stream>>>(deg, dis, N1);
    scan_rowoff(N1);
    copy1_k<<<1, 64, 0, stream>>>(ecnt, rowoff + N1);     // E1 for level-2 remap bound
    hipMemsetAsync(cur, 0, (size_t)N1 * 4, stream);
    remap_fill_k<<<E0 / 256, 256, 0, stream>>>(src, dst, nullptr, E0, newpos, rowoff, cur, cs1, cd1);

    // ================= GCN2 (N1 nodes) =================
    mmh_k<<<N1 / 64, 256, 0, stream>>>(fB, selOld, score, W2, fA, N1);
    agg_k<<<B_ * Gb1, 256, 0, stream>>>(fA, rowoff, cs1, dis, b2, p2, fB, score, K1, Gb1);

    // ---- pool 2: K1 -> K2 per graph ----
    hipMemsetAsync(newpos, 0xFF, (size_t)N1 * 4, stream);
    topk_k<<<B_, 1024, 0, stream>>>(score, K1, K2, selOld, newpos);
    readout_part_k<<<B_ * RS, 512, 0, stream>>>(fB, selOld, score, K2, part);
    readout_red_k<<<B_, 256, 0, stream>>>(part, K2, zsum);

    // ---- build level-2 CSR from (cs1,cd1) + newpos ----
    hipMemsetAsync(deg, 0, (size_t)(N2 + 1) * 4, stream);
    remap_count_k<<<E0 / 256, 256, 0, stream>>>(cs1, cd1, ecnt, 0, newpos, deg);
    dis_k<<<(N2 + 255) / 256, 256, 0, stream>>>(deg, dis, N2);
    scan_rowoff(N2);
    hipMemsetAsync(cur, 0, (size_t)N2 * 4, stream);
    remap_fill_k<<<E0 / 256, 256, 0, stream>>>(cs1, cd1, ecnt, 0, newpos, rowoff, cur, cs2, cd2);

    // ================= GCN3 (N2 nodes) =================
    mmh_k<<<N2 / 64, 256, 0, stream>>>(fB, selOld, score, W3, fA, N2);
    agg_k<<<B_ * Gb2, 256, 0, stream>>>(fA, rowoff, cs2, dis, b3, p3, fB, score, K2, Gb2);

    // ---- pool 3: K2 -> K3 per graph ----
    topk_k<<<B_, 1024, 0, stream>>>(score, K2, K3, selOld, newpos);
    readout_part_k<<<B_ * RS, 512, 0, stream>>>(fB, selOld, score, K3, part);
    readout_red_k<<<B_, 256, 0, stream>>>(part, K3, zsum);

    // ================= fused MLP head =================
    head_k<<<B_, 256, 0, stream>>>(zsum, lw1, lb1, lw2, lb2, lw3, lb3, (float*)d_out);
}

// Round 7
// 582.978 us; speedup vs baseline: 5.0445x; 1.0531x over previous
//
#include <hip/hip_runtime.h>
#include <math.h>

namespace {
constexpr int B_   = 64;
constexpr int NPG  = 2048;
constexpr int N0   = B_ * NPG;      // 131072
constexpr int E0   = N0 * 4;        // 524288
constexpr int H_   = 128;
constexpr int K1   = 1639, K2 = 1312, K3 = 1050;
constexpr int N1   = B_ * K1;       // 104896
constexpr int N2   = B_ * K2;       // 83968
constexpr int N3   = B_ * K3;       // 67200
constexpr int ACT  = 124;
constexpr int RS   = 32;            // readout segments per graph
}

// ---------- h = X[M,4] @ W[4,128] ----------
__global__ void mm4_k(const float* __restrict__ X, const float* __restrict__ W,
                      float* __restrict__ out, int M)
{
    __shared__ float sW[512];
    for (int i = threadIdx.x; i < 512; i += blockDim.x) sW[i] = W[i];
    __syncthreads();
    int gid = blockIdx.x * blockDim.x + threadIdx.x;
    int n = gid >> 7, c = gid & 127;
    if (n >= M) return;
    float4 xv = *(const float4*)(X + (size_t)n * 4);
    out[gid] = xv.x * sW[c] + xv.y * sW[128 + c] + xv.z * sW[256 + c] + xv.w * sW[384 + c];
}

// ---------- C[r,:] = (Xin[selOld[r],:]*score[selOld[r]]) @ W[128,128] ----------
// 64 rows/block, A-tile in LDS; LDS read as float4 along k; W double-buffered
// one 4-row group ahead in registers. M multiple of 64 (N1, N2 are).
__global__ __launch_bounds__(256) void mmh_k(const float* __restrict__ Xin,
                                             const int* __restrict__ selOld,
                                             const float* __restrict__ score,
                                             const float* __restrict__ W,
                                             float* __restrict__ C, int M)
{
    __shared__ float sA[64 * 128];   // 32 KB
    int tid = threadIdx.x;
    int row0 = blockIdx.x * 64;
    #pragma unroll
    for (int ch = 0; ch < 8; ++ch) {
        int i = ch * 1024 + tid * 4;
        int r = i >> 7, c = i & 127;
        int g = selOld[row0 + r];
        float sc = score[g];
        float4 v = *(const float4*)(Xin + (size_t)g * H_ + c);
        v.x *= sc; v.y *= sc; v.z *= sc; v.w *= sc;
        *(float4*)(sA + i) = v;
    }
    __syncthreads();
    int c4 = (tid & 31) * 4;
    int rg = tid >> 5;               // 0..7 -> rows rg*8 .. rg*8+7
    const float* sArow = sA + rg * 8 * 128;
    float4 acc[8];
    #pragma unroll
    for (int q = 0; q < 8; ++q) acc[q] = make_float4(0.f, 0.f, 0.f, 0.f);

    const float* Wp = W + c4;
    float4 w0 = *(const float4*)(Wp + 0 * 128);
    float4 w1 = *(const float4*)(Wp + 1 * 128);
    float4 w2 = *(const float4*)(Wp + 2 * 128);
    float4 w3 = *(const float4*)(Wp + 3 * 128);
    #pragma unroll 1
    for (int g4 = 0; g4 < 31; ++g4) {
        int kk = g4 * 4;
        const float* Wn = Wp + (kk + 4) * 128;
        float4 n0 = *(const float4*)(Wn + 0 * 128);
        float4 n1 = *(const float4*)(Wn + 1 * 128);
        float4 n2 = *(const float4*)(Wn + 2 * 128);
        float4 n3 = *(const float4*)(Wn + 3 * 128);
        #pragma unroll
        for (int q = 0; q < 8; ++q) {
            float4 a = *(const float4*)(sArow + q * 128 + kk);
            acc[q].x += a.x * w0.x; acc[q].y += a.x * w0.y; acc[q].z += a.x * w0.z; acc[q].w += a.x * w0.w;
            acc[q].x += a.y * w1.x; acc[q].y += a.y * w1.y; acc[q].z += a.y * w1.z; acc[q].w += a.y * w1.w;
            acc[q].x += a.z * w2.x; acc[q].y += a.z * w2.y; acc[q].z += a.z * w2.z; acc[q].w += a.z * w2.w;
            acc[q].x += a.w * w3.x; acc[q].y += a.w * w3.y; acc[q].z += a.w * w3.z; acc[q].w += a.w * w3.w;
        }
        w0 = n0; w1 = n1; w2 = n2; w3 = n3;
    }
    {
        const int kk = 124;
        #pragma unroll
        for (int q = 0; q < 8; ++q) {
            float4 a = *(const float4*)(sArow + q * 128 + kk);
            acc[q].x += a.x * w0.x; acc[q].y += a.x * w0.y; acc[q].z += a.x * w0.z; acc[q].w += a.x * w0.w;
            acc[q].x += a.y * w1.x; acc[q].y += a.y * w1.y; acc[q].z += a.y * w1.z; acc[q].w += a.y * w1.w;
            acc[q].x += a.z * w2.x; acc[q].y += a.z * w2.y; acc[q].z += a.z * w2.z; acc[q].w += a.z * w2.w;
            acc[q].x += a.w * w3.x; acc[q].y += a.w * w3.y; acc[q].z += a.w * w3.z; acc[q].w += a.w * w3.w;
        }
    }
    #pragma unroll
    for (int q = 0; q < 8; ++q) {
        int r = row0 + rg * 8 + q;
        *(float4*)(C + (size_t)r * H_ + c4) = acc[q];
    }
}

// ---------- degree count (level 0) ----------
__global__ void count_deg_k(const int* __restrict__ dst, int E, int* __restrict__ deg)
{
    int e = blockIdx.x * blockDim.x + threadIdx.x;
    if (e < E) atomicAdd(deg + dst[e], 1);
}

// ---------- exclusive scan (3-kernel) over deg[0..n-1] -> rowoff ----------
__global__ __launch_bounds__(1024) void scan1_k(const int* __restrict__ in, int* __restrict__ out,
                                                int* __restrict__ bsum, int n)
{
    __shared__ int s[1024];
    int t = threadIdx.x;
    int i = blockIdx.x * 1024 + t;
    int v = (i < n) ? in[i] : 0;
    s[t] = v;
    __syncthreads();
    for (int d = 1; d < 1024; d <<= 1) {
        int add = (t >= d) ? s[t - d] : 0;
        __syncthreads();
        s[t] += add;
        __syncthreads();
    }
    if (i < n) out[i] = s[t] - v;          // exclusive
    if (t == 1023) bsum[blockIdx.x] = s[1023];
}

__global__ void scan2_k(int* __restrict__ bsum, int nb, int* __restrict__ totalOut)
{
    if (threadIdx.x == 0) {
        int acc = 0;
        for (int i = 0; i < nb; ++i) { int v = bsum[i]; bsum[i] = acc; acc += v; }
        if (totalOut) *totalOut = acc;
    }
}

__global__ void scan3_k(int* __restrict__ out, const int* __restrict__ bsum, int n)
{
    int i = blockIdx.x * blockDim.x + threadIdx.x;
    if (i < n) out[i] += bsum[i >> 10];
}

// ---------- level-0 counting-sort fill: bucket src ids by dst ----------
__global__ void fill_k(const int* __restrict__ src, const int* __restrict__ dst, int E,
                       const int* __restrict__ rowoff, int* __restrict__ cur,
                       int* __restrict__ esrc)
{
    int e = blockIdx.x * blockDim.x + threadIdx.x;
    if (e >= E) return;
    int d = dst[e];
    int pos = rowoff[d] + atomicAdd(cur + d, 1);
    esrc[pos] = src[e];
}

// ---------- remap pass A: count surviving-edge degrees ----------
__global__ void remap_count_k(const int* __restrict__ osrc, const int* __restrict__ odst,
                              const int* __restrict__ ecntIn, int fixedE,
                              const int* __restrict__ newpos, int* __restrict__ deg)
{
    int E = ecntIn ? *ecntIn : fixedE;
    int e = blockIdx.x * blockDim.x + threadIdx.x;
    if (e >= E) return;
    int ns = newpos[osrc[e]];
    int nd = newpos[odst[e]];
    if (ns >= 0 && nd >= 0) atomicAdd(deg + nd, 1);
}

// ---------- remap pass B: fill next-level CSR (+ compacted edge list) ----------
__global__ void remap_fill_k(const int* __restrict__ osrc, const int* __restrict__ odst,
                             const int* __restrict__ ecntIn, int fixedE,
                             const int* __restrict__ newpos, const int* __restrict__ rowoff,
                             int* __restrict__ cur,
                             int* __restrict__ esrc, int* __restrict__ edst)
{
    int E = ecntIn ? *ecntIn : fixedE;
    int e = blockIdx.x * blockDim.x + threadIdx.x;
    if (e >= E) return;
    int ns = newpos[osrc[e]];
    int nd = newpos[odst[e]];
    if (ns >= 0 && nd >= 0) {
        int pos = rowoff[nd] + atomicAdd(cur + nd, 1);
        esrc[pos] = ns;
        edst[pos] = nd;
    }
}

// ---------- fused gather-aggregate + self-loop + bias + relu + pooling score ----------
// one wave per dst node; 4-wide unrolled edge loop; rsqrt(deg+1) computed in-kernel.
// XCD-swizzled: graph g's blocks pinned to XCD g%8 (L2 locality heuristic).
__global__ __launch_bounds__(256) void agg_k(const float* __restrict__ Hf,
                                             const int* __restrict__ rowoff,
                                             const int* __restrict__ esrc,
                                             const int* __restrict__ deg,
                                             const float* __restrict__ bias,
                                             const float* __restrict__ p,
                                             float* __restrict__ out,
                                             float* __restrict__ score,
                                             int npg, int Gb)
{
    int pb = blockIdx.x;
    int x  = pb & 7;                    // target XCD
    int m  = pb >> 3;
    int g  = x + 8 * (m / Gb);          // graph
    int lb = m % Gb;                    // local block within graph
    int j  = lb * 4 + (threadIdx.x >> 6);
    if (j >= npg) return;
    int n = g * npg + j;
    int lane = threadIdx.x & 63;
    float dn = rsqrtf((float)deg[n] + 1.0f);
    int beg = rowoff[n];
    int end = rowoff[n + 1];
    float2 hv = ((const float2*)(Hf + (size_t)n * H_))[lane];
    float acc0 = hv.x * dn * dn + bias[lane * 2 + 0];
    float acc1 = hv.y * dn * dn + bias[lane * 2 + 1];
    int e = beg;
    while (e + 4 <= end) {
        int s0 = esrc[e], s1 = esrc[e + 1], s2 = esrc[e + 2], s3 = esrc[e + 3];
        float c0 = rsqrtf((float)deg[s0] + 1.0f) * dn;
        float c1 = rsqrtf((float)deg[s1] + 1.0f) * dn;
        float c2 = rsqrtf((float)deg[s2] + 1.0f) * dn;
        float c3 = rsqrtf((float)deg[s3] + 1.0f) * dn;
        float2 v0 = ((const float2*)(Hf + (size_t)s0 * H_))[lane];
        float2 v1 = ((const float2*)(Hf + (size_t)s1 * H_))[lane];
        float2 v2 = ((const float2*)(Hf + (size_t)s2 * H_))[lane];
        float2 v3 = ((const float2*)(Hf + (size_t)s3 * H_))[lane];
        acc0 += v0.x * c0; acc1 += v0.y * c0;
        acc0 += v1.x * c1; acc1 += v1.y * c1;
        acc0 += v2.x * c2; acc1 += v2.y * c2;
        acc0 += v3.x * c3; acc1 += v3.y * c3;
        e += 4;
    }
    while (e < end) {
        int s = esrc[e];
        float c = rsqrtf((float)deg[s] + 1.0f) * dn;
        float2 sv = ((const float2*)(Hf + (size_t)s * H_))[lane];
        acc0 += sv.x * c;
        acc1 += sv.y * c;
        ++e;
    }
    float o0 = fmaxf(acc0, 0.f);
    float o1 = fmaxf(acc1, 0.f);
    ((float2*)(out + (size_t)n * H_))[lane] = make_float2(o0, o1);
    // fused pooling score: tanh(dot(o, p) / ||p||)
    float p0 = p[lane * 2], p1 = p[lane * 2 + 1];
    float dt = o0 * p0 + o1 * p1;
    float nr = p0 * p0 + p1 * p1;
    for (int mm = 32; mm > 0; mm >>= 1) {
        dt += __shfl_xor(dt, mm);
        nr += __shfl_xor(nr, mm);
    }
    if (lane == 0) score[n] = tanhf(dt / sqrtf(nr));
}

// ---------- exact per-graph top-k via bitonic sort (desc, tie: low index) ----------
__global__ __launch_bounds__(1024) void topk_k(const float* __restrict__ score, int n, int k,
                                               int* __restrict__ selOld, int* __restrict__ newpos)
{
    __shared__ unsigned long long key[2048];
    int b = blockIdx.x;
    const float* s = score + (size_t)b * n;
    for (int i = threadIdx.x; i < 2048; i += 1024) {
        unsigned long long pk = 0ull;
        if (i < n) {
            unsigned u = __float_as_uint(s[i]);
            u = (u & 0x80000000u) ? ~u : (u | 0x80000000u);
            pk = ((unsigned long long)u << 32) | (unsigned)(65535 - i);
        }
        key[i] = pk;
    }
    __syncthreads();
    for (int sz = 2; sz <= 2048; sz <<= 1) {
        for (int st = sz >> 1; st > 0; st >>= 1) {
            for (int t = threadIdx.x; t < 2048; t += 1024) {
                int j = t ^ st;
                if (j > t) {
                    unsigned long long a = key[t], c = key[j];
                    bool desc = ((t & sz) == 0);
                    if ((a < c) == desc) { key[t] = c; key[j] = a; }
                }
            }
            __syncthreads();
        }
    }
    for (int j = threadIdx.x; j < k; j += 1024) {
        int o = 65535 - (int)(key[j] & 0xFFFFFFFFull);
        int oldg = b * n + o;
        selOld[b * k + j] = oldg;
        newpos[oldg] = b * k + j;
    }
}

// ---------- readout stage 1: per-(graph,segment) partial max/sum over gathered rows ----------
__global__ __launch_bounds__(512) void readout_part_k(const float* __restrict__ X,
                                                      const int* __restrict__ selOld,
                                                      const float* __restrict__ score,
                                                      int kRows, float* __restrict__ part)
{
    __shared__ float smax[4][128];
    __shared__ float ssum[4][128];
    int b = blockIdx.x / RS;
    int s = blockIdx.x % RS;
    int chunk = (kRows + RS - 1) / RS;
    int j0 = s * chunk;
    int j1 = min(kRows, j0 + chunk);
    int f = threadIdx.x & 127;
    int q = threadIdx.x >> 7;          // 4 row groups
    float mx = -3.4e38f, sm = 0.f;
    for (int j = j0 + q; j < j1; j += 4) {
        int g = selOld[b * kRows + j];
        float v = X[(size_t)g * H_ + f] * score[g];
        mx = fmaxf(mx, v); sm += v;
    }
    smax[q][f] = mx; ssum[q][f] = sm;
    __syncthreads();
    if (q == 0) {
        mx = fmaxf(fmaxf(smax[0][f], smax[1][f]), fmaxf(smax[2][f], smax[3][f]));
        sm = ssum[0][f] + ssum[1][f] + ssum[2][f] + ssum[3][f];
        float* pr = part + ((size_t)b * RS + s) * 256;
        pr[f] = mx;
        pr[128 + f] = sm;
    }
}

// ---------- fused readout-reduce + 3-layer MLP head, one block per graph ----------
__global__ __launch_bounds__(256) void head_k(const float* __restrict__ part1,
                                              const float* __restrict__ part2,
                                              const float* __restrict__ part3,
                                              const float* __restrict__ lw1, const float* __restrict__ lb1,
                                              const float* __restrict__ lw2, const float* __restrict__ lb2,
                                              const float* __restrict__ lw3, const float* __restrict__ lb3,
                                              float* __restrict__ out)
{
    __shared__ float sZ[256];
    __shared__ float sZ1[128];
    __shared__ float sZ2[64];
    __shared__ float red[256];
    int b = blockIdx.x;
    int t = threadIdx.x;
    // fold RS partials of all 3 levels into z = x1+x2+x3
    {
        int f = t & 127;
        const float* pr1 = part1 + (size_t)b * RS * 256;
        const float* pr2 = part2 + (size_t)b * RS * 256;
        const float* pr3 = part3 + (size_t)b * RS * 256;
        float zv;
        if (t < 128) {
            float m1 = -3.4e38f, m2 = -3.4e38f, m3 = -3.4e38f;
            #pragma unroll
            for (int s = 0; s < RS; ++s) {
                m1 = fmaxf(m1, pr1[s * 256 + f]);
                m2 = fmaxf(m2, pr2[s * 256 + f]);
                m3 = fmaxf(m3, pr3[s * 256 + f]);
            }
            zv = m1 + m2 + m3;
        } else {
            float s1 = 0.f, s2 = 0.f, s3 = 0.f;
            #pragma unroll
            for (int s = 0; s < RS; ++s) {
                s1 += pr1[s * 256 + 128 + f];
                s2 += pr2[s * 256 + 128 + f];
                s3 += pr3[s * 256 + 128 + f];
            }
            zv = s1 * (1.0f / (float)K1) + s2 * (1.0f / (float)K2) + s3 * (1.0f / (float)K3);
        }
        sZ[t] = zv;
    }
    __syncthreads();
    // layer 1: 256 -> 128, two threads per output
    {
        int c = t & 127, h = t >> 7;
        float acc = 0.f;
        #pragma unroll
        for (int i = 0; i < 128; ++i) {
            int ii = h * 128 + i;
            acc += sZ[ii] * lw1[ii * 128 + c];
        }
        red[t] = acc;
        __syncthreads();
        if (t < 128) sZ1[t] = fmaxf(red[t] + red[128 + t] + lb1[t], 0.f);
        __syncthreads();
    }
    // layer 2: 128 -> 64, four threads per output
    {
        int c = t & 63, q = t >> 6;
        float acc = 0.f;
        #pragma unroll
        for (int i = 0; i < 32; ++i) {
            int ii = q * 32 + i;
            acc += sZ1[ii] * lw2[ii * 64 + c];
        }
        red[t] = acc;
        __syncthreads();
        if (t < 64) sZ2[t] = fmaxf(red[t] + red[64 + t] + red[128 + t] + red[192 + t] + lb2[t], 0.f);
        __syncthreads();
    }
    // layer 3: 64 -> 124, two threads per output, sigmoid
    {
        if (t < 2 * ACT) {
            int c = t >> 1, h = t & 1;
            float acc = 0.f;
            #pragma unroll
            for (int i = 0; i < 32; ++i) {
                int ii = h * 32 + i;
                acc += sZ2[ii] * lw3[ii * ACT + c];
            }
            red[t] = acc;
        }
        __syncthreads();
        if (t < ACT) {
            float s = red[2 * t] + red[2 * t + 1] + lb3[t];
            out[b * ACT + t] = 1.f / (1.f + expf(-s));
        }
    }
}

extern "C" void kernel_launch(void* const* d_in, const int* in_sizes, int n_in,
                              void* d_out, int out_size, void* d_ws, size_t ws_size,
                              hipStream_t stream)
{
    const float* x   = (const float*)d_in[0];
    const int*   src = (const int*)d_in[1];
    const int*   dst = (const int*)d_in[2];
    const float* W1  = (const float*)d_in[3];
    const float* b1  = (const float*)d_in[4];
    const float* W2  = (const float*)d_in[5];
    const float* b2  = (const float*)d_in[6];
    const float* W3  = (const float*)d_in[7];
    const float* b3  = (const float*)d_in[8];
    const float* p1  = (const float*)d_in[9];
    const float* p2  = (const float*)d_in[10];
    const float* p3  = (const float*)d_in[11];
    const float* lw1 = (const float*)d_in[12];
    const float* lb1 = (const float*)d_in[13];
    const float* lw2 = (const float*)d_in[14];
    const float* lb2 = (const float*)d_in[15];
    const float* lw3 = (const float*)d_in[16];
    const float* lb3 = (const float*)d_in[17];

    char* w = (char*)d_ws;
    size_t off = 0;
    auto alloc = [&](size_t bytes) -> void* {
        void* p = w + off;
        off = (off + bytes + 255) & ~(size_t)255;
        return p;
    };
    float* fA     = (float*)alloc((size_t)N0 * H_ * 4);   // h = X@W (pre-aggregate)
    float* fB     = (float*)alloc((size_t)N0 * H_ * 4);   // gcn output activations
    float* score  = (float*)alloc((size_t)N0 * 4);
    int*   newpos = (int*)  alloc((size_t)N0 * 4);
    int*   deg    = (int*)  alloc((size_t)(N0 + 1) * 4);
    int*   cur    = (int*)  alloc((size_t)N0 * 4);        // adjacent to deg: one memset
    int*   selOld = (int*)  alloc((size_t)N1 * 4);
    int*   rowoff = (int*)  alloc((size_t)(N0 + 1) * 4);
    int*   bsum   = (int*)  alloc((size_t)1024 * 4);
    int*   cs0    = (int*)  alloc((size_t)E0 * 4);        // level-0 CSR src
    int*   cs1    = (int*)  alloc((size_t)E0 * 4);        // level-1 CSR src
    int*   cd1    = (int*)  alloc((size_t)E0 * 4);        // level-1 edge dst list
    int*   cs2    = (int*)  alloc((size_t)E0 * 4);        // level-2 CSR src
    int*   cd2    = (int*)  alloc((size_t)E0 * 4);        // level-2 edge dst list
    float* part1  = (float*)alloc((size_t)B_ * RS * 256 * 4);
    float* part2  = (float*)alloc((size_t)B_ * RS * 256 * 4);
    float* part3  = (float*)alloc((size_t)B_ * RS * 256 * 4);
    int*   ecnt   = (int*)  alloc(256);                   // [0] = E1 (level-1 edge count)

    const size_t degcur_bytes = (size_t)((char*)cur - (char*)deg) + (size_t)N0 * 4;

    auto scan_rowoff = [&](int nNodes, int* totalOut) {
        int n = nNodes + 1;
        int nb = (n + 1023) / 1024;
        scan1_k<<<nb, 1024, 0, stream>>>(deg, rowoff, bsum, n);
        scan2_k<<<1, 64, 0, stream>>>(bsum, nb, totalOut);
        scan3_k<<<(n + 255) / 256, 256, 0, stream>>>(rowoff, bsum, n);
    };

    // blocks per graph (4 nodes/block) for agg_k swizzled launch
    const int Gb0 = (NPG + 3) / 4;     // 512
    const int Gb1 = (K1 + 3) / 4;      // 410
    const int Gb2 = (K2 + 3) / 4;      // 328

    // ================= GCN1 (level-0 graph: N0 nodes, E0 edges) =================
    hipMemsetAsync(deg, 0, degcur_bytes, stream);
    mm4_k<<<(N0 * H_) / 256, 256, 0, stream>>>(x, W1, fA, N0);
    count_deg_k<<<E0 / 256, 256, 0, stream>>>(dst, E0, deg);
    scan_rowoff(N0, nullptr);
    fill_k<<<E0 / 256, 256, 0, stream>>>(src, dst, E0, rowoff, cur, cs0);
    agg_k<<<B_ * Gb0, 256, 0, stream>>>(fA, rowoff, cs0, deg, b1, p1, fB, score, NPG, Gb0);

    // ---- pool 1: 2048 -> K1 per graph ----
    hipMemsetAsync(newpos, 0xFF, (size_t)N0 * 4, stream);
    topk_k<<<B_, 1024, 0, stream>>>(score, NPG, K1, selOld, newpos);
    readout_part_k<<<B_ * RS, 512, 0, stream>>>(fB, selOld, score, K1, part1);

    // ---- build level-1 CSR directly from (src,dst) + newpos ----
    hipMemsetAsync(deg, 0, degcur_bytes, stream);
    remap_count_k<<<E0 / 256, 256, 0, stream>>>(src, dst, nullptr, E0, newpos, deg);
    scan_rowoff(N1, ecnt);          // also writes E1 total into ecnt
    remap_fill_k<<<E0 / 256, 256, 0, stream>>>(src, dst, nullptr, E0, newpos, rowoff, cur, cs1, cd1);

    // ================= GCN2 (N1 nodes) =================
    mmh_k<<<N1 / 64, 256, 0, stream>>>(fB, selOld, score, W2, fA, N1);
    agg_k<<<B_ * Gb1, 256, 0, stream>>>(fA, rowoff, cs1, deg, b2, p2, fB, score, K1, Gb1);

    // ---- pool 2: K1 -> K2 per graph ----
    hipMemsetAsync(newpos, 0xFF, (size_t)N1 * 4, stream);
    topk_k<<<B_, 1024, 0, stream>>>(score, K1, K2, selOld, newpos);
    readout_part_k<<<B_ * RS, 512, 0, stream>>>(fB, selOld, score, K2, part2);

    // ---- build level-2 CSR from (cs1,cd1) + newpos ----
    hipMemsetAsync(deg, 0, degcur_bytes, stream);
    remap_count_k<<<E0 / 256, 256, 0, stream>>>(cs1, cd1, ecnt, 0, newpos, deg);
    scan_rowoff(N2, nullptr);
    remap_fill_k<<<E0 / 256, 256, 0, stream>>>(cs1, cd1, ecnt, 0, newpos, rowoff, cur, cs2, cd2);

    // ================= GCN3 (N2 nodes) =================
    mmh_k<<<N2 / 64, 256, 0, stream>>>(fB, selOld, score, W3, fA, N2);
    agg_k<<<B_ * Gb2, 256, 0, stream>>>(fA, rowoff, cs2, deg, b3, p3, fB, score, K2, Gb2);

    // ---- pool 3: K2 -> K3 per graph ----
    topk_k<<<B_, 1024, 0, stream>>>(score, K2, K3, selOld, newpos);
    readout_part_k<<<B_ * RS, 512, 0, stream>>>(fB, selOld, score, K3, part3);

    // ================= fused readout-fold + MLP head =================
    head_k<<<B_, 256, 0, stream>>>(part1, part2, part3, lw1, lb1, lw2, lb2, lw3, lb3, (float*)d_out);
}

// Round 8
// 518.306 us; speedup vs baseline: 5.6739x; 1.1248x over previous
//
#include <hip/hip_runtime.h>
#include <math.h>

namespace {
constexpr int B_   = 64;
constexpr int NPG  = 2048;
constexpr int N0   = B_ * NPG;      // 131072
constexpr int E0   = N0 * 4;        // 524288
constexpr int H_   = 128;
constexpr int K1   = 1639, K2 = 1312, K3 = 1050;
constexpr int N1   = B_ * K1;       // 104896
constexpr int N2   = B_ * K2;       // 83968
constexpr int N3   = B_ * K3;       // 67200
constexpr int ACT  = 124;
constexpr int RS   = 32;            // readout segments per graph
}

// ---------- C[r,:] = (Xin[selOld[r],:]*score[selOld[r]]) @ W[128,128] ----------
// 64 rows/block, A-tile in LDS; LDS read as float4 along k; W double-buffered
// one 4-row group ahead in registers. M multiple of 64 (N1, N2 are).
__global__ __launch_bounds__(256) void mmh_k(const float* __restrict__ Xin,
                                             const int* __restrict__ selOld,
                                             const float* __restrict__ score,
                                             const float* __restrict__ W,
                                             float* __restrict__ C, int M)
{
    __shared__ float sA[64 * 128];   // 32 KB
    int tid = threadIdx.x;
    int row0 = blockIdx.x * 64;
    #pragma unroll
    for (int ch = 0; ch < 8; ++ch) {
        int i = ch * 1024 + tid * 4;
        int r = i >> 7, c = i & 127;
        int g = selOld[row0 + r];
        float sc = score[g];
        float4 v = *(const float4*)(Xin + (size_t)g * H_ + c);
        v.x *= sc; v.y *= sc; v.z *= sc; v.w *= sc;
        *(float4*)(sA + i) = v;
    }
    __syncthreads();
    int c4 = (tid & 31) * 4;
    int rg = tid >> 5;               // 0..7 -> rows rg*8 .. rg*8+7
    const float* sArow = sA + rg * 8 * 128;
    float4 acc[8];
    #pragma unroll
    for (int q = 0; q < 8; ++q) acc[q] = make_float4(0.f, 0.f, 0.f, 0.f);

    const float* Wp = W + c4;
    float4 w0 = *(const float4*)(Wp + 0 * 128);
    float4 w1 = *(const float4*)(Wp + 1 * 128);
    float4 w2 = *(const float4*)(Wp + 2 * 128);
    float4 w3 = *(const float4*)(Wp + 3 * 128);
    #pragma unroll 1
    for (int g4 = 0; g4 < 31; ++g4) {
        int kk = g4 * 4;
        const float* Wn = Wp + (kk + 4) * 128;
        float4 n0 = *(const float4*)(Wn + 0 * 128);
        float4 n1 = *(const float4*)(Wn + 1 * 128);
        float4 n2 = *(const float4*)(Wn + 2 * 128);
        float4 n3 = *(const float4*)(Wn + 3 * 128);
        #pragma unroll
        for (int q = 0; q < 8; ++q) {
            float4 a = *(const float4*)(sArow + q * 128 + kk);
            acc[q].x += a.x * w0.x; acc[q].y += a.x * w0.y; acc[q].z += a.x * w0.z; acc[q].w += a.x * w0.w;
            acc[q].x += a.y * w1.x; acc[q].y += a.y * w1.y; acc[q].z += a.y * w1.z; acc[q].w += a.y * w1.w;
            acc[q].x += a.z * w2.x; acc[q].y += a.z * w2.y; acc[q].z += a.z * w2.z; acc[q].w += a.z * w2.w;
            acc[q].x += a.w * w3.x; acc[q].y += a.w * w3.y; acc[q].z += a.w * w3.z; acc[q].w += a.w * w3.w;
        }
        w0 = n0; w1 = n1; w2 = n2; w3 = n3;
    }
    {
        const int kk = 124;
        #pragma unroll
        for (int q = 0; q < 8; ++q) {
            float4 a = *(const float4*)(sArow + q * 128 + kk);
            acc[q].x += a.x * w0.x; acc[q].y += a.x * w0.y; acc[q].z += a.x * w0.z; acc[q].w += a.x * w0.w;
            acc[q].x += a.y * w1.x; acc[q].y += a.y * w1.y; acc[q].z += a.y * w1.z; acc[q].w += a.y * w1.w;
            acc[q].x += a.z * w2.x; acc[q].y += a.z * w2.y; acc[q].z += a.z * w2.z; acc[q].w += a.z * w2.w;
            acc[q].x += a.w * w3.x; acc[q].y += a.w * w3.y; acc[q].z += a.w * w3.z; acc[q].w += a.w * w3.w;
        }
    }
    #pragma unroll
    for (int q = 0; q < 8; ++q) {
        int r = row0 + rg * 8 + q;
        *(float4*)(C + (size_t)r * H_ + c4) = acc[q];
    }
}

// ---------- degree count (level 0) ----------
__global__ void count_deg_k(const int* __restrict__ dst, int E, int* __restrict__ deg)
{
    int e = blockIdx.x * blockDim.x + threadIdx.x;
    if (e < E) atomicAdd(deg + dst[e], 1);
}

// ---------- exclusive scan (3-kernel) over deg[0..n] -> rowoff; scan3 also emits dis ----------
__global__ __launch_bounds__(1024) void scan1_k(const int* __restrict__ in, int* __restrict__ out,
                                                int* __restrict__ bsum, int n)
{
    __shared__ int s[1024];
    int t = threadIdx.x;
    int i = blockIdx.x * 1024 + t;
    int v = (i < n) ? in[i] : 0;
    s[t] = v;
    __syncthreads();
    for (int d = 1; d < 1024; d <<= 1) {
        int add = (t >= d) ? s[t - d] : 0;
        __syncthreads();
        s[t] += add;
        __syncthreads();
    }
    if (i < n) out[i] = s[t] - v;          // exclusive
    if (t == 1023) bsum[blockIdx.x] = s[1023];
}

__global__ void scan2_k(int* __restrict__ bsum, int nb, int* __restrict__ totalOut)
{
    if (threadIdx.x == 0) {
        int acc = 0;
        for (int i = 0; i < nb; ++i) { int v = bsum[i]; bsum[i] = acc; acc += v; }
        if (totalOut) *totalOut = acc;
    }
}

__global__ void scan3_k(int* __restrict__ out, const int* __restrict__ bsum, int n,
                        const int* __restrict__ deg, float* __restrict__ dis)
{
    int i = blockIdx.x * blockDim.x + threadIdx.x;
    if (i < n) {
        out[i] += bsum[i >> 10];
        dis[i] = rsqrtf((float)deg[i] + 1.0f);
    }
}

// ---------- level-0 counting-sort fill: bucket src ids by dst ----------
__global__ void fill_k(const int* __restrict__ src, const int* __restrict__ dst, int E,
                       const int* __restrict__ rowoff, int* __restrict__ cur,
                       int* __restrict__ esrc)
{
    int e = blockIdx.x * blockDim.x + threadIdx.x;
    if (e >= E) return;
    int d = dst[e];
    int pos = rowoff[d] + atomicAdd(cur + d, 1);
    esrc[pos] = src[e];
}

// ---------- remap pass A: count surviving-edge degrees ----------
__global__ void remap_count_k(const int* __restrict__ osrc, const int* __restrict__ odst,
                              const int* __restrict__ ecntIn, int fixedE,
                              const int* __restrict__ newpos, int* __restrict__ deg)
{
    int E = ecntIn ? *ecntIn : fixedE;
    int e = blockIdx.x * blockDim.x + threadIdx.x;
    if (e >= E) return;
    int ns = newpos[osrc[e]];
    int nd = newpos[odst[e]];
    if (ns >= 0 && nd >= 0) atomicAdd(deg + nd, 1);
}

// ---------- remap pass B: fill next-level CSR (+ compacted edge list) ----------
__global__ void remap_fill_k(const int* __restrict__ osrc, const int* __restrict__ odst,
                             const int* __restrict__ ecntIn, int fixedE,
                             const int* __restrict__ newpos, const int* __restrict__ rowoff,
                             int* __restrict__ cur,
                             int* __restrict__ esrc, int* __restrict__ edst)
{
    int E = ecntIn ? *ecntIn : fixedE;
    int e = blockIdx.x * blockDim.x + threadIdx.x;
    if (e >= E) return;
    int ns = newpos[osrc[e]];
    int nd = newpos[odst[e]];
    if (ns >= 0 && nd >= 0) {
        int pos = rowoff[nd] + atomicAdd(cur + nd, 1);
        esrc[pos] = ns;
        edst[pos] = nd;
    }
}

// ---------- level-0 fused GCN: aggregate in 4-dim x-space, expand by W1 ----------
// out[n] = relu((sum_e dis[s]dis[n] x[s] + dis[n]^2 x[n]) @ W1 + b1); score fused.
// one wave per node; XCD-swizzled.
__global__ __launch_bounds__(256) void aggx_k(const float* __restrict__ X,
                                              const int* __restrict__ rowoff,
                                              const int* __restrict__ esrc,
                                              const float* __restrict__ dis,
                                              const float* __restrict__ W1,
                                              const float* __restrict__ b1,
                                              const float* __restrict__ p1,
                                              float* __restrict__ out,
                                              float* __restrict__ score,
                                              int npg, int Gb)
{
    __shared__ float sW[512];
    __shared__ float sb[128];
    __shared__ float sp[128];
    int tid = threadIdx.x;
    for (int i = tid; i < 512; i += 256) sW[i] = W1[i];
    if (tid < 128) { sb[tid] = b1[tid]; sp[tid] = p1[tid]; }
    __syncthreads();
    int pb = blockIdx.x;
    int x8 = pb & 7;
    int m  = pb >> 3;
    int g  = x8 + 8 * (m / Gb);
    int lb = m % Gb;
    int j  = lb * 4 + (tid >> 6);
    if (j >= npg) return;
    int n = g * npg + j;
    int lane = tid & 63;
    float dn = dis[n];
    float4 xa = *(const float4*)(X + (size_t)n * 4);
    float s2 = dn * dn;
    xa.x *= s2; xa.y *= s2; xa.z *= s2; xa.w *= s2;
    int beg = rowoff[n], end = rowoff[n + 1];
    for (int e = beg; e < end; ++e) {
        int s = esrc[e];
        float c = dis[s] * dn;
        float4 xs = *(const float4*)(X + (size_t)s * 4);
        xa.x += xs.x * c; xa.y += xs.y * c; xa.z += xs.z * c; xa.w += xs.w * c;
    }
    int c0 = lane * 2;
    float o0 = xa.x * sW[c0]     + xa.y * sW[128 + c0]     + xa.z * sW[256 + c0]     + xa.w * sW[384 + c0]     + sb[c0];
    float o1 = xa.x * sW[c0 + 1] + xa.y * sW[128 + c0 + 1] + xa.z * sW[256 + c0 + 1] + xa.w * sW[384 + c0 + 1] + sb[c0 + 1];
    o0 = fmaxf(o0, 0.f);
    o1 = fmaxf(o1, 0.f);
    ((float2*)(out + (size_t)n * H_))[lane] = make_float2(o0, o1);
    float p0 = sp[c0], p1v = sp[c0 + 1];
    float dt = o0 * p0 + o1 * p1v;
    float nr = p0 * p0 + p1v * p1v;
    for (int mm = 32; mm > 0; mm >>= 1) {
        dt += __shfl_xor(dt, mm);
        nr += __shfl_xor(nr, mm);
    }
    if (lane == 0) score[n] = tanhf(dt / sqrtf(nr));
}

// ---------- levels 1-2 gather-aggregate: 2 edges/wave-iter, float4 lanes ----------
// lanes 0-31 process even edges, 32-63 odd edges; combine via shfl_xor(32).
__global__ __launch_bounds__(256) void agg_k(const float* __restrict__ Hf,
                                             const int* __restrict__ rowoff,
                                             const int* __restrict__ esrc,
                                             const float* __restrict__ dis,
                                             const float* __restrict__ bias,
                                             const float* __restrict__ p,
                                             float* __restrict__ out,
                                             float* __restrict__ score,
                                             int npg, int Gb)
{
    int pb = blockIdx.x;
    int x8 = pb & 7;
    int m  = pb >> 3;
    int g  = x8 + 8 * (m / Gb);
    int lb = m % Gb;
    int j  = lb * 4 + (threadIdx.x >> 6);
    if (j >= npg) return;
    int n = g * npg + j;
    int lane = threadIdx.x & 63;
    int half = lane >> 5;
    int l4 = (lane & 31) * 4;
    float dn = dis[n];
    int beg = rowoff[n], end = rowoff[n + 1];
    float4 acc = make_float4(0.f, 0.f, 0.f, 0.f);
    for (int e = beg + half; e < end; e += 2) {
        int s = esrc[e];
        float c = dis[s] * dn;
        float4 v = *(const float4*)(Hf + (size_t)s * H_ + l4);
        acc.x += v.x * c; acc.y += v.y * c; acc.z += v.z * c; acc.w += v.w * c;
    }
    acc.x += __shfl_xor(acc.x, 32);
    acc.y += __shfl_xor(acc.y, 32);
    acc.z += __shfl_xor(acc.z, 32);
    acc.w += __shfl_xor(acc.w, 32);
    if (half == 0) {
        float4 hv = *(const float4*)(Hf + (size_t)n * H_ + l4);
        float4 bv = *(const float4*)(bias + l4);
        float s2 = dn * dn;
        float o0 = fmaxf(acc.x + hv.x * s2 + bv.x, 0.f);
        float o1 = fmaxf(acc.y + hv.y * s2 + bv.y, 0.f);
        float o2 = fmaxf(acc.z + hv.z * s2 + bv.z, 0.f);
        float o3 = fmaxf(acc.w + hv.w * s2 + bv.w, 0.f);
        *(float4*)(out + (size_t)n * H_ + l4) = make_float4(o0, o1, o2, o3);
        float4 pv = *(const float4*)(p + l4);
        float dt = o0 * pv.x + o1 * pv.y + o2 * pv.z + o3 * pv.w;
        float nr = pv.x * pv.x + pv.y * pv.y + pv.z * pv.z + pv.w * pv.w;
        for (int mm = 16; mm > 0; mm >>= 1) {
            dt += __shfl_xor(dt, mm);
            nr += __shfl_xor(nr, mm);
        }
        if ((lane & 31) == 0) score[n] = tanhf(dt / sqrtf(nr));
    }
}

// ---------- exact per-graph top-k via bitonic sort (desc, tie: low index) ----------
__global__ __launch_bounds__(1024) void topk_k(const float* __restrict__ score, int n, int k,
                                               int* __restrict__ selOld, int* __restrict__ newpos)
{
    __shared__ unsigned long long key[2048];
    int b = blockIdx.x;
    const float* s = score + (size_t)b * n;
    for (int i = threadIdx.x; i < 2048; i += 1024) {
        unsigned long long pk = 0ull;
        if (i < n) {
            unsigned u = __float_as_uint(s[i]);
            u = (u & 0x80000000u) ? ~u : (u | 0x80000000u);
            pk = ((unsigned long long)u << 32) | (unsigned)(65535 - i);
        }
        key[i] = pk;
    }
    __syncthreads();
    for (int sz = 2; sz <= 2048; sz <<= 1) {
        for (int st = sz >> 1; st > 0; st >>= 1) {
            for (int t = threadIdx.x; t < 2048; t += 1024) {
                int j = t ^ st;
                if (j > t) {
                    unsigned long long a = key[t], c = key[j];
                    bool desc = ((t & sz) == 0);
                    if ((a < c) == desc) { key[t] = c; key[j] = a; }
                }
            }
            __syncthreads();
        }
    }
    for (int j = threadIdx.x; j < k; j += 1024) {
        int o = 65535 - (int)(key[j] & 0xFFFFFFFFull);
        int oldg = b * n + o;
        selOld[b * k + j] = oldg;
        newpos[oldg] = b * k + j;
    }
}

// ---------- readout stage 1: per-(graph,segment) partial max/sum, float4 lanes ----------
__global__ __launch_bounds__(512) void readout_part_k(const float* __restrict__ X,
                                                      const int* __restrict__ selOld,
                                                      const float* __restrict__ score,
                                                      int kRows, float* __restrict__ part)
{
    __shared__ float smax[16][128];
    __shared__ float ssum[16][128];
    int b = blockIdx.x / RS;
    int s = blockIdx.x % RS;
    int chunk = (kRows + RS - 1) / RS;
    int j0 = s * chunk;
    int j1 = min(kRows, j0 + chunk);
    int tid = threadIdx.x;
    int f4 = (tid & 31) * 4;
    int q = tid >> 5;                  // 16 row groups
    float4 mx = make_float4(-3.4e38f, -3.4e38f, -3.4e38f, -3.4e38f);
    float4 sm = make_float4(0.f, 0.f, 0.f, 0.f);
    for (int j = j0 + q; j < j1; j += 16) {
        int g = selOld[b * kRows + j];
        float sc = score[g];
        float4 v = *(const float4*)(X + (size_t)g * H_ + f4);
        v.x *= sc; v.y *= sc; v.z *= sc; v.w *= sc;
        mx.x = fmaxf(mx.x, v.x); mx.y = fmaxf(mx.y, v.y);
        mx.z = fmaxf(mx.z, v.z); mx.w = fmaxf(mx.w, v.w);
        sm.x += v.x; sm.y += v.y; sm.z += v.z; sm.w += v.w;
    }
    *(float4*)&smax[q][f4] = mx;
    *(float4*)&ssum[q][f4] = sm;
    __syncthreads();
    if (tid < 128) {
        float m = smax[0][tid], a = ssum[0][tid];
        #pragma unroll
        for (int gq = 1; gq < 16; ++gq) {
            m = fmaxf(m, smax[gq][tid]);
            a += ssum[gq][tid];
        }
        float* pr = part + ((size_t)b * RS + s) * 256;
        pr[tid] = m;
        pr[128 + tid] = a;
    }
}

// ---------- fused readout-reduce + 3-layer MLP head, one block per graph ----------
__global__ __launch_bounds__(256) void head_k(const float* __restrict__ part1,
                                              const float* __restrict__ part2,
                                              const float* __restrict__ part3,
                                              const float* __restrict__ lw1, const float* __restrict__ lb1,
                                              const float* __restrict__ lw2, const float* __restrict__ lb2,
                                              const float* __restrict__ lw3, const float* __restrict__ lb3,
                                              float* __restrict__ out)
{
    __shared__ float sZ[256];
    __shared__ float sZ1[128];
    __shared__ float sZ2[64];
    __shared__ float red[256];
    int b = blockIdx.x;
    int t = threadIdx.x;
    // fold RS partials of all 3 levels into z = x1+x2+x3
    {
        int f = t & 127;
        const float* pr1 = part1 + (size_t)b * RS * 256;
        const float* pr2 = part2 + (size_t)b * RS * 256;
        const float* pr3 = part3 + (size_t)b * RS * 256;
        float zv;
        if (t < 128) {
            float m1 = -3.4e38f, m2 = -3.4e38f, m3 = -3.4e38f;
            #pragma unroll
            for (int s = 0; s < RS; ++s) {
                m1 = fmaxf(m1, pr1[s * 256 + f]);
                m2 = fmaxf(m2, pr2[s * 256 + f]);
                m3 = fmaxf(m3, pr3[s * 256 + f]);
            }
            zv = m1 + m2 + m3;
        } else {
            float s1 = 0.f, s2 = 0.f, s3 = 0.f;
            #pragma unroll
            for (int s = 0; s < RS; ++s) {
                s1 += pr1[s * 256 + 128 + f];
                s2 += pr2[s * 256 + 128 + f];
                s3 += pr3[s * 256 + 128 + f];
            }
            zv = s1 * (1.0f / (float)K1) + s2 * (1.0f / (float)K2) + s3 * (1.0f / (float)K3);
        }
        sZ[t] = zv;
    }
    __syncthreads();
    // layer 1: 256 -> 128, two threads per output
    {
        int c = t & 127, h = t >> 7;
        float acc = 0.f;
        #pragma unroll
        for (int i = 0; i < 128; ++i) {
            int ii = h * 128 + i;
            acc += sZ[ii] * lw1[ii * 128 + c];
        }
        red[t] = acc;
        __syncthreads();
        if (t < 128) sZ1[t] = fmaxf(red[t] + red[128 + t] + lb1[t], 0.f);
        __syncthreads();
    }
    // layer 2: 128 -> 64, four threads per output
    {
        int c = t & 63, q = t >> 6;
        float acc = 0.f;
        #pragma unroll
        for (int i = 0; i < 32; ++i) {
            int ii = q * 32 + i;
            acc += sZ1[ii] * lw2[ii * 64 + c];
        }
        red[t] = acc;
        __syncthreads();
        if (t < 64) sZ2[t] = fmaxf(red[t] + red[64 + t] + red[128 + t] + red[192 + t] + lb2[t], 0.f);
        __syncthreads();
    }
    // layer 3: 64 -> 124, two threads per output, sigmoid
    {
        if (t < 2 * ACT) {
            int c = t >> 1, h = t & 1;
            float acc = 0.f;
            #pragma unroll
            for (int i = 0; i < 32; ++i) {
                int ii = h * 32 + i;
                acc += sZ2[ii] * lw3[ii * ACT + c];
            }
            red[t] = acc;
        }
        __syncthreads();
        if (t < ACT) {
            float s = red[2 * t] + red[2 * t + 1] + lb3[t];
            out[b * ACT + t] = 1.f / (1.f + expf(-s));
        }
    }
}

extern "C" void kernel_launch(void* const* d_in, const int* in_sizes, int n_in,
                              void* d_out, int out_size, void* d_ws, size_t ws_size,
                              hipStream_t stream)
{
    const float* x   = (const float*)d_in[0];
    const int*   src = (const int*)d_in[1];
    const int*   dst = (const int*)d_in[2];
    const float* W1  = (const float*)d_in[3];
    const float* b1  = (const float*)d_in[4];
    const float* W2  = (const float*)d_in[5];
    const float* b2  = (const float*)d_in[6];
    const float* W3  = (const float*)d_in[7];
    const float* b3  = (const float*)d_in[8];
    const float* p1  = (const float*)d_in[9];
    const float* p2  = (const float*)d_in[10];
    const float* p3  = (const float*)d_in[11];
    const float* lw1 = (const float*)d_in[12];
    const float* lb1 = (const float*)d_in[13];
    const float* lw2 = (const float*)d_in[14];
    const float* lb2 = (const float*)d_in[15];
    const float* lw3 = (const float*)d_in[16];
    const float* lb3 = (const float*)d_in[17];

    char* w = (char*)d_ws;
    size_t off = 0;
    auto alloc = [&](size_t bytes) -> void* {
        void* p = w + off;
        off = (off + bytes + 255) & ~(size_t)255;
        return p;
    };
    float* fA     = (float*)alloc((size_t)N0 * H_ * 4);   // h = Xg@W (levels 1-2)
    float* fB     = (float*)alloc((size_t)N0 * H_ * 4);   // gcn output activations
    float* score  = (float*)alloc((size_t)N0 * 4);
    int*   newpos = (int*)  alloc((size_t)N0 * 4);
    int*   deg    = (int*)  alloc((size_t)(N0 + 1) * 4);
    int*   cur    = (int*)  alloc((size_t)N0 * 4);        // adjacent to deg: one memset
    float* dis    = (float*)alloc((size_t)(N0 + 1) * 4);
    int*   selOld = (int*)  alloc((size_t)N1 * 4);
    int*   rowoff = (int*)  alloc((size_t)(N0 + 1) * 4);
    int*   bsum   = (int*)  alloc((size_t)1024 * 4);
    int*   cs0    = (int*)  alloc((size_t)E0 * 4);        // level-0 CSR src
    int*   cs1    = (int*)  alloc((size_t)E0 * 4);        // level-1 CSR src
    int*   cd1    = (int*)  alloc((size_t)E0 * 4);        // level-1 edge dst list
    int*   cs2    = (int*)  alloc((size_t)E0 * 4);        // level-2 CSR src
    int*   cd2    = (int*)  alloc((size_t)E0 * 4);        // level-2 edge dst list
    float* part1  = (float*)alloc((size_t)B_ * RS * 256 * 4);
    float* part2  = (float*)alloc((size_t)B_ * RS * 256 * 4);
    float* part3  = (float*)alloc((size_t)B_ * RS * 256 * 4);
    int*   ecnt   = (int*)  alloc(256);                   // [0] = E1 (level-1 edge count)

    const size_t degcur_bytes = (size_t)((char*)cur - (char*)deg) + (size_t)N0 * 4;

    auto scan_rowoff = [&](int nNodes, int* totalOut) {
        int n = nNodes + 1;
        int nb = (n + 1023) / 1024;
        scan1_k<<<nb, 1024, 0, stream>>>(deg, rowoff, bsum, n);
        scan2_k<<<1, 64, 0, stream>>>(bsum, nb, totalOut);
        scan3_k<<<(n + 255) / 256, 256, 0, stream>>>(rowoff, bsum, n, deg, dis);
    };

    // blocks per graph (4 nodes/block) for agg launches
    const int Gb0 = (NPG + 3) / 4;     // 512
    const int Gb1 = (K1 + 3) / 4;      // 410
    const int Gb2 = (K2 + 3) / 4;      // 328

    // ================= GCN1 (level-0: aggregate in x-space, expand by W1) =================
    hipMemsetAsync(deg, 0, degcur_bytes, stream);
    count_deg_k<<<E0 / 256, 256, 0, stream>>>(dst, E0, deg);
    scan_rowoff(N0, nullptr);
    fill_k<<<E0 / 256, 256, 0, stream>>>(src, dst, E0, rowoff, cur, cs0);
    aggx_k<<<B_ * Gb0, 256, 0, stream>>>(x, rowoff, cs0, dis, W1, b1, p1, fB, score, NPG, Gb0);

    // ---- pool 1: 2048 -> K1 per graph ----
    hipMemsetAsync(newpos, 0xFF, (size_t)N0 * 4, stream);
    topk_k<<<B_, 1024, 0, stream>>>(score, NPG, K1, selOld, newpos);
    readout_part_k<<<B_ * RS, 512, 0, stream>>>(fB, selOld, score, K1, part1);

    // ---- build level-1 CSR directly from (src,dst) + newpos ----
    hipMemsetAsync(deg, 0, degcur_bytes, stream);
    remap_count_k<<<E0 / 256, 256, 0, stream>>>(src, dst, nullptr, E0, newpos, deg);
    scan_rowoff(N1, ecnt);          // also writes E1 total into ecnt
    remap_fill_k<<<E0 / 256, 256, 0, stream>>>(src, dst, nullptr, E0, newpos, rowoff, cur, cs1, cd1);

    // ================= GCN2 (N1 nodes) =================
    mmh_k<<<N1 / 64, 256, 0, stream>>>(fB, selOld, score, W2, fA, N1);
    agg_k<<<B_ * Gb1, 256, 0, stream>>>(fA, rowoff, cs1, dis, b2, p2, fB, score, K1, Gb1);

    // ---- pool 2: K1 -> K2 per graph ----
    hipMemsetAsync(newpos, 0xFF, (size_t)N1 * 4, stream);
    topk_k<<<B_, 1024, 0, stream>>>(score, K1, K2, selOld, newpos);
    readout_part_k<<<B_ * RS, 512, 0, stream>>>(fB, selOld, score, K2, part2);

    // ---- build level-2 CSR from (cs1,cd1) + newpos ----
    hipMemsetAsync(deg, 0, degcur_bytes, stream);
    remap_count_k<<<E0 / 256, 256, 0, stream>>>(cs1, cd1, ecnt, 0, newpos, deg);
    scan_rowoff(N2, nullptr);
    remap_fill_k<<<E0 / 256, 256, 0, stream>>>(cs1, cd1, ecnt, 0, newpos, rowoff, cur, cs2, cd2);

    // ================= GCN3 (N2 nodes) =================
    mmh_k<<<N2 / 64, 256, 0, stream>>>(fB, selOld, score, W3, fA, N2);
    agg_k<<<B_ * Gb2, 256, 0, stream>>>(fA, rowoff, cs2, dis, b3, p3, fB, score, K2, Gb2);

    // ---- pool 3: K2 -> K3 per graph ----
    topk_k<<<B_, 1024, 0, stream>>>(score, K2, K3, selOld, newpos);
    readout_part_k<<<B_ * RS, 512, 0, stream>>>(fB, selOld, score, K3, part3);

    // ================= fused readout-fold + MLP head =================
    head_k<<<B_, 256, 0, stream>>>(part1, part2, part3, lw1, lb1, lw2, lb2, lw3, lb3, (float*)d_out);
}

// Round 9
// 492.206 us; speedup vs baseline: 5.9747x; 1.0530x over previous
//
#include <hip/hip_runtime.h>
#include <math.h>

namespace {
constexpr int B_   = 64;
constexpr int NPG  = 2048;
constexpr int N0   = B_ * NPG;      // 131072
constexpr int E0   = N0 * 4;        // 524288
constexpr int H_   = 128;
constexpr int K1   = 1639, K2 = 1312, K3 = 1050;
constexpr int N1   = B_ * K1;       // 104896
constexpr int N2   = B_ * K2;       // 83968
constexpr int N3   = B_ * K3;       // 67200
constexpr int ACT  = 124;
constexpr int RS   = 32;            // readout segments per graph
}

// ---------- C[r,:] = (Xin[selOld[r],:]*score[selOld[r]]) @ W[128,128] ----------
__global__ __launch_bounds__(256) void mmh_k(const float* __restrict__ Xin,
                                             const int* __restrict__ selOld,
                                             const float* __restrict__ score,
                                             const float* __restrict__ W,
                                             float* __restrict__ C, int M)
{
    __shared__ float sA[64 * 128];   // 32 KB
    int tid = threadIdx.x;
    int row0 = blockIdx.x * 64;
    #pragma unroll
    for (int ch = 0; ch < 8; ++ch) {
        int i = ch * 1024 + tid * 4;
        int r = i >> 7, c = i & 127;
        int g = selOld[row0 + r];
        float sc = score[g];
        float4 v = *(const float4*)(Xin + (size_t)g * H_ + c);
        v.x *= sc; v.y *= sc; v.z *= sc; v.w *= sc;
        *(float4*)(sA + i) = v;
    }
    __syncthreads();
    int c4 = (tid & 31) * 4;
    int rg = tid >> 5;               // 0..7 -> rows rg*8 .. rg*8+7
    const float* sArow = sA + rg * 8 * 128;
    float4 acc[8];
    #pragma unroll
    for (int q = 0; q < 8; ++q) acc[q] = make_float4(0.f, 0.f, 0.f, 0.f);

    const float* Wp = W + c4;
    float4 w0 = *(const float4*)(Wp + 0 * 128);
    float4 w1 = *(const float4*)(Wp + 1 * 128);
    float4 w2 = *(const float4*)(Wp + 2 * 128);
    float4 w3 = *(const float4*)(Wp + 3 * 128);
    #pragma unroll 1
    for (int g4 = 0; g4 < 31; ++g4) {
        int kk = g4 * 4;
        const float* Wn = Wp + (kk + 4) * 128;
        float4 n0 = *(const float4*)(Wn + 0 * 128);
        float4 n1 = *(const float4*)(Wn + 1 * 128);
        float4 n2 = *(const float4*)(Wn + 2 * 128);
        float4 n3 = *(const float4*)(Wn + 3 * 128);
        #pragma unroll
        for (int q = 0; q < 8; ++q) {
            float4 a = *(const float4*)(sArow + q * 128 + kk);
            acc[q].x += a.x * w0.x; acc[q].y += a.x * w0.y; acc[q].z += a.x * w0.z; acc[q].w += a.x * w0.w;
            acc[q].x += a.y * w1.x; acc[q].y += a.y * w1.y; acc[q].z += a.y * w1.z; acc[q].w += a.y * w1.w;
            acc[q].x += a.z * w2.x; acc[q].y += a.z * w2.y; acc[q].z += a.z * w2.z; acc[q].w += a.z * w2.w;
            acc[q].x += a.w * w3.x; acc[q].y += a.w * w3.y; acc[q].z += a.w * w3.z; acc[q].w += a.w * w3.w;
        }
        w0 = n0; w1 = n1; w2 = n2; w3 = n3;
    }
    {
        const int kk = 124;
        #pragma unroll
        for (int q = 0; q < 8; ++q) {
            float4 a = *(const float4*)(sArow + q * 128 + kk);
            acc[q].x += a.x * w0.x; acc[q].y += a.x * w0.y; acc[q].z += a.x * w0.z; acc[q].w += a.x * w0.w;
            acc[q].x += a.y * w1.x; acc[q].y += a.y * w1.y; acc[q].z += a.y * w1.z; acc[q].w += a.y * w1.w;
            acc[q].x += a.z * w2.x; acc[q].y += a.z * w2.y; acc[q].z += a.z * w2.z; acc[q].w += a.z * w2.w;
            acc[q].x += a.w * w3.x; acc[q].y += a.w * w3.y; acc[q].z += a.w * w3.z; acc[q].w += a.w * w3.w;
        }
    }
    #pragma unroll
    for (int q = 0; q < 8; ++q) {
        int r = row0 + rg * 8 + q;
        *(float4*)(C + (size_t)r * H_ + c4) = acc[q];
    }
}

// ---------- degree count (level 0) ----------
__global__ void count_deg_k(const int* __restrict__ dst, int E, int* __restrict__ deg)
{
    int e = blockIdx.x * blockDim.x + threadIdx.x;
    if (e < E) atomicAdd(deg + dst[e], 1);
}

// ---------- exclusive scan over deg[0..n] -> rowoff; scan2 also emits 1/||p||; scan3 emits dis ----------
__global__ __launch_bounds__(1024) void scan1_k(const int* __restrict__ in, int* __restrict__ out,
                                                int* __restrict__ bsum, int n)
{
    __shared__ int s[1024];
    int t = threadIdx.x;
    int i = blockIdx.x * 1024 + t;
    int v = (i < n) ? in[i] : 0;
    s[t] = v;
    __syncthreads();
    for (int d = 1; d < 1024; d <<= 1) {
        int add = (t >= d) ? s[t - d] : 0;
        __syncthreads();
        s[t] += add;
        __syncthreads();
    }
    if (i < n) out[i] = s[t] - v;          // exclusive
    if (t == 1023) bsum[blockIdx.x] = s[1023];
}

__global__ void scan2_k(int* __restrict__ bsum, int nb, int* __restrict__ totalOut,
                        const float* __restrict__ p, float* __restrict__ invnOut)
{
    if (threadIdx.x == 0) {
        int acc = 0;
        for (int i = 0; i < nb; ++i) { int v = bsum[i]; bsum[i] = acc; acc += v; }
        if (totalOut) *totalOut = acc;
        if (p) {
            float s = 0.f;
            for (int i = 0; i < 128; ++i) s += p[i] * p[i];
            *invnOut = rsqrtf(s);
        }
    }
}

__global__ void scan3_k(int* __restrict__ out, const int* __restrict__ bsum, int n,
                        const int* __restrict__ deg, float* __restrict__ dis)
{
    int i = blockIdx.x * blockDim.x + threadIdx.x;
    if (i < n) {
        out[i] += bsum[i >> 10];
        dis[i] = rsqrtf((float)deg[i] + 1.0f);
    }
}

// ---------- level-0 counting-sort fill: bucket src ids by dst ----------
__global__ void fill_k(const int* __restrict__ src, const int* __restrict__ dst, int E,
                       const int* __restrict__ rowoff, int* __restrict__ cur,
                       int* __restrict__ esrc)
{
    int e = blockIdx.x * blockDim.x + threadIdx.x;
    if (e >= E) return;
    int d = dst[e];
    int pos = rowoff[d] + atomicAdd(cur + d, 1);
    esrc[pos] = src[e];
}

// ---------- remap pass A: count surviving-edge degrees ----------
__global__ void remap_count_k(const int* __restrict__ osrc, const int* __restrict__ odst,
                              const int* __restrict__ ecntIn, int fixedE,
                              const int* __restrict__ newpos, int* __restrict__ deg)
{
    int E = ecntIn ? *ecntIn : fixedE;
    int e = blockIdx.x * blockDim.x + threadIdx.x;
    if (e >= E) return;
    int ns = newpos[osrc[e]];
    int nd = newpos[odst[e]];
    if (ns >= 0 && nd >= 0) atomicAdd(deg + nd, 1);
}

// ---------- remap pass B: fill next-level CSR (+ compacted edge list) ----------
__global__ void remap_fill_k(const int* __restrict__ osrc, const int* __restrict__ odst,
                             const int* __restrict__ ecntIn, int fixedE,
                             const int* __restrict__ newpos, const int* __restrict__ rowoff,
                             int* __restrict__ cur,
                             int* __restrict__ esrc, int* __restrict__ edst)
{
    int E = ecntIn ? *ecntIn : fixedE;
    int e = blockIdx.x * blockDim.x + threadIdx.x;
    if (e >= E) return;
    int ns = newpos[osrc[e]];
    int nd = newpos[odst[e]];
    if (ns >= 0 && nd >= 0) {
        int pos = rowoff[nd] + atomicAdd(cur + nd, 1);
        esrc[pos] = ns;
        edst[pos] = nd;
    }
}

// ---------- level-0 fused GCN, phase-split ----------
// phase1: thread-per-node 4-dim aggregation -> LDS
// phase2: wave-serial 4->128 expansion + write + dt reduce
// phase3: thread-parallel tanh scores.
// 256 nodes/block; npg must be divisible by 256 (2048 is). XCD-swizzled.
__global__ __launch_bounds__(256) void aggx_k(const float* __restrict__ X,
                                              const int* __restrict__ rowoff,
                                              const int* __restrict__ esrc,
                                              const float* __restrict__ dis,
                                              const float* __restrict__ W1,
                                              const float* __restrict__ b1,
                                              const float* __restrict__ p1,
                                              const float* __restrict__ invn,
                                              float* __restrict__ out,
                                              float* __restrict__ score,
                                              int npg, int Gb)
{
    __shared__ float sW[512];
    __shared__ float sb[128];
    __shared__ float sp[128];
    __shared__ float sxa[256 * 4];
    __shared__ float sdt[256];
    int tid = threadIdx.x;
    for (int i = tid; i < 512; i += 256) sW[i] = W1[i];
    if (tid < 128) { sb[tid] = b1[tid]; sp[tid] = p1[tid]; }
    int pb = blockIdx.x;
    int x8 = pb & 7;
    int m  = pb >> 3;
    int g  = x8 + 8 * (m / Gb);
    int lb = m % Gb;
    int nbase = g * npg + lb * 256;
    // phase 1: per-thread aggregation in 4-dim input space
    int n = nbase + tid;
    float dn = dis[n];
    float4 xa = *(const float4*)(X + (size_t)n * 4);
    float s2 = dn * dn;
    xa.x *= s2; xa.y *= s2; xa.z *= s2; xa.w *= s2;
    int beg = rowoff[n], end = rowoff[n + 1];
    for (int e = beg; e < end; ++e) {
        int s = esrc[e];
        float c = dis[s] * dn;
        float4 xs = *(const float4*)(X + (size_t)s * 4);
        xa.x += xs.x * c; xa.y += xs.y * c; xa.z += xs.z * c; xa.w += xs.w * c;
    }
    *(float4*)(sxa + tid * 4) = xa;
    __syncthreads();
    // phase 2: each wave expands 64 nodes, 2 channels per lane
    int wv = tid >> 6;
    int lane = tid & 63;
    int c0 = lane * 2;
    float wa0 = sW[c0],     wb0 = sW[128 + c0],     wc0 = sW[256 + c0],     wd0 = sW[384 + c0];
    float wa1 = sW[c0 + 1], wb1 = sW[128 + c0 + 1], wc1 = sW[256 + c0 + 1], wd1 = sW[384 + c0 + 1];
    float bb0 = sb[c0], bb1 = sb[c0 + 1];
    float pp0 = sp[c0], pp1 = sp[c0 + 1];
    #pragma unroll 4
    for (int ii = 0; ii < 64; ++ii) {
        int i = wv * 64 + ii;
        float4 a = *(const float4*)(sxa + i * 4);
        float o0 = fmaxf(a.x * wa0 + a.y * wb0 + a.z * wc0 + a.w * wd0 + bb0, 0.f);
        float o1 = fmaxf(a.x * wa1 + a.y * wb1 + a.z * wc1 + a.w * wd1 + bb1, 0.f);
        ((float2*)(out + (size_t)(nbase + i) * H_))[lane] = make_float2(o0, o1);
        float dt = o0 * pp0 + o1 * pp1;
        for (int mm = 32; mm > 0; mm >>= 1) dt += __shfl_xor(dt, mm);
        if (lane == 0) sdt[i] = dt;
    }
    __syncthreads();
    // phase 3: thread-parallel score
    score[nbase + tid] = tanhf(sdt[tid] * invn[0]);
}

// ---------- levels 1-2 gather-aggregate: 2 edges/wave-iter, float4 lanes ----------
__global__ __launch_bounds__(256) void agg_k(const float* __restrict__ Hf,
                                             const int* __restrict__ rowoff,
                                             const int* __restrict__ esrc,
                                             const float* __restrict__ dis,
                                             const float* __restrict__ bias,
                                             const float* __restrict__ p,
                                             const float* __restrict__ invn,
                                             float* __restrict__ out,
                                             float* __restrict__ score,
                                             int npg, int Gb)
{
    int pb = blockIdx.x;
    int x8 = pb & 7;
    int m  = pb >> 3;
    int g  = x8 + 8 * (m / Gb);
    int lb = m % Gb;
    int j  = lb * 4 + (threadIdx.x >> 6);
    if (j >= npg) return;
    int n = g * npg + j;
    int lane = threadIdx.x & 63;
    int half = lane >> 5;
    int l4 = (lane & 31) * 4;
    float dn = dis[n];
    int beg = rowoff[n], end = rowoff[n + 1];
    float4 acc = make_float4(0.f, 0.f, 0.f, 0.f);
    for (int e = beg + half; e < end; e += 2) {
        int s = esrc[e];
        float c = dis[s] * dn;
        float4 v = *(const float4*)(Hf + (size_t)s * H_ + l4);
        acc.x += v.x * c; acc.y += v.y * c; acc.z += v.z * c; acc.w += v.w * c;
    }
    acc.x += __shfl_xor(acc.x, 32);
    acc.y += __shfl_xor(acc.y, 32);
    acc.z += __shfl_xor(acc.z, 32);
    acc.w += __shfl_xor(acc.w, 32);
    if (half == 0) {
        float4 hv = *(const float4*)(Hf + (size_t)n * H_ + l4);
        float4 bv = *(const float4*)(bias + l4);
        float s2 = dn * dn;
        float o0 = fmaxf(acc.x + hv.x * s2 + bv.x, 0.f);
        float o1 = fmaxf(acc.y + hv.y * s2 + bv.y, 0.f);
        float o2 = fmaxf(acc.z + hv.z * s2 + bv.z, 0.f);
        float o3 = fmaxf(acc.w + hv.w * s2 + bv.w, 0.f);
        *(float4*)(out + (size_t)n * H_ + l4) = make_float4(o0, o1, o2, o3);
        float4 pv = *(const float4*)(p + l4);
        float dt = o0 * pv.x + o1 * pv.y + o2 * pv.z + o3 * pv.w;
        for (int mm = 16; mm > 0; mm >>= 1) dt += __shfl_xor(dt, mm);
        if ((lane & 31) == 0) score[n] = tanhf(dt * invn[0]);
    }
}

// ---------- exact per-graph top-k via bitonic sort (desc, tie: low index) ----------
__global__ __launch_bounds__(1024) void topk_k(const float* __restrict__ score, int n, int k,
                                               int* __restrict__ selOld, int* __restrict__ newpos)
{
    __shared__ unsigned long long key[2048];
    int b = blockIdx.x;
    const float* s = score + (size_t)b * n;
    for (int i = threadIdx.x; i < 2048; i += 1024) {
        unsigned long long pk = 0ull;
        if (i < n) {
            unsigned u = __float_as_uint(s[i]);
            u = (u & 0x80000000u) ? ~u : (u | 0x80000000u);
            pk = ((unsigned long long)u << 32) | (unsigned)(65535 - i);
        }
        key[i] = pk;
    }
    __syncthreads();
    for (int sz = 2; sz <= 2048; sz <<= 1) {
        for (int st = sz >> 1; st > 0; st >>= 1) {
            for (int t = threadIdx.x; t < 2048; t += 1024) {
                int j = t ^ st;
                if (j > t) {
                    unsigned long long a = key[t], c = key[j];
                    bool desc = ((t & sz) == 0);
                    if ((a < c) == desc) { key[t] = c; key[j] = a; }
                }
            }
            __syncthreads();
        }
    }
    for (int j = threadIdx.x; j < k; j += 1024) {
        int o = 65535 - (int)(key[j] & 0xFFFFFFFFull);
        int oldg = b * n + o;
        selOld[b * k + j] = oldg;
        newpos[oldg] = b * k + j;
    }
}

// ---------- readout stage 1: per-(graph,segment) partial max/sum, float4 lanes ----------
__global__ __launch_bounds__(512) void readout_part_k(const float* __restrict__ X,
                                                      const int* __restrict__ selOld,
                                                      const float* __restrict__ score,
                                                      int kRows, float* __restrict__ part)
{
    __shared__ float smax[16][128];
    __shared__ float ssum[16][128];
    int b = blockIdx.x / RS;
    int s = blockIdx.x % RS;
    int chunk = (kRows + RS - 1) / RS;
    int j0 = s * chunk;
    int j1 = min(kRows, j0 + chunk);
    int tid = threadIdx.x;
    int f4 = (tid & 31) * 4;
    int q = tid >> 5;                  // 16 row groups
    float4 mx = make_float4(-3.4e38f, -3.4e38f, -3.4e38f, -3.4e38f);
    float4 sm = make_float4(0.f, 0.f, 0.f, 0.f);
    for (int j = j0 + q; j < j1; j += 16) {
        int g = selOld[b * kRows + j];
        float sc = score[g];
        float4 v = *(const float4*)(X + (size_t)g * H_ + f4);
        v.x *= sc; v.y *= sc; v.z *= sc; v.w *= sc;
        mx.x = fmaxf(mx.x, v.x); mx.y = fmaxf(mx.y, v.y);
        mx.z = fmaxf(mx.z, v.z); mx.w = fmaxf(mx.w, v.w);
        sm.x += v.x; sm.y += v.y; sm.z += v.z; sm.w += v.w;
    }
    *(float4*)&smax[q][f4] = mx;
    *(float4*)&ssum[q][f4] = sm;
    __syncthreads();
    if (tid < 128) {
        float m = smax[0][tid], a = ssum[0][tid];
        #pragma unroll
        for (int gq = 1; gq < 16; ++gq) {
            m = fmaxf(m, smax[gq][tid]);
            a += ssum[gq][tid];
        }
        float* pr = part + ((size_t)b * RS + s) * 256;
        pr[tid] = m;
        pr[128 + tid] = a;
    }
}

// ---------- fused readout-reduce + 3-layer MLP head, one block per graph ----------
__global__ __launch_bounds__(256) void head_k(const float* __restrict__ part1,
                                              const float* __restrict__ part2,
                                              const float* __restrict__ part3,
                                              const float* __restrict__ lw1, const float* __restrict__ lb1,
                                              const float* __restrict__ lw2, const float* __restrict__ lb2,
                                              const float* __restrict__ lw3, const float* __restrict__ lb3,
                                              float* __restrict__ out)
{
    __shared__ float sZ[256];
    __shared__ float sZ1[128];
    __shared__ float sZ2[64];
    __shared__ float red[256];
    int b = blockIdx.x;
    int t = threadIdx.x;
    {
        int f = t & 127;
        const float* pr1 = part1 + (size_t)b * RS * 256;
        const float* pr2 = part2 + (size_t)b * RS * 256;
        const float* pr3 = part3 + (size_t)b * RS * 256;
        float zv;
        if (t < 128) {
            float m1 = -3.4e38f, m2 = -3.4e38f, m3 = -3.4e38f;
            #pragma unroll
            for (int s = 0; s < RS; ++s) {
                m1 = fmaxf(m1, pr1[s * 256 + f]);
                m2 = fmaxf(m2, pr2[s * 256 + f]);
                m3 = fmaxf(m3, pr3[s * 256 + f]);
            }
            zv = m1 + m2 + m3;
        } else {
            float s1 = 0.f, s2 = 0.f, s3 = 0.f;
            #pragma unroll
            for (int s = 0; s < RS; ++s) {
                s1 += pr1[s * 256 + 128 + f];
                s2 += pr2[s * 256 + 128 + f];
                s3 += pr3[s * 256 + 128 + f];
            }
            zv = s1 * (1.0f / (float)K1) + s2 * (1.0f / (float)K2) + s3 * (1.0f / (float)K3);
        }
        sZ[t] = zv;
    }
    __syncthreads();
    {
        int c = t & 127, h = t >> 7;
        float acc = 0.f;
        #pragma unroll
        for (int i = 0; i < 128; ++i) {
            int ii = h * 128 + i;
            acc += sZ[ii] * lw1[ii * 128 + c];
        }
        red[t] = acc;
        __syncthreads();
        if (t < 128) sZ1[t] = fmaxf(red[t] + red[128 + t] + lb1[t], 0.f);
        __syncthreads();
    }
    {
        int c = t & 63, q = t >> 6;
        float acc = 0.f;
        #pragma unroll
        for (int i = 0; i < 32; ++i) {
            int ii = q * 32 + i;
            acc += sZ1[ii] * lw2[ii * 64 + c];
        }
        red[t] = acc;
        __syncthreads();
        if (t < 64) sZ2[t] = fmaxf(red[t] + red[64 + t] + red[128 + t] + red[192 + t] + lb2[t], 0.f);
        __syncthreads();
    }
    {
        if (t < 2 * ACT) {
            int c = t >> 1, h = t & 1;
            float acc = 0.f;
            #pragma unroll
            for (int i = 0; i < 32; ++i) {
                int ii = h * 32 + i;
                acc += sZ2[ii] * lw3[ii * ACT + c];
            }
            red[t] = acc;
        }
        __syncthreads();
        if (t < ACT) {
            float s = red[2 * t] + red[2 * t + 1] + lb3[t];
            out[b * ACT + t] = 1.f / (1.f + expf(-s));
        }
    }
}

extern "C" void kernel_launch(void* const* d_in, const int* in_sizes, int n_in,
                              void* d_out, int out_size, void* d_ws, size_t ws_size,
                              hipStream_t stream)
{
    const float* x   = (const float*)d_in[0];
    const int*   src = (const int*)d_in[1];
    const int*   dst = (const int*)d_in[2];
    const float* W1  = (const float*)d_in[3];
    const float* b1  = (const float*)d_in[4];
    const float* W2  = (const float*)d_in[5];
    const float* b2  = (const float*)d_in[6];
    const float* W3  = (const float*)d_in[7];
    const float* b3  = (const float*)d_in[8];
    const float* p1  = (const float*)d_in[9];
    const float* p2  = (const float*)d_in[10];
    const float* p3  = (const float*)d_in[11];
    const float* lw1 = (const float*)d_in[12];
    const float* lb1 = (const float*)d_in[13];
    const float* lw2 = (const float*)d_in[14];
    const float* lb2 = (const float*)d_in[15];
    const float* lw3 = (const float*)d_in[16];
    const float* lb3 = (const float*)d_in[17];

    char* w = (char*)d_ws;
    size_t off = 0;
    auto alloc = [&](size_t bytes) -> void* {
        void* p = w + off;
        off = (off + bytes + 255) & ~(size_t)255;
        return p;
    };
    float* fA     = (float*)alloc((size_t)N0 * H_ * 4);   // staged h (levels 1-2)
    float* fB     = (float*)alloc((size_t)N0 * H_ * 4);   // gcn output activations
    float* score  = (float*)alloc((size_t)N0 * 4);
    int*   newpos = (int*)  alloc((size_t)N0 * 4);
    int*   deg    = (int*)  alloc((size_t)(N0 + 1) * 4);
    int*   cur    = (int*)  alloc((size_t)N0 * 4);        // adjacent to deg: one memset
    float* dis    = (float*)alloc((size_t)(N0 + 1) * 4);
    int*   selOld = (int*)  alloc((size_t)N1 * 4);
    int*   rowoff = (int*)  alloc((size_t)(N0 + 1) * 4);
    int*   bsum   = (int*)  alloc((size_t)1024 * 4);
    int*   cs0    = (int*)  alloc((size_t)E0 * 4);        // level-0 CSR src
    int*   cs1    = (int*)  alloc((size_t)E0 * 4);        // level-1 CSR src
    int*   cd1    = (int*)  alloc((size_t)E0 * 4);        // level-1 edge dst list
    int*   cs2    = (int*)  alloc((size_t)E0 * 4);        // level-2 CSR src
    int*   cd2    = (int*)  alloc((size_t)E0 * 4);        // level-2 edge dst list
    float* part1  = (float*)alloc((size_t)B_ * RS * 256 * 4);
    float* part2  = (float*)alloc((size_t)B_ * RS * 256 * 4);
    float* part3  = (float*)alloc((size_t)B_ * RS * 256 * 4);
    int*   ecnt   = (int*)  alloc(256);                   // [0] = E1 (level-1 edge count)
    float* invn   = (float*)alloc(256);                   // 1/||p|| per current level

    const size_t degcur_bytes = (size_t)((char*)cur - (char*)deg) + (size_t)N0 * 4;

    auto scan_rowoff = [&](int nNodes, int* totalOut, const float* p) {
        int n = nNodes + 1;
        int nb = (n + 1023) / 1024;
        scan1_k<<<nb, 1024, 0, stream>>>(deg, rowoff, bsum, n);
        scan2_k<<<1, 64, 0, stream>>>(bsum, nb, totalOut, p, invn);
        scan3_k<<<(n + 255) / 256, 256, 0, stream>>>(rowoff, bsum, n, deg, dis);
    };

    const int GbX = NPG / 256;         // 8 blocks/graph for aggx (256 nodes each)
    const int Gb1 = (K1 + 3) / 4;      // 410
    const int Gb2 = (K2 + 3) / 4;      // 328

    // ================= GCN1 (level-0: aggregate in x-space, expand by W1) =================
    hipMemsetAsync(deg, 0, degcur_bytes, stream);
    count_deg_k<<<E0 / 256, 256, 0, stream>>>(dst, E0, deg);
    scan_rowoff(N0, nullptr, p1);
    fill_k<<<E0 / 256, 256, 0, stream>>>(src, dst, E0, rowoff, cur, cs0);
    aggx_k<<<B_ * GbX, 256, 0, stream>>>(x, rowoff, cs0, dis, W1, b1, p1, invn, fB, score, NPG, GbX);

    // ---- pool 1: 2048 -> K1 per graph ----
    hipMemsetAsync(newpos, 0xFF, (size_t)N0 * 4, stream);
    topk_k<<<B_, 1024, 0, stream>>>(score, NPG, K1, selOld, newpos);
    readout_part_k<<<B_ * RS, 512, 0, stream>>>(fB, selOld, score, K1, part1);

    // ---- build level-1 CSR directly from (src,dst) + newpos ----
    hipMemsetAsync(deg, 0, degcur_bytes, stream);
    remap_count_k<<<E0 / 256, 256, 0, stream>>>(src, dst, nullptr, E0, newpos, deg);
    scan_rowoff(N1, ecnt, p2);      // also writes E1 total into ecnt
    remap_fill_k<<<E0 / 256, 256, 0, stream>>>(src, dst, nullptr, E0, newpos, rowoff, cur, cs1, cd1);

    // ================= GCN2 (N1 nodes) =================
    mmh_k<<<N1 / 64, 256, 0, stream>>>(fB, selOld, score, W2, fA, N1);
    agg_k<<<B_ * Gb1, 256, 0, stream>>>(fA, rowoff, cs1, dis, b2, p2, invn, fB, score, K1, Gb1);

    // ---- pool 2: K1 -> K2 per graph ----
    hipMemsetAsync(newpos, 0xFF, (size_t)N1 * 4, stream);
    topk_k<<<B_, 1024, 0, stream>>>(score, K1, K2, selOld, newpos);
    readout_part_k<<<B_ * RS, 512, 0, stream>>>(fB, selOld, score, K2, part2);

    // ---- build level-2 CSR from (cs1,cd1) + newpos ----
    hipMemsetAsync(deg, 0, degcur_bytes, stream);
    remap_count_k<<<E0 / 256, 256, 0, stream>>>(cs1, cd1, ecnt, 0, newpos, deg);
    scan_rowoff(N2, nullptr, p3);
    remap_fill_k<<<E0 / 256, 256, 0, stream>>>(cs1, cd1, ecnt, 0, newpos, rowoff, cur, cs2, cd2);

    // ================= GCN3 (N2 nodes) =================
    mmh_k<<<N2 / 64, 256, 0, stream>>>(fB, selOld, score, W3, fA, N2);
    agg_k<<<B_ * Gb2, 256, 0, stream>>>(fA, rowoff, cs2, dis, b3, p3, invn, fB, score, K2, Gb2);

    // ---- pool 3: K2 -> K3 per graph ----
    topk_k<<<B_, 1024, 0, stream>>>(score, K2, K3, selOld, newpos);
    readout_part_k<<<B_ * RS, 512, 0, stream>>>(fB, selOld, score, K3, part3);

    // ================= fused readout-fold + MLP head =================
    head_k<<<B_, 256, 0, stream>>>(part1, part2, part3, lw1, lb1, lw2, lb2, lw3, lb3, (float*)d_out);
}

// Round 10
// 460.950 us; speedup vs baseline: 6.3799x; 1.0678x over previous
//
#include <hip/hip_runtime.h>
#include <math.h>

namespace {
constexpr int B_   = 64;
constexpr int NPG  = 2048;
constexpr int N0   = B_ * NPG;      // 131072
constexpr int E0   = N0 * 4;        // 524288
constexpr int H_   = 128;
constexpr int K1   = 1639, K2 = 1312, K3 = 1050;
constexpr int N1   = B_ * K1;       // 104896
constexpr int N2   = B_ * K2;       // 83968
constexpr int N3   = B_ * K3;       // 67200
constexpr int ACT  = 124;
constexpr int RS   = 32;            // readout segments per graph
}

// ---------- C[r,:] = (Xin[selOld[r],:]*score[selOld[r]]) @ W[128,128] ----------
// 64 rows/block, A-tile in LDS; software-pipelined: A-regs and W-regs for
// group g4+1 are prefetched before the FMAs of group g4 (hides LDS+L2 latency).
__global__ __launch_bounds__(256) void mmh_k(const float* __restrict__ Xin,
                                             const int* __restrict__ selOld,
                                             const float* __restrict__ score,
                                             const float* __restrict__ W,
                                             float* __restrict__ C, int M)
{
    __shared__ float sA[64 * 128];   // 32 KB
    int tid = threadIdx.x;
    int row0 = blockIdx.x * 64;
    #pragma unroll
    for (int ch = 0; ch < 8; ++ch) {
        int i = ch * 1024 + tid * 4;
        int r = i >> 7, c = i & 127;
        int g = selOld[row0 + r];
        float sc = score[g];
        float4 v = *(const float4*)(Xin + (size_t)g * H_ + c);
        v.x *= sc; v.y *= sc; v.z *= sc; v.w *= sc;
        *(float4*)(sA + i) = v;
    }
    __syncthreads();
    int c4 = (tid & 31) * 4;
    int rg = tid >> 5;               // 0..7 -> rows rg*8 .. rg*8+7
    const float* sArow = sA + rg * 8 * 128;
    float4 acc[8];
    #pragma unroll
    for (int q = 0; q < 8; ++q) acc[q] = make_float4(0.f, 0.f, 0.f, 0.f);

    const float* Wp = W + c4;
    float4 w0 = *(const float4*)(Wp + 0 * 128);
    float4 w1 = *(const float4*)(Wp + 1 * 128);
    float4 w2 = *(const float4*)(Wp + 2 * 128);
    float4 w3 = *(const float4*)(Wp + 3 * 128);
    float4 a0[8];
    #pragma unroll
    for (int q = 0; q < 8; ++q) a0[q] = *(const float4*)(sArow + q * 128);

    #pragma unroll 1
    for (int g4 = 0; g4 < 31; ++g4) {
        int kk = g4 * 4;
        // prefetch next W group (L1/L2) and next A group (LDS)
        const float* Wn = Wp + (kk + 4) * 128;
        float4 n0 = *(const float4*)(Wn + 0 * 128);
        float4 n1 = *(const float4*)(Wn + 1 * 128);
        float4 n2 = *(const float4*)(Wn + 2 * 128);
        float4 n3 = *(const float4*)(Wn + 3 * 128);
        float4 an[8];
        #pragma unroll
        for (int q = 0; q < 8; ++q) an[q] = *(const float4*)(sArow + q * 128 + kk + 4);
        // FMAs on current group
        #pragma unroll
        for (int q = 0; q < 8; ++q) {
            float4 a = a0[q];
            acc[q].x += a.x * w0.x; acc[q].y += a.x * w0.y; acc[q].z += a.x * w0.z; acc[q].w += a.x * w0.w;
            acc[q].x += a.y * w1.x; acc[q].y += a.y * w1.y; acc[q].z += a.y * w1.z; acc[q].w += a.y * w1.w;
            acc[q].x += a.z * w2.x; acc[q].y += a.z * w2.y; acc[q].z += a.z * w2.z; acc[q].w += a.z * w2.w;
            acc[q].x += a.w * w3.x; acc[q].y += a.w * w3.y; acc[q].z += a.w * w3.z; acc[q].w += a.w * w3.w;
        }
        #pragma unroll
        for (int q = 0; q < 8; ++q) a0[q] = an[q];
        w0 = n0; w1 = n1; w2 = n2; w3 = n3;
    }
    #pragma unroll
    for (int q = 0; q < 8; ++q) {
        float4 a = a0[q];
        acc[q].x += a.x * w0.x; acc[q].y += a.x * w0.y; acc[q].z += a.x * w0.z; acc[q].w += a.x * w0.w;
        acc[q].x += a.y * w1.x; acc[q].y += a.y * w1.y; acc[q].z += a.y * w1.z; acc[q].w += a.y * w1.w;
        acc[q].x += a.z * w2.x; acc[q].y += a.z * w2.y; acc[q].z += a.z * w2.z; acc[q].w += a.z * w2.w;
        acc[q].x += a.w * w3.x; acc[q].y += a.w * w3.y; acc[q].z += a.w * w3.z; acc[q].w += a.w * w3.w;
    }
    #pragma unroll
    for (int q = 0; q < 8; ++q) {
        int r = row0 + rg * 8 + q;
        *(float4*)(C + (size_t)r * H_ + c4) = acc[q];
    }
}

// ---------- degree count (level 0) ----------
__global__ void count_deg_k(const int* __restrict__ dst, int E, int* __restrict__ deg)
{
    int e = blockIdx.x * blockDim.x + threadIdx.x;
    if (e < E) atomicAdd(deg + dst[e], 1);
}

// ---------- exclusive scan over deg[0..n] -> rowoff ----------
__global__ __launch_bounds__(1024) void scan1_k(const int* __restrict__ in, int* __restrict__ out,
                                                int* __restrict__ bsum, int n)
{
    __shared__ int s[1024];
    int t = threadIdx.x;
    int i = blockIdx.x * 1024 + t;
    int v = (i < n) ? in[i] : 0;
    s[t] = v;
    __syncthreads();
    for (int d = 1; d < 1024; d <<= 1) {
        int add = (t >= d) ? s[t - d] : 0;
        __syncthreads();
        s[t] += add;
        __syncthreads();
    }
    if (i < n) out[i] = s[t] - v;          // exclusive
    if (t == 1023) bsum[blockIdx.x] = s[1023];
}

// parallel block-sum scan (nb <= 256) + parallel 1/||p||
__global__ __launch_bounds__(256) void scan2_k(int* __restrict__ bsum, int nb,
                                               int* __restrict__ totalOut,
                                               const float* __restrict__ p,
                                               float* __restrict__ invnOut)
{
    __shared__ int s[256];
    __shared__ float ps[128];
    int t = threadIdx.x;
    int v = (t < nb) ? bsum[t] : 0;
    s[t] = v;
    if (p && t < 128) ps[t] = p[t] * p[t];
    __syncthreads();
    for (int d = 1; d < 256; d <<= 1) {
        int add = (t >= d) ? s[t - d] : 0;
        __syncthreads();
        s[t] += add;
        __syncthreads();
    }
    if (t < nb) bsum[t] = s[t] - v;
    if (t == 0 && totalOut) *totalOut = s[255];
    // reduce ps
    for (int d = 64; d > 0; d >>= 1) {
        if (p && t < d) ps[t] += ps[t + d];
        __syncthreads();
    }
    if (p && t == 0) *invnOut = rsqrtf(ps[0]);
}

__global__ void scan3_k(int* __restrict__ out, const int* __restrict__ bsum, int n,
                        const int* __restrict__ deg, float* __restrict__ dis)
{
    int i = blockIdx.x * blockDim.x + threadIdx.x;
    if (i < n) {
        out[i] += bsum[i >> 10];
        dis[i] = rsqrtf((float)deg[i] + 1.0f);
    }
}

// ---------- level-0 counting-sort fill: bucket src ids by dst ----------
__global__ void fill_k(const int* __restrict__ src, const int* __restrict__ dst, int E,
                       const int* __restrict__ rowoff, int* __restrict__ cur,
                       int* __restrict__ esrc)
{
    int e = blockIdx.x * blockDim.x + threadIdx.x;
    if (e >= E) return;
    int d = dst[e];
    int pos = rowoff[d] + atomicAdd(cur + d, 1);
    esrc[pos] = src[e];
}

// ---------- remap pass A: count surviving-edge degrees ----------
__global__ void remap_count_k(const int* __restrict__ osrc, const int* __restrict__ odst,
                              const int* __restrict__ ecntIn, int fixedE,
                              const int* __restrict__ newpos, int* __restrict__ deg)
{
    int E = ecntIn ? *ecntIn : fixedE;
    int e = blockIdx.x * blockDim.x + threadIdx.x;
    if (e >= E) return;
    int ns = newpos[osrc[e]];
    int nd = newpos[odst[e]];
    if (ns >= 0 && nd >= 0) atomicAdd(deg + nd, 1);
}

// ---------- remap pass B: fill next-level CSR (+ compacted edge list) ----------
__global__ void remap_fill_k(const int* __restrict__ osrc, const int* __restrict__ odst,
                             const int* __restrict__ ecntIn, int fixedE,
                             const int* __restrict__ newpos, const int* __restrict__ rowoff,
                             int* __restrict__ cur,
                             int* __restrict__ esrc, int* __restrict__ edst)
{
    int E = ecntIn ? *ecntIn : fixedE;
    int e = blockIdx.x * blockDim.x + threadIdx.x;
    if (e >= E) return;
    int ns = newpos[osrc[e]];
    int nd = newpos[odst[e]];
    if (ns >= 0 && nd >= 0) {
        int pos = rowoff[nd] + atomicAdd(cur + nd, 1);
        esrc[pos] = ns;
        edst[pos] = nd;
    }
}

// ---------- level-0 fused GCN, phase-split ----------
__global__ __launch_bounds__(256) void aggx_k(const float* __restrict__ X,
                                              const int* __restrict__ rowoff,
                                              const int* __restrict__ esrc,
                                              const float* __restrict__ dis,
                                              const float* __restrict__ W1,
                                              const float* __restrict__ b1,
                                              const float* __restrict__ p1,
                                              const float* __restrict__ invn,
                                              float* __restrict__ out,
                                              float* __restrict__ score,
                                              int npg, int Gb)
{
    __shared__ float sW[512];
    __shared__ float sb[128];
    __shared__ float sp[128];
    __shared__ float sxa[256 * 4];
    __shared__ float sdt[256];
    int tid = threadIdx.x;
    for (int i = tid; i < 512; i += 256) sW[i] = W1[i];
    if (tid < 128) { sb[tid] = b1[tid]; sp[tid] = p1[tid]; }
    int pb = blockIdx.x;
    int x8 = pb & 7;
    int m  = pb >> 3;
    int g  = x8 + 8 * (m / Gb);
    int lb = m % Gb;
    int nbase = g * npg + lb * 256;
    // phase 1: per-thread aggregation in 4-dim input space
    int n = nbase + tid;
    float dn = dis[n];
    float4 xa = *(const float4*)(X + (size_t)n * 4);
    float s2 = dn * dn;
    xa.x *= s2; xa.y *= s2; xa.z *= s2; xa.w *= s2;
    int beg = rowoff[n], end = rowoff[n + 1];
    for (int e = beg; e < end; ++e) {
        int s = esrc[e];
        float c = dis[s] * dn;
        float4 xs = *(const float4*)(X + (size_t)s * 4);
        xa.x += xs.x * c; xa.y += xs.y * c; xa.z += xs.z * c; xa.w += xs.w * c;
    }
    *(float4*)(sxa + tid * 4) = xa;
    __syncthreads();
    // phase 2: each wave expands 64 nodes, 2 channels per lane
    int wv = tid >> 6;
    int lane = tid & 63;
    int c0 = lane * 2;
    float wa0 = sW[c0],     wb0 = sW[128 + c0],     wc0 = sW[256 + c0],     wd0 = sW[384 + c0];
    float wa1 = sW[c0 + 1], wb1 = sW[128 + c0 + 1], wc1 = sW[256 + c0 + 1], wd1 = sW[384 + c0 + 1];
    float bb0 = sb[c0], bb1 = sb[c0 + 1];
    float pp0 = sp[c0], pp1 = sp[c0 + 1];
    #pragma unroll 4
    for (int ii = 0; ii < 64; ++ii) {
        int i = wv * 64 + ii;
        float4 a = *(const float4*)(sxa + i * 4);
        float o0 = fmaxf(a.x * wa0 + a.y * wb0 + a.z * wc0 + a.w * wd0 + bb0, 0.f);
        float o1 = fmaxf(a.x * wa1 + a.y * wb1 + a.z * wc1 + a.w * wd1 + bb1, 0.f);
        ((float2*)(out + (size_t)(nbase + i) * H_))[lane] = make_float2(o0, o1);
        float dt = o0 * pp0 + o1 * pp1;
        for (int mm = 32; mm > 0; mm >>= 1) dt += __shfl_xor(dt, mm);
        if (lane == 0) sdt[i] = dt;
    }
    __syncthreads();
    // phase 3: thread-parallel score
    score[nbase + tid] = tanhf(sdt[tid] * invn[0]);
}

// ---------- levels 1-2 gather-aggregate: 2 edges/wave-iter, float4 lanes ----------
__global__ __launch_bounds__(256) void agg_k(const float* __restrict__ Hf,
                                             const int* __restrict__ rowoff,
                                             const int* __restrict__ esrc,
                                             const float* __restrict__ dis,
                                             const float* __restrict__ bias,
                                             const float* __restrict__ p,
                                             const float* __restrict__ invn,
                                             float* __restrict__ out,
                                             float* __restrict__ score,
                                             int npg, int Gb)
{
    int pb = blockIdx.x;
    int x8 = pb & 7;
    int m  = pb >> 3;
    int g  = x8 + 8 * (m / Gb);
    int lb = m % Gb;
    int j  = lb * 4 + (threadIdx.x >> 6);
    if (j >= npg) return;
    int n = g * npg + j;
    int lane = threadIdx.x & 63;
    int half = lane >> 5;
    int l4 = (lane & 31) * 4;
    float dn = dis[n];
    int beg = rowoff[n], end = rowoff[n + 1];
    float4 acc = make_float4(0.f, 0.f, 0.f, 0.f);
    for (int e = beg + half; e < end; e += 2) {
        int s = esrc[e];
        float c = dis[s] * dn;
        float4 v = *(const float4*)(Hf + (size_t)s * H_ + l4);
        acc.x += v.x * c; acc.y += v.y * c; acc.z += v.z * c; acc.w += v.w * c;
    }
    acc.x += __shfl_xor(acc.x, 32);
    acc.y += __shfl_xor(acc.y, 32);
    acc.z += __shfl_xor(acc.z, 32);
    acc.w += __shfl_xor(acc.w, 32);
    if (half == 0) {
        float4 hv = *(const float4*)(Hf + (size_t)n * H_ + l4);
        float4 bv = *(const float4*)(bias + l4);
        float s2 = dn * dn;
        float o0 = fmaxf(acc.x + hv.x * s2 + bv.x, 0.f);
        float o1 = fmaxf(acc.y + hv.y * s2 + bv.y, 0.f);
        float o2 = fmaxf(acc.z + hv.z * s2 + bv.z, 0.f);
        float o3 = fmaxf(acc.w + hv.w * s2 + bv.w, 0.f);
        *(float4*)(out + (size_t)n * H_ + l4) = make_float4(o0, o1, o2, o3);
        float4 pv = *(const float4*)(p + l4);
        float dt = o0 * pv.x + o1 * pv.y + o2 * pv.z + o3 * pv.w;
        for (int mm = 16; mm > 0; mm >>= 1) dt += __shfl_xor(dt, mm);
        if ((lane & 31) == 0) score[n] = tanhf(dt * invn[0]);
    }
}

// ---------- exact per-graph top-k via bitonic sort (desc, tie: low index) ----------
__global__ __launch_bounds__(1024) void topk_k(const float* __restrict__ score, int n, int k,
                                               int* __restrict__ selOld, int* __restrict__ newpos)
{
    __shared__ unsigned long long key[2048];
    int b = blockIdx.x;
    const float* s = score + (size_t)b * n;
    for (int i = threadIdx.x; i < 2048; i += 1024) {
        unsigned long long pk = 0ull;
        if (i < n) {
            unsigned u = __float_as_uint(s[i]);
            u = (u & 0x80000000u) ? ~u : (u | 0x80000000u);
            pk = ((unsigned long long)u << 32) | (unsigned)(65535 - i);
        }
        key[i] = pk;
    }
    __syncthreads();
    for (int sz = 2; sz <= 2048; sz <<= 1) {
        for (int st = sz >> 1; st > 0; st >>= 1) {
            for (int t = threadIdx.x; t < 2048; t += 1024) {
                int j = t ^ st;
                if (j > t) {
                    unsigned long long a = key[t], c = key[j];
                    bool desc = ((t & sz) == 0);
                    if ((a < c) == desc) { key[t] = c; key[j] = a; }
                }
            }
            __syncthreads();
        }
    }
    for (int j = threadIdx.x; j < k; j += 1024) {
        int o = 65535 - (int)(key[j] & 0xFFFFFFFFull);
        int oldg = b * n + o;
        selOld[b * k + j] = oldg;
        newpos[oldg] = b * k + j;
    }
}

// ---------- readout stage 1: per-(graph,segment) partial max/sum, float4 lanes ----------
__global__ __launch_bounds__(512) void readout_part_k(const float* __restrict__ X,
                                                      const int* __restrict__ selOld,
                                                      const float* __restrict__ score,
                                                      int kRows, float* __restrict__ part)
{
    __shared__ float smax[16][128];
    __shared__ float ssum[16][128];
    int b = blockIdx.x / RS;
    int s = blockIdx.x % RS;
    int chunk = (kRows + RS - 1) / RS;
    int j0 = s * chunk;
    int j1 = min(kRows, j0 + chunk);
    int tid = threadIdx.x;
    int f4 = (tid & 31) * 4;
    int q = tid >> 5;                  // 16 row groups
    float4 mx = make_float4(-3.4e38f, -3.4e38f, -3.4e38f, -3.4e38f);
    float4 sm = make_float4(0.f, 0.f, 0.f, 0.f);
    for (int j = j0 + q; j < j1; j += 16) {
        int g = selOld[b * kRows + j];
        float sc = score[g];
        float4 v = *(const float4*)(X + (size_t)g * H_ + f4);
        v.x *= sc; v.y *= sc; v.z *= sc; v.w *= sc;
        mx.x = fmaxf(mx.x, v.x); mx.y = fmaxf(mx.y, v.y);
        mx.z = fmaxf(mx.z, v.z); mx.w = fmaxf(mx.w, v.w);
        sm.x += v.x; sm.y += v.y; sm.z += v.z; sm.w += v.w;
    }
    *(float4*)&smax[q][f4] = mx;
    *(float4*)&ssum[q][f4] = sm;
    __syncthreads();
    if (tid < 128) {
        float m = smax[0][tid], a = ssum[0][tid];
        #pragma unroll
        for (int gq = 1; gq < 16; ++gq) {
            m = fmaxf(m, smax[gq][tid]);
            a += ssum[gq][tid];
        }
        float* pr = part + ((size_t)b * RS + s) * 256;
        pr[tid] = m;
        pr[128 + tid] = a;
    }
}

// ---------- fused readout-reduce + 3-layer MLP head, one block per graph ----------
__global__ __launch_bounds__(256) void head_k(const float* __restrict__ part1,
                                              const float* __restrict__ part2,
                                              const float* __restrict__ part3,
                                              const float* __restrict__ lw1, const float* __restrict__ lb1,
                                              const float* __restrict__ lw2, const float* __restrict__ lb2,
                                              const float* __restrict__ lw3, const float* __restrict__ lb3,
                                              float* __restrict__ out)
{
    __shared__ float sZ[256];
    __shared__ float sZ1[128];
    __shared__ float sZ2[64];
    __shared__ float red[256];
    int b = blockIdx.x;
    int t = threadIdx.x;
    {
        int f = t & 127;
        const float* pr1 = part1 + (size_t)b * RS * 256;
        const float* pr2 = part2 + (size_t)b * RS * 256;
        const float* pr3 = part3 + (size_t)b * RS * 256;
        float zv;
        if (t < 128) {
            float m1 = -3.4e38f, m2 = -3.4e38f, m3 = -3.4e38f;
            #pragma unroll
            for (int s = 0; s < RS; ++s) {
                m1 = fmaxf(m1, pr1[s * 256 + f]);
                m2 = fmaxf(m2, pr2[s * 256 + f]);
                m3 = fmaxf(m3, pr3[s * 256 + f]);
            }
            zv = m1 + m2 + m3;
        } else {
            float s1 = 0.f, s2 = 0.f, s3 = 0.f;
            #pragma unroll
            for (int s = 0; s < RS; ++s) {
                s1 += pr1[s * 256 + 128 + f];
                s2 += pr2[s * 256 + 128 + f];
                s3 += pr3[s * 256 + 128 + f];
            }
            zv = s1 * (1.0f / (float)K1) + s2 * (1.0f / (float)K2) + s3 * (1.0f / (float)K3);
        }
        sZ[t] = zv;
    }
    __syncthreads();
    {
        int c = t & 127, h = t >> 7;
        float acc = 0.f;
        #pragma unroll
        for (int i = 0; i < 128; ++i) {
            int ii = h * 128 + i;
            acc += sZ[ii] * lw1[ii * 128 + c];
        }
        red[t] = acc;
        __syncthreads();
        if (t < 128) sZ1[t] = fmaxf(red[t] + red[128 + t] + lb1[t], 0.f);
        __syncthreads();
    }
    {
        int c = t & 63, q = t >> 6;
        float acc = 0.f;
        #pragma unroll
        for (int i = 0; i < 32; ++i) {
            int ii = q * 32 + i;
            acc += sZ1[ii] * lw2[ii * 64 + c];
        }
        red[t] = acc;
        __syncthreads();
        if (t < 64) sZ2[t] = fmaxf(red[t] + red[64 + t] + red[128 + t] + red[192 + t] + lb2[t], 0.f);
        __syncthreads();
    }
    {
        if (t < 2 * ACT) {
            int c = t >> 1, h = t & 1;
            float acc = 0.f;
            #pragma unroll
            for (int i = 0; i < 32; ++i) {
                int ii = h * 32 + i;
                acc += sZ2[ii] * lw3[ii * ACT + c];
            }
            red[t] = acc;
        }
        __syncthreads();
        if (t < ACT) {
            float s = red[2 * t] + red[2 * t + 1] + lb3[t];
            out[b * ACT + t] = 1.f / (1.f + expf(-s));
        }
    }
}

extern "C" void kernel_launch(void* const* d_in, const int* in_sizes, int n_in,
                              void* d_out, int out_size, void* d_ws, size_t ws_size,
                              hipStream_t stream)
{
    const float* x   = (const float*)d_in[0];
    const int*   src = (const int*)d_in[1];
    const int*   dst = (const int*)d_in[2];
    const float* W1  = (const float*)d_in[3];
    const float* b1  = (const float*)d_in[4];
    const float* W2  = (const float*)d_in[5];
    const float* b2  = (const float*)d_in[6];
    const float* W3  = (const float*)d_in[7];
    const float* b3  = (const float*)d_in[8];
    const float* p1  = (const float*)d_in[9];
    const float* p2  = (const float*)d_in[10];
    const float* p3  = (const float*)d_in[11];
    const float* lw1 = (const float*)d_in[12];
    const float* lb1 = (const float*)d_in[13];
    const float* lw2 = (const float*)d_in[14];
    const float* lb2 = (const float*)d_in[15];
    const float* lw3 = (const float*)d_in[16];
    const float* lb3 = (const float*)d_in[17];

    char* w = (char*)d_ws;
    size_t off = 0;
    auto alloc = [&](size_t bytes) -> void* {
        void* p = w + off;
        off = (off + bytes + 255) & ~(size_t)255;
        return p;
    };
    float* fA     = (float*)alloc((size_t)N0 * H_ * 4);   // staged h (levels 1-2)
    float* fB     = (float*)alloc((size_t)N0 * H_ * 4);   // gcn output activations
    float* score  = (float*)alloc((size_t)N0 * 4);
    int*   newpos = (int*)  alloc((size_t)N0 * 4);
    int*   deg    = (int*)  alloc((size_t)(N0 + 1) * 4);
    int*   cur    = (int*)  alloc((size_t)N0 * 4);        // adjacent to deg: one memset
    float* dis    = (float*)alloc((size_t)(N0 + 1) * 4);
    int*   selOld = (int*)  alloc((size_t)N1 * 4);
    int*   rowoff = (int*)  alloc((size_t)(N0 + 1) * 4);
    int*   bsum   = (int*)  alloc((size_t)1024 * 4);
    int*   cs0    = (int*)  alloc((size_t)E0 * 4);        // level-0 CSR src
    int*   cs1    = (int*)  alloc((size_t)E0 * 4);        // level-1 CSR src
    int*   cd1    = (int*)  alloc((size_t)E0 * 4);        // level-1 edge dst list
    int*   cs2    = (int*)  alloc((size_t)E0 * 4);        // level-2 CSR src
    int*   cd2    = (int*)  alloc((size_t)E0 * 4);        // level-2 edge dst list
    float* part1  = (float*)alloc((size_t)B_ * RS * 256 * 4);
    float* part2  = (float*)alloc((size_t)B_ * RS * 256 * 4);
    float* part3  = (float*)alloc((size_t)B_ * RS * 256 * 4);
    int*   ecnt   = (int*)  alloc(256);                   // [0] = E1 (level-1 edge count)
    float* invn   = (float*)alloc(256);                   // 1/||p|| per current level

    const size_t degcur_bytes = (size_t)((char*)cur - (char*)deg) + (size_t)N0 * 4;

    auto scan_rowoff = [&](int nNodes, int* totalOut, const float* p) {
        int n = nNodes + 1;
        int nb = (n + 1023) / 1024;
        scan1_k<<<nb, 1024, 0, stream>>>(deg, rowoff, bsum, n);
        scan2_k<<<1, 256, 0, stream>>>(bsum, nb, totalOut, p, invn);
        scan3_k<<<(n + 255) / 256, 256, 0, stream>>>(rowoff, bsum, n, deg, dis);
    };

    const int GbX = NPG / 256;         // 8 blocks/graph for aggx (256 nodes each)
    const int Gb1 = (K1 + 3) / 4;      // 410
    const int Gb2 = (K2 + 3) / 4;      // 328

    // ================= GCN1 (level-0: aggregate in x-space, expand by W1) =================
    hipMemsetAsync(deg, 0, degcur_bytes, stream);
    count_deg_k<<<E0 / 256, 256, 0, stream>>>(dst, E0, deg);
    scan_rowoff(N0, nullptr, p1);
    fill_k<<<E0 / 256, 256, 0, stream>>>(src, dst, E0, rowoff, cur, cs0);
    aggx_k<<<B_ * GbX, 256, 0, stream>>>(x, rowoff, cs0, dis, W1, b1, p1, invn, fB, score, NPG, GbX);

    // ---- pool 1: 2048 -> K1 per graph ----
    hipMemsetAsync(newpos, 0xFF, (size_t)N0 * 4, stream);
    topk_k<<<B_, 1024, 0, stream>>>(score, NPG, K1, selOld, newpos);
    readout_part_k<<<B_ * RS, 512, 0, stream>>>(fB, selOld, score, K1, part1);

    // ---- build level-1 CSR directly from (src,dst) + newpos ----
    hipMemsetAsync(deg, 0, degcur_bytes, stream);
    remap_count_k<<<E0 / 256, 256, 0, stream>>>(src, dst, nullptr, E0, newpos, deg);
    scan_rowoff(N1, ecnt, p2);      // also writes E1 total into ecnt
    remap_fill_k<<<E0 / 256, 256, 0, stream>>>(src, dst, nullptr, E0, newpos, rowoff, cur, cs1, cd1);

    // ================= GCN2 (N1 nodes) =================
    mmh_k<<<N1 / 64, 256, 0, stream>>>(fB, selOld, score, W2, fA, N1);
    agg_k<<<B_ * Gb1, 256, 0, stream>>>(fA, rowoff, cs1, dis, b2, p2, invn, fB, score, K1, Gb1);

    // ---- pool 2: K1 -> K2 per graph ----
    hipMemsetAsync(newpos, 0xFF, (size_t)N1 * 4, stream);
    topk_k<<<B_, 1024, 0, stream>>>(score, K1, K2, selOld, newpos);
    readout_part_k<<<B_ * RS, 512, 0, stream>>>(fB, selOld, score, K2, part2);

    // ---- build level-2 CSR from (cs1,cd1) + newpos ----
    hipMemsetAsync(deg, 0, degcur_bytes, stream);
    remap_count_k<<<E0 / 256, 256, 0, stream>>>(cs1, cd1, ecnt, 0, newpos, deg);
    scan_rowoff(N2, nullptr, p3);
    remap_fill_k<<<E0 / 256, 256, 0, stream>>>(cs1, cd1, ecnt, 0, newpos, rowoff, cur, cs2, cd2);

    // ================= GCN3 (N2 nodes) =================
    mmh_k<<<N2 / 64, 256, 0, stream>>>(fB, selOld, score, W3, fA, N2);
    agg_k<<<B_ * Gb2, 256, 0, stream>>>(fA, rowoff, cs2, dis, b3, p3, invn, fB, score, K2, Gb2);

    // ---- pool 3: K2 -> K3 per graph ----
    topk_k<<<B_, 1024, 0, stream>>>(score, K2, K3, selOld, newpos);
    readout_part_k<<<B_ * RS, 512, 0, stream>>>(fB, selOld, score, K3, part3);

    // ================= fused readout-fold + MLP head =================
    head_k<<<B_, 256, 0, stream>>>(part1, part2, part3, lw1, lb1, lw2, lb2, lw3, lb3, (float*)d_out);
}